// Round 2
// baseline (2549.442 us; speedup 1.0000x reference)
//
#include <hip/hip_runtime.h>
#include <hip/hip_bf16.h>

#define N_NODES 50000
#define N_REL   16
#define DIM     128
#define NBLK    4
#define BS      32
#define N_EDGES 800000
#define NSEG    (N_NODES * N_REL)      // 800000 segments (dst, rel)
#define SCAN_BLK 1024                  // elements per scan block
#define N_SCAN_BLKS ((NSEG + SCAN_BLK - 1) / SCAN_BLK)   // 782

// ---------------------------------------------------------------------------
// Kernel 1: count edges per (dst, rel) segment
// ---------------------------------------------------------------------------
__global__ __launch_bounds__(256) void count_kernel(const int* __restrict__ dst,
                                                    const int* __restrict__ et,
                                                    int* __restrict__ cnt, int E) {
    int e = blockIdx.x * 256 + threadIdx.x;
    if (e < E) atomicAdd(&cnt[dst[e] * N_REL + et[e]], 1);
}

// ---------------------------------------------------------------------------
// Exclusive scan over NSEG ints: scan1 (per-block) -> scan2 (block sums) ->
// scan3 (add block offsets). After scan3, off[] = global exclusive prefix.
// ---------------------------------------------------------------------------
__global__ __launch_bounds__(256) void scan1_kernel(const int* __restrict__ in,
                                                    int* __restrict__ out,
                                                    int* __restrict__ bsum, int M) {
    const int t = threadIdx.x;
    const int base = blockIdx.x * SCAN_BLK + t * 4;
    int v0 = (base + 0 < M) ? in[base + 0] : 0;
    int v1 = (base + 1 < M) ? in[base + 1] : 0;
    int v2 = (base + 2 < M) ? in[base + 2] : 0;
    int v3 = (base + 3 < M) ? in[base + 3] : 0;
    const int s = v0 + v1 + v2 + v3;
    const int lane = t & 63, wid = t >> 6;
    int inc = s;
    for (int d = 1; d < 64; d <<= 1) {
        int u = __shfl_up(inc, d, 64);
        if (lane >= d) inc += u;
    }
    __shared__ int wsum[5];
    if (lane == 63) wsum[wid] = inc;
    __syncthreads();
    if (t == 0) {
        int a = 0;
        for (int w = 0; w < 4; ++w) { int u = wsum[w]; wsum[w] = a; a += u; }
        wsum[4] = a;
    }
    __syncthreads();
    const int ex = inc - s + wsum[wid];
    if (base + 0 < M) out[base + 0] = ex;
    if (base + 1 < M) out[base + 1] = ex + v0;
    if (base + 2 < M) out[base + 2] = ex + v0 + v1;
    if (base + 3 < M) out[base + 3] = ex + v0 + v1 + v2;
    if (t == 0) bsum[blockIdx.x] = wsum[4];
}

__global__ __launch_bounds__(1024) void scan2_kernel(int* __restrict__ bsum, int nb) {
    const int t = threadIdx.x;                 // 1024 threads, nb <= 1024
    int s = (t < nb) ? bsum[t] : 0;
    const int lane = t & 63, wid = t >> 6;
    int inc = s;
    for (int d = 1; d < 64; d <<= 1) {
        int u = __shfl_up(inc, d, 64);
        if (lane >= d) inc += u;
    }
    __shared__ int wsum[16];
    if (lane == 63) wsum[wid] = inc;
    __syncthreads();
    if (t == 0) {
        int a = 0;
        for (int w = 0; w < 16; ++w) { int u = wsum[w]; wsum[w] = a; a += u; }
    }
    __syncthreads();
    const int ex = inc - s + wsum[wid];
    if (t < nb) bsum[t] = ex;
}

__global__ __launch_bounds__(256) void scan3_kernel(int* __restrict__ out,
                                                    const int* __restrict__ bsum, int M) {
    int i = blockIdx.x * 256 + threadIdx.x;
    if (i < M) out[i] += bsum[i / SCAN_BLK];
}

// ---------------------------------------------------------------------------
// Scatter edges into CSR order: srcs[pos] = src[e], pos from segment cursor.
// After this pass, off[seg] = segment END (start = end - cnt[seg]).
// ---------------------------------------------------------------------------
__global__ __launch_bounds__(256) void scatter_kernel(const int* __restrict__ src,
                                                      const int* __restrict__ dst,
                                                      const int* __restrict__ et,
                                                      int* __restrict__ off,
                                                      int* __restrict__ srcs, int E) {
    int e = blockIdx.x * 256 + threadIdx.x;
    if (e < E) {
        int seg = dst[e] * N_REL + et[e];
        int pos = atomicAdd(&off[seg], 1);
        srcs[pos] = src[e];
    }
}

// ---------------------------------------------------------------------------
// Dense: out[n][:] = bias + act(x[n]) @ root
// ---------------------------------------------------------------------------
template<bool RELU>
__global__ __launch_bounds__(256) void dense_kernel(const float* __restrict__ x,
                                                    const float* __restrict__ root,
                                                    const float* __restrict__ bias,
                                                    float* __restrict__ out, int Ntot) {
    __shared__ float root_sh[DIM * 64];   // [k][j_local]  32KB
    __shared__ float x_sh[32 * DIM];      // [n_local][k]  16KB

    const int jhalf = blockIdx.y;
    const int base  = blockIdx.x * 32;
    const int nn    = min(32, Ntot - base);

    for (int idx = threadIdx.x * 4; idx < DIM * 64; idx += 1024) {
        int row = idx >> 6, col = idx & 63;
        *(float4*)&root_sh[idx] = *(const float4*)&root[row * DIM + jhalf * 64 + col];
    }
    for (int idx = threadIdx.x * 4; idx < nn * DIM; idx += 1024) {
        float4 v = *(const float4*)&x[base * DIM + idx];
        if (RELU) {
            v.x = fmaxf(v.x, 0.f); v.y = fmaxf(v.y, 0.f);
            v.z = fmaxf(v.z, 0.f); v.w = fmaxf(v.w, 0.f);
        }
        *(float4*)&x_sh[idx] = v;
    }
    __syncthreads();

    const int jl   = threadIdx.x & 63;
    const int wave = threadIdx.x >> 6;
    const float bj = bias[jhalf * 64 + jl];

    for (int nl = wave; nl < nn; nl += 4) {
        float acc = bj;
#pragma unroll 16
        for (int k = 0; k < DIM; ++k)
            acc = fmaf(x_sh[nl * DIM + k], root_sh[k * 64 + jl], acc);
        out[(base + nl) * DIM + jhalf * 64 + jl] = acc;
    }
}

// ---------------------------------------------------------------------------
// Gather-aggregate: one half-wave (32 lanes) per (dst node, block column).
// For each non-empty segment (dst, r): xs = sum of x[src] over the segment,
// then acc += W_r^T . (xs / c). No atomics: out row owned by one half-wave.
// out must already contain the dense part (read-modify-write).
// ---------------------------------------------------------------------------
template<bool RELU>
__global__ __launch_bounds__(256) void agg_kernel(const int* __restrict__ srcs,
                                                  const int* __restrict__ off,
                                                  const int* __restrict__ cnt,
                                                  const float* __restrict__ x,
                                                  const float* __restrict__ W,
                                                  float* __restrict__ out) {
    __shared__ float Wsh[N_REL * BS * BS];   // 64KB: W[:, b, :, :]
    const int bblk = blockIdx.y;

    for (int idx = threadIdx.x * 4; idx < N_REL * BS * BS; idx += 1024) {
        int r = idx >> 10, rest = idx & 1023;
        *(float4*)&Wsh[idx] = *(const float4*)&W[(r * NBLK + bblk) * 1024 + rest];
    }
    __syncthreads();

    const int hw = threadIdx.x >> 5;         // half-wave id 0..7
    const int o  = threadIdx.x & 31;         // output index within block
    const int v  = blockIdx.x * 8 + hw;      // dst node (grid sized exactly)

    // preload this node's 16 segment (end, count) pairs across lanes 0..15
    int endv = 0, cv = 0;
    if (o < N_REL) {
        endv = off[v * N_REL + o];
        cv   = cnt[v * N_REL + o];
    }

    float acc = out[v * DIM + bblk * BS + o];

    for (int r = 0; r < N_REL; ++r) {
        const int c = __shfl(cv, r, 32);
        if (c == 0) continue;
        const int end = __shfl(endv, r, 32);
        float xs = 0.f;
        for (int k = end - c; k < end; ++k) {
            const int s = srcs[k];
            float xv = x[s * DIM + bblk * BS + o];
            if (RELU) xv = fmaxf(xv, 0.f);
            xs += xv;
        }
        xs *= (1.0f / (float)c);
        const float* wr = &Wsh[r * (BS * BS)];
#pragma unroll
        for (int i = 0; i < BS; i += 2) {
            float xi0 = __shfl(xs, i,     32);
            float xi1 = __shfl(xs, i + 1, 32);
            acc = fmaf(xi0, wr[i * BS + o],       acc);
            acc = fmaf(xi1, wr[(i + 1) * BS + o], acc);
        }
    }
    out[v * DIM + bblk * BS + o] = acc;
}

// ---------------------------------------------------------------------------
extern "C" void kernel_launch(void* const* d_in, const int* in_sizes, int n_in,
                              void* d_out, int out_size, void* d_ws, size_t ws_size,
                              hipStream_t stream) {
    const int*   edge_index = (const int*)d_in[0];
    const int*   src   = edge_index;             // row 0
    const int*   dstv  = edge_index + N_EDGES;   // row 1
    const int*   et    = (const int*)d_in[1];
    const float* x0    = (const float*)d_in[2];
    const float* W1    = (const float*)d_in[3];
    const float* root1 = (const float*)d_in[4];
    const float* bias1 = (const float*)d_in[5];
    const float* W2    = (const float*)d_in[6];
    const float* root2 = (const float*)d_in[7];
    const float* bias2 = (const float*)d_in[8];
    float* out = (float*)d_out;

    // workspace layout
    float* h    = (float*)d_ws;                  // N*D fp32      25.6MB
    int*   cnt  = (int*)(h + (size_t)N_NODES * DIM);   // NSEG   3.2MB
    int*   off  = cnt + NSEG;                    // NSEG          3.2MB
    int*   srcs = off + NSEG;                    // E             3.2MB
    int*   bsum = srcs + N_EDGES;                // scan block sums

    // ---- build CSR sorted by (dst, rel): count -> scan -> scatter ----
    hipMemsetAsync(cnt, 0, (size_t)NSEG * sizeof(int), stream);
    count_kernel<<<(N_EDGES + 255) / 256, 256, 0, stream>>>(dstv, et, cnt, N_EDGES);
    scan1_kernel<<<N_SCAN_BLKS, 256, 0, stream>>>(cnt, off, bsum, NSEG);
    scan2_kernel<<<1, 1024, 0, stream>>>(bsum, N_SCAN_BLKS);
    scan3_kernel<<<(NSEG + 255) / 256, 256, 0, stream>>>(off, bsum, NSEG);
    scatter_kernel<<<(N_EDGES + 255) / 256, 256, 0, stream>>>(src, dstv, et, off, srcs, N_EDGES);

    dim3 dgrid((N_NODES + 31) / 32, 2);
    dim3 agrid(N_NODES / 8, NBLK);               // 6250 x 4

    // ---- layer 1: h = x0 @ root1 + bias1 + aggregated messages ----
    dense_kernel<false><<<dgrid, 256, 0, stream>>>(x0, root1, bias1, h, N_NODES);
    agg_kernel<false><<<agrid, 256, 0, stream>>>(srcs, off, cnt, x0, W1, h);

    // ---- layer 2: out = relu(h) @ root2 + bias2 + aggregated messages ----
    dense_kernel<true><<<dgrid, 256, 0, stream>>>(h, root2, bias2, out, N_NODES);
    agg_kernel<true><<<agrid, 256, 0, stream>>>(srcs, off, cnt, h, W2, out);
}

// Round 3
// 826.962 us; speedup vs baseline: 3.0829x; 3.0829x over previous
//
#include <hip/hip_runtime.h>
#include <hip/hip_bf16.h>

#define N_NODES 50000
#define N_REL   16
#define DIM     128
#define NBLK    4
#define BS      32
#define N_EDGES 800000
#define NSEG    (N_NODES * N_REL)
#define SCAN_BLK 1024
#define N_SCAN_BLKS ((NSEG + SCAN_BLK - 1) / SCAN_BLK)

__device__ __forceinline__ float bf2f(ushort u) {
    return __uint_as_float(((unsigned int)u) << 16);
}

// ---------------------------------------------------------------------------
// CSR build: count -> scan -> scatter (same as round 2, it works)
// ---------------------------------------------------------------------------
__global__ __launch_bounds__(256) void count_kernel(const int* __restrict__ dst,
                                                    const int* __restrict__ et,
                                                    int* __restrict__ cnt, int E) {
    int e = blockIdx.x * 256 + threadIdx.x;
    if (e < E) atomicAdd(&cnt[dst[e] * N_REL + et[e]], 1);
}

__global__ __launch_bounds__(256) void scan1_kernel(const int* __restrict__ in,
                                                    int* __restrict__ out,
                                                    int* __restrict__ bsum, int M) {
    const int t = threadIdx.x;
    const int base = blockIdx.x * SCAN_BLK + t * 4;
    int v0 = (base + 0 < M) ? in[base + 0] : 0;
    int v1 = (base + 1 < M) ? in[base + 1] : 0;
    int v2 = (base + 2 < M) ? in[base + 2] : 0;
    int v3 = (base + 3 < M) ? in[base + 3] : 0;
    const int s = v0 + v1 + v2 + v3;
    const int lane = t & 63, wid = t >> 6;
    int inc = s;
    for (int d = 1; d < 64; d <<= 1) {
        int u = __shfl_up(inc, d, 64);
        if (lane >= d) inc += u;
    }
    __shared__ int wsum[5];
    if (lane == 63) wsum[wid] = inc;
    __syncthreads();
    if (t == 0) {
        int a = 0;
        for (int w = 0; w < 4; ++w) { int u = wsum[w]; wsum[w] = a; a += u; }
        wsum[4] = a;
    }
    __syncthreads();
    const int ex = inc - s + wsum[wid];
    if (base + 0 < M) out[base + 0] = ex;
    if (base + 1 < M) out[base + 1] = ex + v0;
    if (base + 2 < M) out[base + 2] = ex + v0 + v1;
    if (base + 3 < M) out[base + 3] = ex + v0 + v1 + v2;
    if (t == 0) bsum[blockIdx.x] = wsum[4];
}

__global__ __launch_bounds__(1024) void scan2_kernel(int* __restrict__ bsum, int nb) {
    const int t = threadIdx.x;
    int s = (t < nb) ? bsum[t] : 0;
    const int lane = t & 63, wid = t >> 6;
    int inc = s;
    for (int d = 1; d < 64; d <<= 1) {
        int u = __shfl_up(inc, d, 64);
        if (lane >= d) inc += u;
    }
    __shared__ int wsum[16];
    if (lane == 63) wsum[wid] = inc;
    __syncthreads();
    if (t == 0) {
        int a = 0;
        for (int w = 0; w < 16; ++w) { int u = wsum[w]; wsum[w] = a; a += u; }
    }
    __syncthreads();
    const int ex = inc - s + wsum[wid];
    if (t < nb) bsum[t] = ex;
}

__global__ __launch_bounds__(256) void scan3_kernel(int* __restrict__ out,
                                                    const int* __restrict__ bsum, int M) {
    int i = blockIdx.x * 256 + threadIdx.x;
    if (i < M) out[i] += bsum[i / SCAN_BLK];
}

__global__ __launch_bounds__(256) void scatter_kernel(const int* __restrict__ src,
                                                      const int* __restrict__ dst,
                                                      const int* __restrict__ et,
                                                      int* __restrict__ off,
                                                      int* __restrict__ srcs, int E) {
    int e = blockIdx.x * 256 + threadIdx.x;
    if (e < E) {
        int seg = dst[e] * N_REL + et[e];
        int pos = atomicAdd(&off[seg], 1);
        srcs[pos] = src[e];
    }
}

// ---------------------------------------------------------------------------
// Dense: out[n][:] = bias + act(x[n]) @ root
// ---------------------------------------------------------------------------
template<bool RELU>
__global__ __launch_bounds__(256) void dense_kernel(const float* __restrict__ x,
                                                    const float* __restrict__ root,
                                                    const float* __restrict__ bias,
                                                    float* __restrict__ out, int Ntot) {
    __shared__ float root_sh[DIM * 64];
    __shared__ float x_sh[32 * DIM];

    const int jhalf = blockIdx.y;
    const int base  = blockIdx.x * 32;
    const int nn    = min(32, Ntot - base);

    for (int idx = threadIdx.x * 4; idx < DIM * 64; idx += 1024) {
        int row = idx >> 6, col = idx & 63;
        *(float4*)&root_sh[idx] = *(const float4*)&root[row * DIM + jhalf * 64 + col];
    }
    for (int idx = threadIdx.x * 4; idx < nn * DIM; idx += 1024) {
        float4 v = *(const float4*)&x[base * DIM + idx];
        if (RELU) {
            v.x = fmaxf(v.x, 0.f); v.y = fmaxf(v.y, 0.f);
            v.z = fmaxf(v.z, 0.f); v.w = fmaxf(v.w, 0.f);
        }
        *(float4*)&x_sh[idx] = v;
    }
    __syncthreads();

    const int jl   = threadIdx.x & 63;
    const int wave = threadIdx.x >> 6;
    const float bj = bias[jhalf * 64 + jl];

    for (int nl = wave; nl < nn; nl += 4) {
        float acc = bj;
#pragma unroll 16
        for (int k = 0; k < DIM; ++k)
            acc = fmaf(x_sh[nl * DIM + k], root_sh[k * 64 + jl], acc);
        out[(base + nl) * DIM + jhalf * 64 + jl] = acc;
    }
}

// ---------------------------------------------------------------------------
// allR GEMM: allR[rl][b][node][32] (bf16) = act(x[node][b*32..]) @ W[rbase+rl][b]
// Block: 256 thr / 64 nodes. Wave w handles relations rbase+w, +4, ...
// W read as wave-uniform scalars (same (i,o) sequence for all lanes).
// ---------------------------------------------------------------------------
template<bool RELU>
__global__ __launch_bounds__(256) void allr_kernel(const float* __restrict__ x,
                                                   const float* __restrict__ W,
                                                   ushort* __restrict__ allR,
                                                   int rbase, int rcount) {
    __shared__ float xsh[64 * 129];   // +1 pad: bank = (n + c) % 32, conflict-free
    const int base = blockIdx.x * 64;

    for (int idx = threadIdx.x; idx < 64 * DIM; idx += 256) {
        int row = idx >> 7, col = idx & 127;
        float v = (base + row < N_NODES) ? x[(size_t)(base + row) * DIM + col] : 0.f;
        if (RELU) v = fmaxf(v, 0.f);
        xsh[row * 129 + col] = v;
    }
    __syncthreads();

    const int nl   = threadIdx.x & 63;
    const int wv   = threadIdx.x >> 6;
    const int node = base + nl;

    for (int rr = wv; rr < rcount; rr += 4) {
        const int r = __builtin_amdgcn_readfirstlane(rbase + rr);
        for (int b = 0; b < NBLK; ++b) {
            const float* Wp = &W[(size_t)(r * NBLK + b) * (BS * BS)];
            float acc[32];
#pragma unroll
            for (int o = 0; o < 32; ++o) acc[o] = 0.f;
#pragma unroll 4
            for (int i = 0; i < BS; ++i) {
                const float xi = xsh[nl * 129 + b * BS + i];
#pragma unroll
                for (int o = 0; o < 32; ++o)
                    acc[o] = fmaf(xi, Wp[i * BS + o], acc[o]);
            }
            if (node < N_NODES) {
                unsigned int p[16];
#pragma unroll
                for (int j = 0; j < 16; ++j) {
                    __hip_bfloat16 lo = __float2bfloat16(acc[2 * j]);
                    __hip_bfloat16 hi = __float2bfloat16(acc[2 * j + 1]);
                    p[j] = ((unsigned int)*(unsigned short*)&hi << 16) |
                           (unsigned int)*(unsigned short*)&lo;
                }
                uint4* dst = (uint4*)(allR + ((size_t)(rr * NBLK + b) * N_NODES + node) * 32);
                dst[0] = make_uint4(p[0], p[1], p[2], p[3]);
                dst[1] = make_uint4(p[4], p[5], p[6], p[7]);
                dst[2] = make_uint4(p[8], p[9], p[10], p[11]);
                dst[3] = make_uint4(p[12], p[13], p[14], p[15]);
            }
        }
    }
}

// ---------------------------------------------------------------------------
// Aggregate: one half-wave per dst node; sum precomputed allR rows per
// (dst,rel) segment, scale by 1/c, RMW into out. No LDS, no matvec.
// Node's chunk edges are contiguous in CSR -> coalesced srcs window.
// ---------------------------------------------------------------------------
__global__ __launch_bounds__(256) void agg_allr_kernel(const int* __restrict__ srcs,
                                                       const int* __restrict__ off,
                                                       const int* __restrict__ cnt,
                                                       const ushort* __restrict__ allR,
                                                       float* __restrict__ out,
                                                       int rbase, int rcount) {
    const int hw = threadIdx.x >> 5;
    const int o  = threadIdx.x & 31;
    const int v  = blockIdx.x * 8 + hw;

    int endv = 0, cv = 0;
    if (o < rcount) {
        endv = off[v * N_REL + rbase + o];
        cv   = cnt[v * N_REL + rbase + o];
    }

    int wb = __shfl(endv - cv, 0, 32);                 // chunk edge-range start
    int sv = (wb + o < N_EDGES) ? srcs[wb + o] : 0;    // coalesced src window

    const int b = o >> 3;          // block column 0..3
    const int q = o & 7;           // 8 lanes cover one 64B row chunk
    float* op = &out[(size_t)v * DIM + b * BS + q * 4];
    float4 acc = *(const float4*)op;

    for (int rr = 0; rr < rcount; ++rr) {
        const int c = __shfl(cv, rr, 32);
        if (c == 0) continue;
        const int end = __shfl(endv, rr, 32);
        const ushort* cb = allR + (size_t)(rr * NBLK + b) * N_NODES * 32 + q * 4;
        float s0 = 0.f, s1 = 0.f, s2 = 0.f, s3 = 0.f;
        for (int k = end - c; k < end; ++k) {
            int d = k - wb;
            if (d >= 32) {             // slide window (uniform across half-wave)
                wb = k;
                sv = (wb + o < N_EDGES) ? srcs[wb + o] : 0;
                d = 0;
            }
            const int s = __shfl(sv, d, 32);
            ushort4 u = *(const ushort4*)(cb + (size_t)s * 32);
            s0 += bf2f(u.x); s1 += bf2f(u.y); s2 += bf2f(u.z); s3 += bf2f(u.w);
        }
        const float inv = 1.0f / (float)c;
        acc.x = fmaf(s0, inv, acc.x);
        acc.y = fmaf(s1, inv, acc.y);
        acc.z = fmaf(s2, inv, acc.z);
        acc.w = fmaf(s3, inv, acc.w);
    }
    *(float4*)op = acc;
}

// ---------------------------------------------------------------------------
// Fallback (ws too small for allR): round-2 gather-aggregate on x directly.
// ---------------------------------------------------------------------------
template<bool RELU>
__global__ __launch_bounds__(256) void agg_fallback_kernel(const int* __restrict__ srcs,
                                                           const int* __restrict__ off,
                                                           const int* __restrict__ cnt,
                                                           const float* __restrict__ x,
                                                           const float* __restrict__ W,
                                                           float* __restrict__ out) {
    __shared__ float Wsh[N_REL * BS * BS];
    const int bblk = blockIdx.y;
    for (int idx = threadIdx.x * 4; idx < N_REL * BS * BS; idx += 1024) {
        int r = idx >> 10, rest = idx & 1023;
        *(float4*)&Wsh[idx] = *(const float4*)&W[(r * NBLK + bblk) * 1024 + rest];
    }
    __syncthreads();
    const int hw = threadIdx.x >> 5;
    const int o  = threadIdx.x & 31;
    const int v  = blockIdx.x * 8 + hw;
    int endv = 0, cv = 0;
    if (o < N_REL) { endv = off[v * N_REL + o]; cv = cnt[v * N_REL + o]; }
    float acc = out[v * DIM + bblk * BS + o];
    for (int r = 0; r < N_REL; ++r) {
        const int c = __shfl(cv, r, 32);
        if (c == 0) continue;
        const int end = __shfl(endv, r, 32);
        float xs = 0.f;
        for (int k = end - c; k < end; ++k) {
            const int s = srcs[k];
            float xv = x[s * DIM + bblk * BS + o];
            if (RELU) xv = fmaxf(xv, 0.f);
            xs += xv;
        }
        xs *= (1.0f / (float)c);
        const float* wr = &Wsh[r * (BS * BS)];
#pragma unroll
        for (int i = 0; i < BS; i += 2) {
            float xi0 = __shfl(xs, i, 32);
            float xi1 = __shfl(xs, i + 1, 32);
            acc = fmaf(xi0, wr[i * BS + o], acc);
            acc = fmaf(xi1, wr[(i + 1) * BS + o], acc);
        }
    }
    out[v * DIM + bblk * BS + o] = acc;
}

// ---------------------------------------------------------------------------
extern "C" void kernel_launch(void* const* d_in, const int* in_sizes, int n_in,
                              void* d_out, int out_size, void* d_ws, size_t ws_size,
                              hipStream_t stream) {
    const int*   edge_index = (const int*)d_in[0];
    const int*   src   = edge_index;
    const int*   dstv  = edge_index + N_EDGES;
    const int*   et    = (const int*)d_in[1];
    const float* x0    = (const float*)d_in[2];
    const float* W1    = (const float*)d_in[3];
    const float* root1 = (const float*)d_in[4];
    const float* bias1 = (const float*)d_in[5];
    const float* W2    = (const float*)d_in[6];
    const float* root2 = (const float*)d_in[7];
    const float* bias2 = (const float*)d_in[8];
    float* out = (float*)d_out;

    // workspace layout
    float*  h    = (float*)d_ws;                        // 25.6 MB
    int*    cnt  = (int*)(h + (size_t)N_NODES * DIM);   // 3.2 MB
    int*    off  = cnt + NSEG;                          // 3.2 MB
    int*    srcs = off + NSEG;                          // 3.2 MB
    int*    bsum = srcs + N_EDGES;                      // scan sums (pad to 4KB)
    ushort* allR = (ushort*)((char*)d_ws + 35204096ull + 4096ull);

    const size_t fixed  = 35204096ull + 8192ull;
    const size_t perRel = (size_t)N_NODES * DIM * sizeof(ushort);  // 12.8 MB
    int rc = 0;
    if      (ws_size >= fixed + 16 * perRel) rc = 16;
    else if (ws_size >= fixed +  8 * perRel) rc = 8;
    else if (ws_size >= fixed +  4 * perRel) rc = 4;
    else if (ws_size >= fixed +  2 * perRel) rc = 2;
    else if (ws_size >= fixed +  1 * perRel) rc = 1;

    // ---- build CSR sorted by (dst, rel) ----
    hipMemsetAsync(cnt, 0, (size_t)NSEG * sizeof(int), stream);
    count_kernel<<<(N_EDGES + 255) / 256, 256, 0, stream>>>(dstv, et, cnt, N_EDGES);
    scan1_kernel<<<N_SCAN_BLKS, 256, 0, stream>>>(cnt, off, bsum, NSEG);
    scan2_kernel<<<1, 1024, 0, stream>>>(bsum, N_SCAN_BLKS);
    scan3_kernel<<<(NSEG + 255) / 256, 256, 0, stream>>>(off, bsum, NSEG);
    scatter_kernel<<<(N_EDGES + 255) / 256, 256, 0, stream>>>(src, dstv, et, off, srcs, N_EDGES);

    dim3 dgrid((N_NODES + 31) / 32, 2);
    const int ggrid = (N_NODES + 63) / 64;          // 782
    const int agrid = N_NODES / 8;                  // 6250

    if (rc > 0) {
        // ---- layer 1 ----
        dense_kernel<false><<<dgrid, 256, 0, stream>>>(x0, root1, bias1, h, N_NODES);
        for (int rb = 0; rb < N_REL; rb += rc) {
            allr_kernel<false><<<ggrid, 256, 0, stream>>>(x0, W1, allR, rb, rc);
            agg_allr_kernel<<<agrid, 256, 0, stream>>>(srcs, off, cnt, allR, h, rb, rc);
        }
        // ---- layer 2 ----
        dense_kernel<true><<<dgrid, 256, 0, stream>>>(h, root2, bias2, out, N_NODES);
        for (int rb = 0; rb < N_REL; rb += rc) {
            allr_kernel<true><<<ggrid, 256, 0, stream>>>(h, W2, allR, rb, rc);
            agg_allr_kernel<<<agrid, 256, 0, stream>>>(srcs, off, cnt, allR, out, rb, rc);
        }
    } else {
        dim3 fgrid(N_NODES / 8, NBLK);
        dense_kernel<false><<<dgrid, 256, 0, stream>>>(x0, root1, bias1, h, N_NODES);
        agg_fallback_kernel<false><<<fgrid, 256, 0, stream>>>(srcs, off, cnt, x0, W1, h);
        dense_kernel<true><<<dgrid, 256, 0, stream>>>(h, root2, bias2, out, N_NODES);
        agg_fallback_kernel<true><<<fgrid, 256, 0, stream>>>(srcs, off, cnt, h, W2, out);
    }
}

// Round 4
// 450.055 us; speedup vs baseline: 5.6647x; 1.8375x over previous
//
#include <hip/hip_runtime.h>
#include <hip/hip_bf16.h>

#define N_NODES 50000
#define N_REL   16
#define DIM     128
#define NBLK    4
#define BS      32
#define N_EDGES 800000
#define NSEG    (N_NODES * N_REL)
#define SCAN_BLK 1024
#define N_SCAN_BLKS ((NSEG + SCAN_BLK - 1) / SCAN_BLK)
#define NWT     (N_NODES / 16)        // 3125 wave-tiles of 16 nodes (exact)

typedef __attribute__((ext_vector_type(8))) short s8v;   // 8 bf16 (4 VGPRs)
typedef __attribute__((ext_vector_type(4))) float f4v;   // mfma C/D

__device__ __forceinline__ float bf2f(ushort u) {
    return __uint_as_float(((unsigned int)u) << 16);
}
// fp32 -> bf16 bits, round-to-nearest-even (inputs finite)
__device__ __forceinline__ unsigned short f2bfbits(float f) {
    unsigned int u = __float_as_uint(f);
    return (unsigned short)((u + 0x7fffu + ((u >> 16) & 1u)) >> 16);
}

// ---------------------------------------------------------------------------
// CSR build: count -> scan -> scatter
// ---------------------------------------------------------------------------
__global__ __launch_bounds__(256) void count_kernel(const int* __restrict__ dst,
                                                    const int* __restrict__ et,
                                                    int* __restrict__ cnt, int E) {
    int e = blockIdx.x * 256 + threadIdx.x;
    if (e < E) atomicAdd(&cnt[dst[e] * N_REL + et[e]], 1);
}

__global__ __launch_bounds__(256) void scan1_kernel(const int* __restrict__ in,
                                                    int* __restrict__ out,
                                                    int* __restrict__ bsum, int M) {
    const int t = threadIdx.x;
    const int base = blockIdx.x * SCAN_BLK + t * 4;
    int v0 = (base + 0 < M) ? in[base + 0] : 0;
    int v1 = (base + 1 < M) ? in[base + 1] : 0;
    int v2 = (base + 2 < M) ? in[base + 2] : 0;
    int v3 = (base + 3 < M) ? in[base + 3] : 0;
    const int s = v0 + v1 + v2 + v3;
    const int lane = t & 63, wid = t >> 6;
    int inc = s;
    for (int d = 1; d < 64; d <<= 1) {
        int u = __shfl_up(inc, d, 64);
        if (lane >= d) inc += u;
    }
    __shared__ int wsum[5];
    if (lane == 63) wsum[wid] = inc;
    __syncthreads();
    if (t == 0) {
        int a = 0;
        for (int w = 0; w < 4; ++w) { int u = wsum[w]; wsum[w] = a; a += u; }
        wsum[4] = a;
    }
    __syncthreads();
    const int ex = inc - s + wsum[wid];
    if (base + 0 < M) out[base + 0] = ex;
    if (base + 1 < M) out[base + 1] = ex + v0;
    if (base + 2 < M) out[base + 2] = ex + v0 + v1;
    if (base + 3 < M) out[base + 3] = ex + v0 + v1 + v2;
    if (t == 0) bsum[blockIdx.x] = wsum[4];
}

__global__ __launch_bounds__(1024) void scan2_kernel(int* __restrict__ bsum, int nb) {
    const int t = threadIdx.x;
    int s = (t < nb) ? bsum[t] : 0;
    const int lane = t & 63, wid = t >> 6;
    int inc = s;
    for (int d = 1; d < 64; d <<= 1) {
        int u = __shfl_up(inc, d, 64);
        if (lane >= d) inc += u;
    }
    __shared__ int wsum[16];
    if (lane == 63) wsum[wid] = inc;
    __syncthreads();
    if (t == 0) {
        int a = 0;
        for (int w = 0; w < 16; ++w) { int u = wsum[w]; wsum[w] = a; a += u; }
    }
    __syncthreads();
    const int ex = inc - s + wsum[wid];
    if (t < nb) bsum[t] = ex;
}

__global__ __launch_bounds__(256) void scan3_kernel(int* __restrict__ out,
                                                    const int* __restrict__ bsum, int M) {
    int i = blockIdx.x * 256 + threadIdx.x;
    if (i < M) out[i] += bsum[i / SCAN_BLK];
}

__global__ __launch_bounds__(256) void scatter_kernel(const int* __restrict__ src,
                                                      const int* __restrict__ dst,
                                                      const int* __restrict__ et,
                                                      int* __restrict__ off,
                                                      int* __restrict__ srcs, int E) {
    int e = blockIdx.x * 256 + threadIdx.x;
    if (e < E) {
        int seg = dst[e] * N_REL + et[e];
        int pos = atomicAdd(&off[seg], 1);
        srcs[pos] = src[e];
    }
}

// ---------------------------------------------------------------------------
// allR via MFMA. Per wave-tile: 16 nodes, one b (grid.y), all relations.
// D = W^T (A) * X^T (B): lane&15 = node, (lane>>4)*4+reg = out-col -> 8B store.
// A-frag: W[k=(l>>4)*8+i][m=mt*16+(l&15)] (L2-resident gathers).
// B-frag: x[nbase+(l&15)][b*32+(l>>4)*8+i] (16B-contig fp32 -> bf16).
// ---------------------------------------------------------------------------
template<bool RELU>
__global__ __launch_bounds__(256) void allr_mfma_kernel(const float* __restrict__ x,
                                                        const float* __restrict__ W,
                                                        ushort* __restrict__ allR,
                                                        int rbase, int rcount) {
    const int wv = threadIdx.x >> 6;
    const int l  = threadIdx.x & 63;
    const int wt = blockIdx.x * 4 + wv;
    if (wt >= NWT) return;
    const int b  = blockIdx.y;
    const int nbase = wt * 16;
    const int lm = l & 15;
    const int kg = l >> 4;
    const int node = nbase + lm;

    const float* xp = &x[(size_t)node * DIM + b * BS + kg * 8];
    s8v bfrag;
#pragma unroll
    for (int i = 0; i < 8; ++i) {
        float v = xp[i];
        if (RELU) v = fmaxf(v, 0.f);
        bfrag[i] = (short)f2bfbits(v);
    }

    ushort* outb = allR + (size_t)b * N_NODES * 32;
#pragma unroll 2
    for (int rr = 0; rr < rcount; ++rr) {
        const int r = rbase + rr;
        const float* wb = &W[(size_t)(r * NBLK + b) * (BS * BS)];
#pragma unroll
        for (int mt = 0; mt < 2; ++mt) {
            const float* wp = wb + (size_t)(kg * 8) * BS + mt * 16 + lm;
            s8v afrag;
#pragma unroll
            for (int i = 0; i < 8; ++i)
                afrag[i] = (short)f2bfbits(wp[i * BS]);
            f4v acc = {0.f, 0.f, 0.f, 0.f};
            acc = __builtin_amdgcn_mfma_f32_16x16x32_bf16(afrag, bfrag, acc, 0, 0, 0);
            unsigned int p0 = (unsigned int)f2bfbits(acc[0]) |
                              ((unsigned int)f2bfbits(acc[1]) << 16);
            unsigned int p1 = (unsigned int)f2bfbits(acc[2]) |
                              ((unsigned int)f2bfbits(acc[3]) << 16);
            uint2* dp = (uint2*)(outb + ((size_t)rr * NBLK * N_NODES + node) * 32
                                 + mt * 16 + kg * 4);
            *dp = make_uint2(p0, p1);
        }
    }
}

// ---------------------------------------------------------------------------
// Dense root GEMM via MFMA: out[n][:] = bias + act(x[n]) @ root.
// K=128 -> 4 chained mfma; bias rides in as C-in. fp32 out, dwordx4 stores.
// ---------------------------------------------------------------------------
template<bool RELU>
__global__ __launch_bounds__(256) void dense_mfma_kernel(const float* __restrict__ x,
                                                         const float* __restrict__ root,
                                                         const float* __restrict__ bias,
                                                         float* __restrict__ out) {
    const int wv = threadIdx.x >> 6;
    const int l  = threadIdx.x & 63;
    const int wt = blockIdx.x * 4 + wv;
    if (wt >= NWT) return;
    const int nbase = wt * 16;
    const int lm = l & 15;
    const int kg = l >> 4;
    const int node = nbase + lm;

    s8v bfr[4];
#pragma unroll
    for (int kc = 0; kc < 4; ++kc) {
        const float* xp = &x[(size_t)node * DIM + kc * BS + kg * 8];
#pragma unroll
        for (int i = 0; i < 8; ++i) {
            float v = xp[i];
            if (RELU) v = fmaxf(v, 0.f);
            bfr[kc][i] = (short)f2bfbits(v);
        }
    }
#pragma unroll 2
    for (int mt = 0; mt < 8; ++mt) {
        const int col0 = mt * 16 + kg * 4;
        f4v acc = *(const f4v*)&bias[col0];
#pragma unroll
        for (int kc = 0; kc < 4; ++kc) {
            const float* rp = &root[(size_t)(kc * BS + kg * 8) * DIM + mt * 16 + lm];
            s8v afrag;
#pragma unroll
            for (int i = 0; i < 8; ++i)
                afrag[i] = (short)f2bfbits(rp[i * DIM]);
            acc = __builtin_amdgcn_mfma_f32_16x16x32_bf16(afrag, bfr[kc], acc, 0, 0, 0);
        }
        *(f4v*)&out[(size_t)node * DIM + col0] = acc;
    }
}

// ---------------------------------------------------------------------------
// Aggregate (unchanged from round 3): one half-wave per dst node; windowed
// coalesced srcs prefetch; sums bf16 allR rows per segment; RMW into out.
// ---------------------------------------------------------------------------
__global__ __launch_bounds__(256) void agg_allr_kernel(const int* __restrict__ srcs,
                                                       const int* __restrict__ off,
                                                       const int* __restrict__ cnt,
                                                       const ushort* __restrict__ allR,
                                                       float* __restrict__ out,
                                                       int rbase, int rcount) {
    const int hw = threadIdx.x >> 5;
    const int o  = threadIdx.x & 31;
    const int v  = blockIdx.x * 8 + hw;

    int endv = 0, cv = 0;
    if (o < rcount) {
        endv = off[v * N_REL + rbase + o];
        cv   = cnt[v * N_REL + rbase + o];
    }

    int wb = __shfl(endv - cv, 0, 32);
    int sv = (wb + o < N_EDGES) ? srcs[wb + o] : 0;

    const int b = o >> 3;
    const int q = o & 7;
    float* op = &out[(size_t)v * DIM + b * BS + q * 4];
    float4 acc = *(const float4*)op;

    for (int rr = 0; rr < rcount; ++rr) {
        const int c = __shfl(cv, rr, 32);
        if (c == 0) continue;
        const int end = __shfl(endv, rr, 32);
        const ushort* cb = allR + (size_t)(rr * NBLK + b) * N_NODES * 32 + q * 4;
        float s0 = 0.f, s1 = 0.f, s2 = 0.f, s3 = 0.f;
        for (int k = end - c; k < end; ++k) {
            int d = k - wb;
            if (d >= 32) {
                wb = k;
                sv = (wb + o < N_EDGES) ? srcs[wb + o] : 0;
                d = 0;
            }
            const int s = __shfl(sv, d, 32);
            ushort4 u = *(const ushort4*)(cb + (size_t)s * 32);
            s0 += bf2f(u.x); s1 += bf2f(u.y); s2 += bf2f(u.z); s3 += bf2f(u.w);
        }
        const float inv = 1.0f / (float)c;
        acc.x = fmaf(s0, inv, acc.x);
        acc.y = fmaf(s1, inv, acc.y);
        acc.z = fmaf(s2, inv, acc.z);
        acc.w = fmaf(s3, inv, acc.w);
    }
    *(float4*)op = acc;
}

// ---------------------------------------------------------------------------
// Fallback (ws too small for allR): gather-aggregate on x directly.
// ---------------------------------------------------------------------------
template<bool RELU>
__global__ __launch_bounds__(256) void agg_fallback_kernel(const int* __restrict__ srcs,
                                                           const int* __restrict__ off,
                                                           const int* __restrict__ cnt,
                                                           const float* __restrict__ x,
                                                           const float* __restrict__ W,
                                                           float* __restrict__ out) {
    __shared__ float Wsh[N_REL * BS * BS];
    const int bblk = blockIdx.y;
    for (int idx = threadIdx.x * 4; idx < N_REL * BS * BS; idx += 1024) {
        int r = idx >> 10, rest = idx & 1023;
        *(float4*)&Wsh[idx] = *(const float4*)&W[(r * NBLK + bblk) * 1024 + rest];
    }
    __syncthreads();
    const int hw = threadIdx.x >> 5;
    const int o  = threadIdx.x & 31;
    const int v  = blockIdx.x * 8 + hw;
    int endv = 0, cv = 0;
    if (o < N_REL) { endv = off[v * N_REL + o]; cv = cnt[v * N_REL + o]; }
    float acc = out[v * DIM + bblk * BS + o];
    for (int r = 0; r < N_REL; ++r) {
        const int c = __shfl(cv, r, 32);
        if (c == 0) continue;
        const int end = __shfl(endv, r, 32);
        float xs = 0.f;
        for (int k = end - c; k < end; ++k) {
            const int s = srcs[k];
            float xv = x[s * DIM + bblk * BS + o];
            if (RELU) xv = fmaxf(xv, 0.f);
            xs += xv;
        }
        xs *= (1.0f / (float)c);
        const float* wr = &Wsh[r * (BS * BS)];
#pragma unroll
        for (int i = 0; i < BS; i += 2) {
            float xi0 = __shfl(xs, i, 32);
            float xi1 = __shfl(xs, i + 1, 32);
            acc = fmaf(xi0, wr[i * BS + o], acc);
            acc = fmaf(xi1, wr[(i + 1) * BS + o], acc);
        }
    }
    out[v * DIM + bblk * BS + o] = acc;
}

// ---------------------------------------------------------------------------
extern "C" void kernel_launch(void* const* d_in, const int* in_sizes, int n_in,
                              void* d_out, int out_size, void* d_ws, size_t ws_size,
                              hipStream_t stream) {
    const int*   edge_index = (const int*)d_in[0];
    const int*   src   = edge_index;
    const int*   dstv  = edge_index + N_EDGES;
    const int*   et    = (const int*)d_in[1];
    const float* x0    = (const float*)d_in[2];
    const float* W1    = (const float*)d_in[3];
    const float* root1 = (const float*)d_in[4];
    const float* bias1 = (const float*)d_in[5];
    const float* W2    = (const float*)d_in[6];
    const float* root2 = (const float*)d_in[7];
    const float* bias2 = (const float*)d_in[8];
    float* out = (float*)d_out;

    // workspace layout
    float*  h    = (float*)d_ws;                        // 25.6 MB
    int*    cnt  = (int*)(h + (size_t)N_NODES * DIM);   // 3.2 MB
    int*    off  = cnt + NSEG;                          // 3.2 MB
    int*    srcs = off + NSEG;                          // 3.2 MB
    int*    bsum = srcs + N_EDGES;                      // scan sums
    ushort* allR = (ushort*)((char*)d_ws + 35204096ull + 4096ull);

    const size_t fixed  = 35204096ull + 8192ull;
    const size_t perRel = (size_t)N_NODES * DIM * sizeof(ushort);  // 12.8 MB
    int rc = 0;
    if      (ws_size >= fixed + 16 * perRel) rc = 16;
    else if (ws_size >= fixed +  8 * perRel) rc = 8;
    else if (ws_size >= fixed +  4 * perRel) rc = 4;
    else if (ws_size >= fixed +  2 * perRel) rc = 2;
    else if (ws_size >= fixed +  1 * perRel) rc = 1;

    // ---- build CSR sorted by (dst, rel) ----
    hipMemsetAsync(cnt, 0, (size_t)NSEG * sizeof(int), stream);
    count_kernel<<<(N_EDGES + 255) / 256, 256, 0, stream>>>(dstv, et, cnt, N_EDGES);
    scan1_kernel<<<N_SCAN_BLKS, 256, 0, stream>>>(cnt, off, bsum, NSEG);
    scan2_kernel<<<1, 1024, 0, stream>>>(bsum, N_SCAN_BLKS);
    scan3_kernel<<<(NSEG + 255) / 256, 256, 0, stream>>>(off, bsum, NSEG);
    scatter_kernel<<<(N_EDGES + 255) / 256, 256, 0, stream>>>(src, dstv, et, off, srcs, N_EDGES);

    const int tgrid = (NWT + 3) / 4;                 // 782 (wave-tiles / 4)
    dim3 agrid_r(tgrid, NBLK);                       // allr: (782, 4)
    const int agrid = N_NODES / 8;                   // 6250

    if (rc > 0) {
        // ---- layer 1 ----
        dense_mfma_kernel<false><<<tgrid, 256, 0, stream>>>(x0, root1, bias1, h);
        for (int rb = 0; rb < N_REL; rb += rc) {
            allr_mfma_kernel<false><<<agrid_r, 256, 0, stream>>>(x0, W1, allR, rb, rc);
            agg_allr_kernel<<<agrid, 256, 0, stream>>>(srcs, off, cnt, allR, h, rb, rc);
        }
        // ---- layer 2 ----
        dense_mfma_kernel<true><<<tgrid, 256, 0, stream>>>(h, root2, bias2, out);
        for (int rb = 0; rb < N_REL; rb += rc) {
            allr_mfma_kernel<true><<<agrid_r, 256, 0, stream>>>(h, W2, allR, rb, rc);
            agg_allr_kernel<<<agrid, 256, 0, stream>>>(srcs, off, cnt, allR, out, rb, rc);
        }
    } else {
        dim3 fgrid(N_NODES / 8, NBLK);
        dense_mfma_kernel<false><<<tgrid, 256, 0, stream>>>(x0, root1, bias1, h);
        agg_fallback_kernel<false><<<fgrid, 256, 0, stream>>>(srcs, off, cnt, x0, W1, h);
        dense_mfma_kernel<true><<<tgrid, 256, 0, stream>>>(h, root2, bias2, out);
        agg_fallback_kernel<true><<<fgrid, 256, 0, stream>>>(srcs, off, cnt, h, W2, out);
    }
}

// Round 5
// 360.687 us; speedup vs baseline: 7.0683x; 1.2478x over previous
//
#include <hip/hip_runtime.h>
#include <hip/hip_bf16.h>

#define N_NODES 50000
#define N_REL   16
#define DIM     128
#define NBLK    4
#define BS      32
#define N_EDGES 800000
#define NSEG    (N_NODES * N_REL)
#define SCAN_BLK 1024
#define N_SCAN_BLKS ((NSEG + SCAN_BLK - 1) / SCAN_BLK)
#define NWT     (N_NODES / 16)        // 3125 wave-tiles of 16 nodes

typedef __attribute__((ext_vector_type(8))) short s8v;            // 8 bf16
typedef __attribute__((ext_vector_type(8))) unsigned short u8v;   // 8 bf16 bits
typedef __attribute__((ext_vector_type(4))) float f4v;            // mfma C/D

__device__ __forceinline__ float bf2f(unsigned short u) {
    return __uint_as_float(((unsigned int)u) << 16);
}
__device__ __forceinline__ unsigned short f2bfbits(float f) {   // RNE
    unsigned int u = __float_as_uint(f);
    return (unsigned short)((u + 0x7fffu + ((u >> 16) & 1u)) >> 16);
}

// ---------------------------------------------------------------------------
// CSR build: count -> scan -> scatter(evec = {gidx, inv})
// ---------------------------------------------------------------------------
__global__ __launch_bounds__(256) void count_kernel(const int* __restrict__ dst,
                                                    const int* __restrict__ et,
                                                    int* __restrict__ cnt, int E) {
    int e = blockIdx.x * 256 + threadIdx.x;
    if (e < E) atomicAdd(&cnt[dst[e] * N_REL + et[e]], 1);
}

__global__ __launch_bounds__(256) void scan1_kernel(const int* __restrict__ in,
                                                    int* __restrict__ out,
                                                    int* __restrict__ bsum, int M) {
    const int t = threadIdx.x;
    const int base = blockIdx.x * SCAN_BLK + t * 4;
    int v0 = (base + 0 < M) ? in[base + 0] : 0;
    int v1 = (base + 1 < M) ? in[base + 1] : 0;
    int v2 = (base + 2 < M) ? in[base + 2] : 0;
    int v3 = (base + 3 < M) ? in[base + 3] : 0;
    const int s = v0 + v1 + v2 + v3;
    const int lane = t & 63, wid = t >> 6;
    int inc = s;
    for (int d = 1; d < 64; d <<= 1) {
        int u = __shfl_up(inc, d, 64);
        if (lane >= d) inc += u;
    }
    __shared__ int wsum[5];
    if (lane == 63) wsum[wid] = inc;
    __syncthreads();
    if (t == 0) {
        int a = 0;
        for (int w = 0; w < 4; ++w) { int u = wsum[w]; wsum[w] = a; a += u; }
        wsum[4] = a;
    }
    __syncthreads();
    const int ex = inc - s + wsum[wid];
    if (base + 0 < M) out[base + 0] = ex;
    if (base + 1 < M) out[base + 1] = ex + v0;
    if (base + 2 < M) out[base + 2] = ex + v0 + v1;
    if (base + 3 < M) out[base + 3] = ex + v0 + v1 + v2;
    if (t == 0) bsum[blockIdx.x] = wsum[4];
}

__global__ __launch_bounds__(1024) void scan2_kernel(int* __restrict__ bsum, int nb) {
    const int t = threadIdx.x;
    int s = (t < nb) ? bsum[t] : 0;
    const int lane = t & 63, wid = t >> 6;
    int inc = s;
    for (int d = 1; d < 64; d <<= 1) {
        int u = __shfl_up(inc, d, 64);
        if (lane >= d) inc += u;
    }
    __shared__ int wsum[16];
    if (lane == 63) wsum[wid] = inc;
    __syncthreads();
    if (t == 0) {
        int a = 0;
        for (int w = 0; w < 16; ++w) { int u = wsum[w]; wsum[w] = a; a += u; }
    }
    __syncthreads();
    const int ex = inc - s + wsum[wid];
    if (t < nb) bsum[t] = ex;
}

__global__ __launch_bounds__(256) void scan3_kernel(int* __restrict__ out,
                                                    const int* __restrict__ bsum, int M) {
    int i = blockIdx.x * 256 + threadIdx.x;
    if (i < M) out[i] += bsum[i / SCAN_BLK];
}

// fast path: emit per-edge {gather-index, 1/c} in CSR position
__global__ __launch_bounds__(256) void scatter_fast_kernel(const int* __restrict__ src,
                                                           const int* __restrict__ dst,
                                                           const int* __restrict__ et,
                                                           int* __restrict__ off,
                                                           const int* __restrict__ cnt,
                                                           int2* __restrict__ evec, int E) {
    int e = blockIdx.x * 256 + threadIdx.x;
    if (e < E) {
        int r = et[e];
        int seg = dst[e] * N_REL + r;
        int pos = atomicAdd(&off[seg], 1);
        float inv = 1.0f / (float)cnt[seg];
        evec[pos] = make_int2(r * (NBLK * N_NODES) + src[e], __float_as_int(inv));
    }
}

// slow-fallback scatter (srcs list)
__global__ __launch_bounds__(256) void scatter_old_kernel(const int* __restrict__ src,
                                                          const int* __restrict__ dst,
                                                          const int* __restrict__ et,
                                                          int* __restrict__ off,
                                                          int* __restrict__ srcs, int E) {
    int e = blockIdx.x * 256 + threadIdx.x;
    if (e < E) {
        int seg = dst[e] * N_REL + et[e];
        int pos = atomicAdd(&off[seg], 1);
        srcs[pos] = src[e];
    }
}

// ---------------------------------------------------------------------------
// Prep: convert W1,W2,root1,root2 to bf16 in A-fragment lane order.
// WB idx = ((((r*4+b)*2+mt)*4+kg)*16+lm)*8+i  <- W[r][b][kg*8+i][mt*16+lm]
// RB idx = (((mt*4+kc)*4+kg)*16+lm)*8+i       <- root[kc*32+kg*8+i][mt*16+lm]
// ---------------------------------------------------------------------------
__global__ __launch_bounds__(256) void prep_kernel(const float* __restrict__ W1,
                                                   const float* __restrict__ W2,
                                                   const float* __restrict__ r1,
                                                   const float* __restrict__ r2,
                                                   ushort* __restrict__ WB1,
                                                   ushort* __restrict__ WB2,
                                                   ushort* __restrict__ RB1,
                                                   ushort* __restrict__ RB2) {
    int t = blockIdx.x * 256 + threadIdx.x;
    if (t < 262144) {                               // WB1 / WB2
        const float* W = (t < 131072) ? W1 : W2;
        ushort* WB     = (t < 131072) ? WB1 : WB2;
        int idx = t & 131071;
        int i  = idx & 7;
        int lm = (idx >> 3) & 15;
        int kg = (idx >> 7) & 3;
        int mt = (idx >> 9) & 1;
        int b  = (idx >> 10) & 3;
        int r  = idx >> 12;
        WB[idx] = f2bfbits(W[((size_t)(r * 4 + b) * 32 + kg * 8 + i) * 32 + mt * 16 + lm]);
    } else if (t < 294912) {                        // RB1 / RB2
        int u = t - 262144;
        const float* R = (u < 16384) ? r1 : r2;
        ushort* RB     = (u < 16384) ? RB1 : RB2;
        int idx = u & 16383;
        int i  = idx & 7;
        int lm = (idx >> 3) & 15;
        int kg = (idx >> 7) & 3;
        int kc = (idx >> 9) & 3;
        int mt = (idx >> 11) & 7;
        RB[idx] = f2bfbits(R[(size_t)(kc * 32 + kg * 8 + i) * DIM + mt * 16 + lm]);
    }
}

// ---------------------------------------------------------------------------
// allR via MFMA + LDS repack -> 1KB contiguous stores per (wave, rr).
// allR chunk layout: [(r*4+b)][node][32] bf16.
// ---------------------------------------------------------------------------
template<bool IN_BF16, bool RELU>
__global__ __launch_bounds__(256) void allr2_kernel(const void* __restrict__ xin,
                                                    const ushort* __restrict__ WB,
                                                    ushort* __restrict__ allR) {
    __shared__ ushort lsh[4][2][512];
    const int wv = threadIdx.x >> 6;
    const int l  = threadIdx.x & 63;
    const int wt = blockIdx.x * 4 + wv;
    if (wt >= NWT) return;
    const int b  = blockIdx.y;
    const int nbase = wt * 16;
    const int lm = l & 15;
    const int kg = l >> 4;
    const int node = nbase + lm;

    s8v bfrag;
    if (IN_BF16) {
        const ushort* xp = (const ushort*)xin + (size_t)node * DIM + b * BS + kg * 8;
        u8v u = *(const u8v*)xp;
#pragma unroll
        for (int i = 0; i < 8; ++i) {
            unsigned short us = u[i];
            if (RELU) us = (us & 0x8000u) ? (unsigned short)0 : us;
            bfrag[i] = (short)us;
        }
    } else {
        const float* xp = (const float*)xin + (size_t)node * DIM + b * BS + kg * 8;
#pragma unroll
        for (int i = 0; i < 8; ++i) {
            float v = xp[i];
            if (RELU) v = fmaxf(v, 0.f);
            bfrag[i] = (short)f2bfbits(v);
        }
    }

#pragma unroll 2
    for (int rr = 0; rr < N_REL; ++rr) {
        const int par = rr & 1;
#pragma unroll
        for (int mt = 0; mt < 2; ++mt) {
            s8v afrag = *(const s8v*)&WB[((((rr * 4 + b) * 2 + mt) * 4 + kg) * 16 + lm) * 8];
            f4v acc = {0.f, 0.f, 0.f, 0.f};
            acc = __builtin_amdgcn_mfma_f32_16x16x32_bf16(afrag, bfrag, acc, 0, 0, 0);
            unsigned int p0 = (unsigned int)f2bfbits(acc[0]) |
                              ((unsigned int)f2bfbits(acc[1]) << 16);
            unsigned int p1 = (unsigned int)f2bfbits(acc[2]) |
                              ((unsigned int)f2bfbits(acc[3]) << 16);
            *(uint2*)&lsh[wv][par][lm * 32 + mt * 16 + kg * 4] = make_uint2(p0, p1);
        }
        u8v row = *(u8v*)&lsh[wv][par][l * 8];
        *(u8v*)(allR + ((size_t)(rr * 4 + b) * N_NODES + nbase) * 32 + l * 8) = row;
    }
}

// ---------------------------------------------------------------------------
// Dense root GEMM via MFMA, pre-swizzled bf16 root.
// ---------------------------------------------------------------------------
template<bool IN_BF16, bool OUT_BF16, bool RELU>
__global__ __launch_bounds__(256) void dense_rb_kernel(const void* __restrict__ xin,
                                                       const ushort* __restrict__ RB,
                                                       const float* __restrict__ bias,
                                                       void* __restrict__ outv) {
    const int wv = threadIdx.x >> 6;
    const int l  = threadIdx.x & 63;
    const int wt = blockIdx.x * 4 + wv;
    if (wt >= NWT) return;
    const int nbase = wt * 16;
    const int lm = l & 15;
    const int kg = l >> 4;
    const int node = nbase + lm;

    s8v bfr[4];
#pragma unroll
    for (int kc = 0; kc < 4; ++kc) {
        if (IN_BF16) {
            const ushort* xp = (const ushort*)xin + (size_t)node * DIM + kc * BS + kg * 8;
            u8v u = *(const u8v*)xp;
#pragma unroll
            for (int i = 0; i < 8; ++i) {
                unsigned short us = u[i];
                if (RELU) us = (us & 0x8000u) ? (unsigned short)0 : us;
                bfr[kc][i] = (short)us;
            }
        } else {
            const float* xp = (const float*)xin + (size_t)node * DIM + kc * BS + kg * 8;
#pragma unroll
            for (int i = 0; i < 8; ++i) {
                float v = xp[i];
                if (RELU) v = fmaxf(v, 0.f);
                bfr[kc][i] = (short)f2bfbits(v);
            }
        }
    }
#pragma unroll 2
    for (int mt = 0; mt < 8; ++mt) {
        const int col0 = mt * 16 + kg * 4;
        f4v acc = *(const f4v*)&bias[col0];
#pragma unroll
        for (int kc = 0; kc < 4; ++kc) {
            s8v afrag = *(const s8v*)&RB[(((mt * 4 + kc) * 4 + kg) * 16 + lm) * 8];
            acc = __builtin_amdgcn_mfma_f32_16x16x32_bf16(afrag, bfr[kc], acc, 0, 0, 0);
        }
        if (OUT_BF16) {
            unsigned int p0 = (unsigned int)f2bfbits(acc[0]) |
                              ((unsigned int)f2bfbits(acc[1]) << 16);
            unsigned int p1 = (unsigned int)f2bfbits(acc[2]) |
                              ((unsigned int)f2bfbits(acc[3]) << 16);
            *(uint2*)((ushort*)outv + (size_t)node * DIM + col0) = make_uint2(p0, p1);
        } else {
            *(f4v*)((float*)outv + (size_t)node * DIM + col0) = acc;
        }
    }
}

// ---------------------------------------------------------------------------
// Edge-stream aggregate: half-wave per dst node walks its contiguous CSR
// window; per edge: gidx+inv from evec (windowed coalesced prefetch),
// 16B bf16 row-chunk loads, fma. 2 edges/iter. shfl_xor(16) combine, RMW.
// ---------------------------------------------------------------------------
template<bool OUT_BF16>
__global__ __launch_bounds__(256) void agg2_kernel(const int2* __restrict__ evec,
                                                   const int* __restrict__ off,
                                                   const ushort* __restrict__ allR,
                                                   void* __restrict__ outv) {
    const int hw = threadIdx.x >> 5;
    const int o  = threadIdx.x & 31;
    const int v  = blockIdx.x * 8 + hw;

    const int start = (v == 0) ? 0 : off[v * N_REL - 1];
    const int end   = off[v * N_REL + N_REL - 1];

    const int p   = o >> 4;          // edge parity (0/1)
    const int bq  = (o & 15) >> 2;   // block column
    const int sub = o & 3;           // 16B sub-chunk within 64B row

    float acc[8];
#pragma unroll
    for (int j = 0; j < 8; ++j) acc[j] = 0.f;

    int wb = start;
    int2 ev = evec[min(wb + o, N_EDGES - 1)];

    for (int base = start; base < end; base += 2) {
        if (base + 1 - wb >= 32) {
            wb += 32;
            ev = evec[min(wb + o, N_EDGES - 1)];
        }
        const int kk = base + p;
        const int d  = kk - wb;
        const int g  = __shfl(ev.x, d, 32);
        float inv    = __int_as_float(__shfl(ev.y, d, 32));
        if (kk >= end) inv = 0.f;
        const ushort* rp = allR + ((size_t)g + (size_t)bq * N_NODES) * 32 + sub * 8;
        u8v u = *(const u8v*)rp;
#pragma unroll
        for (int j = 0; j < 8; ++j)
            acc[j] = fmaf(bf2f(u[j]), inv, acc[j]);
    }
#pragma unroll
    for (int j = 0; j < 8; ++j)
        acc[j] += __shfl_xor(acc[j], 16, 32);

    if (o < 16) {
        const size_t boff = (size_t)v * DIM + o * 8;
        if (OUT_BF16) {
            ushort* hp = (ushort*)outv + boff;
            u8v hv = *(u8v*)hp;
#pragma unroll
            for (int j = 0; j < 8; ++j)
                hv[j] = f2bfbits(bf2f(hv[j]) + acc[j]);
            *(u8v*)hp = hv;
        } else {
            float* op = (float*)outv + boff;
            float4 r0 = *(float4*)op;
            float4 r1 = *(float4*)(op + 4);
            r0.x += acc[0]; r0.y += acc[1]; r0.z += acc[2]; r0.w += acc[3];
            r1.x += acc[4]; r1.y += acc[5]; r1.z += acc[6]; r1.w += acc[7];
            *(float4*)op = r0;
            *(float4*)(op + 4) = r1;
        }
    }
}

// ---------------------------------------------------------------------------
// Slow fallback (tiny ws): fp32 dense + gather-aggregate on x directly.
// ---------------------------------------------------------------------------
template<bool RELU>
__global__ __launch_bounds__(256) void dense_old_kernel(const float* __restrict__ x,
                                                        const float* __restrict__ root,
                                                        const float* __restrict__ bias,
                                                        float* __restrict__ out) {
    const int wv = threadIdx.x >> 6;
    const int l  = threadIdx.x & 63;
    const int wt = blockIdx.x * 4 + wv;
    if (wt >= NWT) return;
    const int nbase = wt * 16;
    const int lm = l & 15;
    const int kg = l >> 4;
    const int node = nbase + lm;

    s8v bfr[4];
#pragma unroll
    for (int kc = 0; kc < 4; ++kc) {
        const float* xp = &x[(size_t)node * DIM + kc * BS + kg * 8];
#pragma unroll
        for (int i = 0; i < 8; ++i) {
            float v = xp[i];
            if (RELU) v = fmaxf(v, 0.f);
            bfr[kc][i] = (short)f2bfbits(v);
        }
    }
#pragma unroll 2
    for (int mt = 0; mt < 8; ++mt) {
        const int col0 = mt * 16 + kg * 4;
        f4v acc = *(const f4v*)&bias[col0];
#pragma unroll
        for (int kc = 0; kc < 4; ++kc) {
            const float* rp = &root[(size_t)(kc * BS + kg * 8) * DIM + mt * 16 + lm];
            s8v afrag;
#pragma unroll
            for (int i = 0; i < 8; ++i)
                afrag[i] = (short)f2bfbits(rp[i * DIM]);
            acc = __builtin_amdgcn_mfma_f32_16x16x32_bf16(afrag, bfr[kc], acc, 0, 0, 0);
        }
        *(f4v*)&out[(size_t)node * DIM + col0] = acc;
    }
}

template<bool RELU>
__global__ __launch_bounds__(256) void agg_fallback_kernel(const int* __restrict__ srcs,
                                                           const int* __restrict__ off,
                                                           const int* __restrict__ cnt,
                                                           const float* __restrict__ x,
                                                           const float* __restrict__ W,
                                                           float* __restrict__ out) {
    __shared__ float Wsh[N_REL * BS * BS];
    const int bblk = blockIdx.y;
    for (int idx = threadIdx.x * 4; idx < N_REL * BS * BS; idx += 1024) {
        int r = idx >> 10, rest = idx & 1023;
        *(float4*)&Wsh[idx] = *(const float4*)&W[(r * NBLK + bblk) * 1024 + rest];
    }
    __syncthreads();
    const int hw = threadIdx.x >> 5;
    const int o  = threadIdx.x & 31;
    const int v  = blockIdx.x * 8 + hw;
    int endv = 0, cv = 0;
    if (o < N_REL) { endv = off[v * N_REL + o]; cv = cnt[v * N_REL + o]; }
    float acc = out[v * DIM + bblk * BS + o];
    for (int r = 0; r < N_REL; ++r) {
        const int c = __shfl(cv, r, 32);
        if (c == 0) continue;
        const int end = __shfl(endv, r, 32);
        float xs = 0.f;
        for (int k = end - c; k < end; ++k) {
            const int s = srcs[k];
            float xv = x[s * DIM + bblk * BS + o];
            if (RELU) xv = fmaxf(xv, 0.f);
            xs += xv;
        }
        xs *= (1.0f / (float)c);
        const float* wr = &Wsh[r * (BS * BS)];
#pragma unroll
        for (int i = 0; i < BS; i += 2) {
            float xi0 = __shfl(xs, i, 32);
            float xi1 = __shfl(xs, i + 1, 32);
            acc = fmaf(xi0, wr[i * BS + o], acc);
            acc = fmaf(xi1, wr[(i + 1) * BS + o], acc);
        }
    }
    out[v * DIM + bblk * BS + o] = acc;
}

// ---------------------------------------------------------------------------
extern "C" void kernel_launch(void* const* d_in, const int* in_sizes, int n_in,
                              void* d_out, int out_size, void* d_ws, size_t ws_size,
                              hipStream_t stream) {
    const int*   edge_index = (const int*)d_in[0];
    const int*   src   = edge_index;
    const int*   dstv  = edge_index + N_EDGES;
    const int*   et    = (const int*)d_in[1];
    const float* x0    = (const float*)d_in[2];
    const float* W1    = (const float*)d_in[3];
    const float* root1 = (const float*)d_in[4];
    const float* bias1 = (const float*)d_in[5];
    const float* W2    = (const float*)d_in[6];
    const float* root2 = (const float*)d_in[7];
    const float* bias2 = (const float*)d_in[8];
    float* out = (float*)d_out;

    // ---- fast-path workspace layout (231.0 MB total) ----
    char* ws = (char*)d_ws;
    ushort* h    = (ushort*)ws;                             // 12,800,000 (bf16)
    int*    cnt  = (int*)   (ws + 12800000);                //  3,200,000
    int*    off  = (int*)   (ws + 16000000);                //  3,200,000
    int2*   evec = (int2*)  (ws + 19200000);                //  6,400,000
    int*    bsum = (int*)   (ws + 25600000);                //      4,096
    ushort* WB1  = (ushort*)(ws + 25604096);                //    262,144
    ushort* WB2  = (ushort*)(ws + 25866240);                //    262,144
    ushort* RB1  = (ushort*)(ws + 26128384);                //     32,768
    ushort* RB2  = (ushort*)(ws + 26161152);                //     32,768
    ushort* allR = (ushort*)(ws + 26193920);                // 204,800,000
    const size_t FAST_NEED = 230993920ull;

    const int egrid = (N_EDGES + 255) / 256;     // 3125
    const int tgrid = (NWT + 3) / 4;             // 782

    if (ws_size >= FAST_NEED) {
        prep_kernel<<<1152, 256, 0, stream>>>(W1, W2, root1, root2, WB1, WB2, RB1, RB2);
        hipMemsetAsync(cnt, 0, (size_t)NSEG * sizeof(int), stream);
        count_kernel<<<egrid, 256, 0, stream>>>(dstv, et, cnt, N_EDGES);
        scan1_kernel<<<N_SCAN_BLKS, 256, 0, stream>>>(cnt, off, bsum, NSEG);
        scan2_kernel<<<1, 1024, 0, stream>>>(bsum, N_SCAN_BLKS);
        scan3_kernel<<<(NSEG + 255) / 256, 256, 0, stream>>>(off, bsum, NSEG);
        scatter_fast_kernel<<<egrid, 256, 0, stream>>>(src, dstv, et, off, cnt, evec, N_EDGES);

        dim3 agrid_r(tgrid, NBLK);
        const int ngrid = N_NODES / 8;           // 6250

        // ---- layer 1: h(bf16) = x0@root1 + bias1 ; += messages ----
        dense_rb_kernel<false, true, false><<<tgrid, 256, 0, stream>>>(x0, RB1, bias1, h);
        allr2_kernel<false, false><<<agrid_r, 256, 0, stream>>>(x0, WB1, allR);
        agg2_kernel<true><<<ngrid, 256, 0, stream>>>(evec, off, allR, h);

        // ---- layer 2: out(fp32) = relu(h)@root2 + bias2 ; += messages ----
        dense_rb_kernel<true, false, true><<<tgrid, 256, 0, stream>>>(h, RB2, bias2, out);
        allr2_kernel<true, true><<<agrid_r, 256, 0, stream>>>(h, WB2, allR);
        agg2_kernel<false><<<ngrid, 256, 0, stream>>>(evec, off, allR, out);
    } else {
        // ---- slow fallback (ws >= 35.3 MB): fp32 h + direct gather-agg ----
        float* hf    = (float*)d_ws;
        int*   cntf  = (int*)((char*)d_ws + 25600000);
        int*   offf  = (int*)((char*)d_ws + 28800000);
        int*   srcsf = (int*)((char*)d_ws + 32000000);
        int*   bsumf = (int*)((char*)d_ws + 35200000);

        hipMemsetAsync(cntf, 0, (size_t)NSEG * sizeof(int), stream);
        count_kernel<<<egrid, 256, 0, stream>>>(dstv, et, cntf, N_EDGES);
        scan1_kernel<<<N_SCAN_BLKS, 256, 0, stream>>>(cntf, offf, bsumf, NSEG);
        scan2_kernel<<<1, 1024, 0, stream>>>(bsumf, N_SCAN_BLKS);
        scan3_kernel<<<(NSEG + 255) / 256, 256, 0, stream>>>(offf, bsumf, NSEG);
        scatter_old_kernel<<<egrid, 256, 0, stream>>>(src, dstv, et, offf, srcsf, N_EDGES);

        dim3 fgrid(N_NODES / 8, NBLK);
        dense_old_kernel<false><<<tgrid, 256, 0, stream>>>(x0, root1, bias1, hf);
        agg_fallback_kernel<false><<<fgrid, 256, 0, stream>>>(srcsf, offf, cntf, x0, W1, hf);
        dense_old_kernel<true><<<tgrid, 256, 0, stream>>>(hf, root2, bias2, out);
        agg_fallback_kernel<true><<<fgrid, 256, 0, stream>>>(srcsf, offf, cntf, hf, W2, out);
    }
}

// Round 6
// 288.844 us; speedup vs baseline: 8.8263x; 1.2487x over previous
//
#include <hip/hip_runtime.h>
#include <hip/hip_bf16.h>

#define N_NODES 50000
#define N_REL   16
#define DIM     128
#define NBLK    4
#define BS      32
#define N_EDGES 800000
#define NSEG    (N_NODES * N_REL)
#define SCAN_BLK 1024
#define N_SCAN_BLKS ((NSEG + SCAN_BLK - 1) / SCAN_BLK)
#define NWT     (N_NODES / 16)        // 3125 wave-tiles of 16 nodes

typedef __attribute__((ext_vector_type(8))) short s8v;            // 8 bf16
typedef __attribute__((ext_vector_type(8))) unsigned short u8v;   // 8 bf16 bits
typedef __attribute__((ext_vector_type(4))) float f4v;            // mfma C/D

__device__ __forceinline__ float bf2f(unsigned short u) {
    return __uint_as_float(((unsigned int)u) << 16);
}
__device__ __forceinline__ unsigned short f2bfbits(float f) {   // RNE
    unsigned int u = __float_as_uint(f);
    return (unsigned short)((u + 0x7fffu + ((u >> 16) & 1u)) >> 16);
}

// ---------------------------------------------------------------------------
// CSR build: count -> scan -> scatter(evec = {gidx, inv})
// ---------------------------------------------------------------------------
__global__ __launch_bounds__(256) void count_kernel(const int* __restrict__ dst,
                                                    const int* __restrict__ et,
                                                    int* __restrict__ cnt, int E) {
    int e = blockIdx.x * 256 + threadIdx.x;
    if (e < E) atomicAdd(&cnt[dst[e] * N_REL + et[e]], 1);
}

__global__ __launch_bounds__(256) void scan1_kernel(const int* __restrict__ in,
                                                    int* __restrict__ out,
                                                    int* __restrict__ bsum, int M) {
    const int t = threadIdx.x;
    const int base = blockIdx.x * SCAN_BLK + t * 4;
    int v0 = (base + 0 < M) ? in[base + 0] : 0;
    int v1 = (base + 1 < M) ? in[base + 1] : 0;
    int v2 = (base + 2 < M) ? in[base + 2] : 0;
    int v3 = (base + 3 < M) ? in[base + 3] : 0;
    const int s = v0 + v1 + v2 + v3;
    const int lane = t & 63, wid = t >> 6;
    int inc = s;
    for (int d = 1; d < 64; d <<= 1) {
        int u = __shfl_up(inc, d, 64);
        if (lane >= d) inc += u;
    }
    __shared__ int wsum[5];
    if (lane == 63) wsum[wid] = inc;
    __syncthreads();
    if (t == 0) {
        int a = 0;
        for (int w = 0; w < 4; ++w) { int u = wsum[w]; wsum[w] = a; a += u; }
        wsum[4] = a;
    }
    __syncthreads();
    const int ex = inc - s + wsum[wid];
    if (base + 0 < M) out[base + 0] = ex;
    if (base + 1 < M) out[base + 1] = ex + v0;
    if (base + 2 < M) out[base + 2] = ex + v0 + v1;
    if (base + 3 < M) out[base + 3] = ex + v0 + v1 + v2;
    if (t == 0) bsum[blockIdx.x] = wsum[4];
}

__global__ __launch_bounds__(1024) void scan2_kernel(int* __restrict__ bsum, int nb) {
    const int t = threadIdx.x;
    int s = (t < nb) ? bsum[t] : 0;
    const int lane = t & 63, wid = t >> 6;
    int inc = s;
    for (int d = 1; d < 64; d <<= 1) {
        int u = __shfl_up(inc, d, 64);
        if (lane >= d) inc += u;
    }
    __shared__ int wsum[16];
    if (lane == 63) wsum[wid] = inc;
    __syncthreads();
    if (t == 0) {
        int a = 0;
        for (int w = 0; w < 16; ++w) { int u = wsum[w]; wsum[w] = a; a += u; }
    }
    __syncthreads();
    const int ex = inc - s + wsum[wid];
    if (t < nb) bsum[t] = ex;
}

__global__ __launch_bounds__(256) void scan3_kernel(int* __restrict__ out,
                                                    const int* __restrict__ bsum, int M) {
    int i = blockIdx.x * 256 + threadIdx.x;
    if (i < M) out[i] += bsum[i / SCAN_BLK];
}

// fast path: emit per-edge {gather-row, 1/c} in CSR position; row = r*N + src
__global__ __launch_bounds__(256) void scatter_fast_kernel(const int* __restrict__ src,
                                                           const int* __restrict__ dst,
                                                           const int* __restrict__ et,
                                                           int* __restrict__ off,
                                                           const int* __restrict__ cnt,
                                                           int2* __restrict__ evec, int E) {
    int e = blockIdx.x * 256 + threadIdx.x;
    if (e < E) {
        int r = et[e];
        int seg = dst[e] * N_REL + r;
        int pos = atomicAdd(&off[seg], 1);
        float inv = 1.0f / (float)cnt[seg];
        evec[pos] = make_int2(r * N_NODES + src[e], __float_as_int(inv));
    }
}

// slow-fallback scatter (srcs list)
__global__ __launch_bounds__(256) void scatter_old_kernel(const int* __restrict__ src,
                                                          const int* __restrict__ dst,
                                                          const int* __restrict__ et,
                                                          int* __restrict__ off,
                                                          int* __restrict__ srcs, int E) {
    int e = blockIdx.x * 256 + threadIdx.x;
    if (e < E) {
        int seg = dst[e] * N_REL + et[e];
        int pos = atomicAdd(&off[seg], 1);
        srcs[pos] = src[e];
    }
}

// ---------------------------------------------------------------------------
// Prep: convert W1,W2,root1,root2 to bf16 in A-fragment lane order.
// WB idx = ((((r*4+b)*2+mt)*4+kg)*16+lm)*8+i  <- W[r][b][kg*8+i][mt*16+lm]
// RB idx = (((mt*4+kc)*4+kg)*16+lm)*8+i       <- root[kc*32+kg*8+i][mt*16+lm]
// ---------------------------------------------------------------------------
__global__ __launch_bounds__(256) void prep_kernel(const float* __restrict__ W1,
                                                   const float* __restrict__ W2,
                                                   const float* __restrict__ r1,
                                                   const float* __restrict__ r2,
                                                   ushort* __restrict__ WB1,
                                                   ushort* __restrict__ WB2,
                                                   ushort* __restrict__ RB1,
                                                   ushort* __restrict__ RB2) {
    int t = blockIdx.x * 256 + threadIdx.x;
    if (t < 262144) {                               // WB1 / WB2
        const float* W = (t < 131072) ? W1 : W2;
        ushort* WB     = (t < 131072) ? WB1 : WB2;
        int idx = t & 131071;
        int i  = idx & 7;
        int lm = (idx >> 3) & 15;
        int kg = (idx >> 7) & 3;
        int mt = (idx >> 9) & 1;
        int b  = (idx >> 10) & 3;
        int r  = idx >> 12;
        WB[idx] = f2bfbits(W[((size_t)(r * 4 + b) * 32 + kg * 8 + i) * 32 + mt * 16 + lm]);
    } else if (t < 294912) {                        // RB1 / RB2
        int u = t - 262144;
        const float* R = (u < 16384) ? r1 : r2;
        ushort* RB     = (u < 16384) ? RB1 : RB2;
        int idx = u & 16383;
        int i  = idx & 7;
        int lm = (idx >> 3) & 15;
        int kg = (idx >> 7) & 3;
        int kc = (idx >> 9) & 3;
        int mt = (idx >> 11) & 7;
        RB[idx] = f2bfbits(R[(size_t)(kc * 32 + kg * 8 + i) * DIM + mt * 16 + lm]);
    }
}

// ---------------------------------------------------------------------------
// allR transform -> per-row-scaled int8 table, layout [r][node][128].
// Wave tile: 16 nodes, 4 relations (blockIdx.y = rel group). Per (rr):
// 8 MFMA (4 b x 2 mt) -> 32 f32/lane (all for node lm); rowmax via
// in-lane max + shfl_xor over kg lanes; quantize; LDS repack (stride-33
// dwords, <=2-way banks); 2KB contiguous store + 16 scales.
// ---------------------------------------------------------------------------
template<bool IN_BF16, bool RELU>
__global__ __launch_bounds__(256) void allr8_kernel(const void* __restrict__ xin,
                                                    const ushort* __restrict__ WB,
                                                    char* __restrict__ tab,
                                                    float* __restrict__ scl) {
    __shared__ unsigned int lsh[4][16 * 33];    // per-wave 16 nodes x 32+1 dwords
    const int wv = threadIdx.x >> 6;
    const int l  = threadIdx.x & 63;
    const int wt = blockIdx.x * 4 + wv;
    if (wt >= NWT) return;
    const int rg = blockIdx.y;                  // relation group 0..3
    const int nbase = wt * 16;
    const int lm = l & 15;
    const int kg = l >> 4;
    const int node = nbase + lm;

    // load B-fragments for all 4 blocks (x row of node lm)
    s8v bfr[4];
#pragma unroll
    for (int b = 0; b < 4; ++b) {
        if (IN_BF16) {
            const ushort* xp = (const ushort*)xin + (size_t)node * DIM + b * BS + kg * 8;
            u8v u = *(const u8v*)xp;
#pragma unroll
            for (int i = 0; i < 8; ++i) {
                unsigned short us = u[i];
                if (RELU) us = (us & 0x8000u) ? (unsigned short)0 : us;
                bfr[b][i] = (short)us;
            }
        } else {
            const float* xp = (const float*)xin + (size_t)node * DIM + b * BS + kg * 8;
#pragma unroll
            for (int i = 0; i < 8; ++i) {
                float v = xp[i];
                if (RELU) v = fmaxf(v, 0.f);
                bfr[b][i] = (short)f2bfbits(v);
            }
        }
    }

    for (int ri = 0; ri < 4; ++ri) {
        const int rr = rg * 4 + ri;
        f4v acc[4][2];
#pragma unroll
        for (int b = 0; b < 4; ++b) {
#pragma unroll
            for (int mt = 0; mt < 2; ++mt) {
                s8v afrag = *(const s8v*)&WB[((((rr * 4 + b) * 2 + mt) * 4 + kg) * 16 + lm) * 8];
                f4v a = {0.f, 0.f, 0.f, 0.f};
                acc[b][mt] = __builtin_amdgcn_mfma_f32_16x16x32_bf16(afrag, bfr[b], a, 0, 0, 0);
            }
        }
        // rowmax over the node's 128 values (32 in-lane + across 4 kg lanes)
        float m = 0.f;
#pragma unroll
        for (int b = 0; b < 4; ++b)
#pragma unroll
            for (int mt = 0; mt < 2; ++mt)
#pragma unroll
                for (int j = 0; j < 4; ++j)
                    m = fmaxf(m, fabsf(acc[b][mt][j]));
        m = fmaxf(m, __shfl_xor(m, 16, 64));
        m = fmaxf(m, __shfl_xor(m, 32, 64));
        m = fmaxf(m, 1e-30f);
        const float qs  = 127.0f / m;
        const float s   = m * (1.0f / 127.0f);

        // quantize + pack 4 bytes per (b,mt) -> LDS
#pragma unroll
        for (int b = 0; b < 4; ++b) {
#pragma unroll
            for (int mt = 0; mt < 2; ++mt) {
                unsigned int pk = 0;
#pragma unroll
                for (int j = 0; j < 4; ++j) {
                    int q = __float2int_rn(acc[b][mt][j] * qs);
                    q = max(-127, min(127, q));
                    pk |= ((unsigned int)(q & 0xff)) << (8 * j);
                }
                lsh[wv][lm * 33 + b * 8 + mt * 4 + kg] = pk;
            }
        }
        // repack: lane l -> node l>>2, dwords (l&3)*8 .. +7 (32B contiguous)
        const int rn = l >> 2, rq = l & 3;
        unsigned int d0[4], d1[4];
#pragma unroll
        for (int k = 0; k < 4; ++k) d0[k] = lsh[wv][rn * 33 + rq * 8 + k];
#pragma unroll
        for (int k = 0; k < 4; ++k) d1[k] = lsh[wv][rn * 33 + rq * 8 + 4 + k];
        char* gp = tab + ((size_t)rr * N_NODES + nbase) * 128 + l * 32;
        *(uint4*)gp        = make_uint4(d0[0], d0[1], d0[2], d0[3]);
        *(uint4*)(gp + 16) = make_uint4(d1[0], d1[1], d1[2], d1[3]);
        if (l < 16) scl[rr * N_NODES + nbase + l] = s;
    }
}

// ---------------------------------------------------------------------------
// Dense root GEMM via MFMA, pre-swizzled bf16 root.
// ---------------------------------------------------------------------------
template<bool IN_BF16, bool OUT_BF16, bool RELU>
__global__ __launch_bounds__(256) void dense_rb_kernel(const void* __restrict__ xin,
                                                       const ushort* __restrict__ RB,
                                                       const float* __restrict__ bias,
                                                       void* __restrict__ outv) {
    const int wv = threadIdx.x >> 6;
    const int l  = threadIdx.x & 63;
    const int wt = blockIdx.x * 4 + wv;
    if (wt >= NWT) return;
    const int nbase = wt * 16;
    const int lm = l & 15;
    const int kg = l >> 4;
    const int node = nbase + lm;

    s8v bfr[4];
#pragma unroll
    for (int kc = 0; kc < 4; ++kc) {
        if (IN_BF16) {
            const ushort* xp = (const ushort*)xin + (size_t)node * DIM + kc * BS + kg * 8;
            u8v u = *(const u8v*)xp;
#pragma unroll
            for (int i = 0; i < 8; ++i) {
                unsigned short us = u[i];
                if (RELU) us = (us & 0x8000u) ? (unsigned short)0 : us;
                bfr[kc][i] = (short)us;
            }
        } else {
            const float* xp = (const float*)xin + (size_t)node * DIM + kc * BS + kg * 8;
#pragma unroll
            for (int i = 0; i < 8; ++i) {
                float v = xp[i];
                if (RELU) v = fmaxf(v, 0.f);
                bfr[kc][i] = (short)f2bfbits(v);
            }
        }
    }
#pragma unroll 2
    for (int mt = 0; mt < 8; ++mt) {
        const int col0 = mt * 16 + kg * 4;
        f4v acc = *(const f4v*)&bias[col0];
#pragma unroll
        for (int kc = 0; kc < 4; ++kc) {
            s8v afrag = *(const s8v*)&RB[(((mt * 4 + kc) * 4 + kg) * 16 + lm) * 8];
            acc = __builtin_amdgcn_mfma_f32_16x16x32_bf16(afrag, bfr[kc], acc, 0, 0, 0);
        }
        if (OUT_BF16) {
            unsigned int p0 = (unsigned int)f2bfbits(acc[0]) |
                              ((unsigned int)f2bfbits(acc[1]) << 16);
            unsigned int p1 = (unsigned int)f2bfbits(acc[2]) |
                              ((unsigned int)f2bfbits(acc[3]) << 16);
            *(uint2*)((ushort*)outv + (size_t)node * DIM + col0) = make_uint2(p0, p1);
        } else {
            *(f4v*)((float*)outv + (size_t)node * DIM + col0) = acc;
        }
    }
}

// ---------------------------------------------------------------------------
// Edge-stream aggregate over int8 table: half-wave per dst node, windowed
// evec prefetch; per edge one 128B contiguous row read + 1 scale; dequant
// with (inv * scale); 2 edges/iter; shfl_xor(16) combine; RMW into out.
// ---------------------------------------------------------------------------
template<bool OUT_BF16>
__global__ __launch_bounds__(256) void agg8_kernel(const int2* __restrict__ evec,
                                                   const int* __restrict__ off,
                                                   const char* __restrict__ tab,
                                                   const float* __restrict__ scl,
                                                   void* __restrict__ outv) {
    const int hw = threadIdx.x >> 5;
    const int o  = threadIdx.x & 31;
    const int v  = blockIdx.x * 8 + hw;

    const int start = (v == 0) ? 0 : off[v * N_REL - 1];
    const int end   = off[v * N_REL + N_REL - 1];

    const int p = o >> 4;            // edge parity (0/1)
    const int w = o & 15;            // 8-byte sub-chunk -> dims w*8..w*8+7

    float acc[8];
#pragma unroll
    for (int j = 0; j < 8; ++j) acc[j] = 0.f;

    int wb = start;
    int2 ev = evec[min(wb + o, N_EDGES - 1)];

    for (int base = start; base < end; base += 2) {
        if (base + 1 - wb >= 32) {
            wb += 32;
            ev = evec[min(wb + o, N_EDGES - 1)];
        }
        const int kk = base + p;
        const int d  = kk - wb;
        const int g  = __shfl(ev.x, d, 32);
        float inv    = __int_as_float(__shfl(ev.y, d, 32));
        if (kk >= end) inv = 0.f;
        const float invs = inv * scl[g];
        uint2 q = *(const uint2*)(tab + (size_t)g * 128 + w * 8);
#pragma unroll
        for (int j = 0; j < 4; ++j) {
            int b0 = (int)(signed char)((q.x >> (8 * j)) & 0xff);
            acc[j] = fmaf((float)b0, invs, acc[j]);
        }
#pragma unroll
        for (int j = 0; j < 4; ++j) {
            int b1 = (int)(signed char)((q.y >> (8 * j)) & 0xff);
            acc[4 + j] = fmaf((float)b1, invs, acc[4 + j]);
        }
    }
#pragma unroll
    for (int j = 0; j < 8; ++j)
        acc[j] += __shfl_xor(acc[j], 16, 32);

    if (o < 16) {
        const size_t boff = (size_t)v * DIM + o * 8;
        if (OUT_BF16) {
            ushort* hp = (ushort*)outv + boff;
            u8v hv = *(u8v*)hp;
#pragma unroll
            for (int j = 0; j < 8; ++j)
                hv[j] = f2bfbits(bf2f(hv[j]) + acc[j]);
            *(u8v*)hp = hv;
        } else {
            float* op = (float*)outv + boff;
            float4 r0 = *(float4*)op;
            float4 r1 = *(float4*)(op + 4);
            r0.x += acc[0]; r0.y += acc[1]; r0.z += acc[2]; r0.w += acc[3];
            r1.x += acc[4]; r1.y += acc[5]; r1.z += acc[6]; r1.w += acc[7];
            *(float4*)op = r0;
            *(float4*)(op + 4) = r1;
        }
    }
}

// ---------------------------------------------------------------------------
// Slow fallback (tiny ws): fp32 dense + gather-aggregate on x directly.
// ---------------------------------------------------------------------------
template<bool RELU>
__global__ __launch_bounds__(256) void dense_old_kernel(const float* __restrict__ x,
                                                        const float* __restrict__ root,
                                                        const float* __restrict__ bias,
                                                        float* __restrict__ out) {
    const int wv = threadIdx.x >> 6;
    const int l  = threadIdx.x & 63;
    const int wt = blockIdx.x * 4 + wv;
    if (wt >= NWT) return;
    const int nbase = wt * 16;
    const int lm = l & 15;
    const int kg = l >> 4;
    const int node = nbase + lm;

    s8v bfr[4];
#pragma unroll
    for (int kc = 0; kc < 4; ++kc) {
        const float* xp = &x[(size_t)node * DIM + kc * BS + kg * 8];
#pragma unroll
        for (int i = 0; i < 8; ++i) {
            float v = xp[i];
            if (RELU) v = fmaxf(v, 0.f);
            bfr[kc][i] = (short)f2bfbits(v);
        }
    }
#pragma unroll 2
    for (int mt = 0; mt < 8; ++mt) {
        const int col0 = mt * 16 + kg * 4;
        f4v acc = *(const f4v*)&bias[col0];
#pragma unroll
        for (int kc = 0; kc < 4; ++kc) {
            const float* rp = &root[(size_t)(kc * BS + kg * 8) * DIM + mt * 16 + lm];
            s8v afrag;
#pragma unroll
            for (int i = 0; i < 8; ++i)
                afrag[i] = (short)f2bfbits(rp[i * DIM]);
            acc = __builtin_amdgcn_mfma_f32_16x16x32_bf16(afrag, bfr[kc], acc, 0, 0, 0);
        }
        *(f4v*)&out[(size_t)node * DIM + col0] = acc;
    }
}

template<bool RELU>
__global__ __launch_bounds__(256) void agg_fallback_kernel(const int* __restrict__ srcs,
                                                           const int* __restrict__ off,
                                                           const int* __restrict__ cnt,
                                                           const float* __restrict__ x,
                                                           const float* __restrict__ W,
                                                           float* __restrict__ out) {
    __shared__ float Wsh[N_REL * BS * BS];
    const int bblk = blockIdx.y;
    for (int idx = threadIdx.x * 4; idx < N_REL * BS * BS; idx += 1024) {
        int r = idx >> 10, rest = idx & 1023;
        *(float4*)&Wsh[idx] = *(const float4*)&W[(r * NBLK + bblk) * 1024 + rest];
    }
    __syncthreads();
    const int hw = threadIdx.x >> 5;
    const int o  = threadIdx.x & 31;
    const int v  = blockIdx.x * 8 + hw;
    int endv = 0, cv = 0;
    if (o < N_REL) { endv = off[v * N_REL + o]; cv = cnt[v * N_REL + o]; }
    float acc = out[v * DIM + bblk * BS + o];
    for (int r = 0; r < N_REL; ++r) {
        const int c = __shfl(cv, r, 32);
        if (c == 0) continue;
        const int end = __shfl(endv, r, 32);
        float xs = 0.f;
        for (int k = end - c; k < end; ++k) {
            const int s = srcs[k];
            float xv = x[s * DIM + bblk * BS + o];
            if (RELU) xv = fmaxf(xv, 0.f);
            xs += xv;
        }
        xs *= (1.0f / (float)c);
        const float* wr = &Wsh[r * (BS * BS)];
#pragma unroll
        for (int i = 0; i < BS; i += 2) {
            float xi0 = __shfl(xs, i, 32);
            float xi1 = __shfl(xs, i + 1, 32);
            acc = fmaf(xi0, wr[i * BS + o], acc);
            acc = fmaf(xi1, wr[(i + 1) * BS + o], acc);
        }
    }
    out[v * DIM + bblk * BS + o] = acc;
}

// ---------------------------------------------------------------------------
extern "C" void kernel_launch(void* const* d_in, const int* in_sizes, int n_in,
                              void* d_out, int out_size, void* d_ws, size_t ws_size,
                              hipStream_t stream) {
    const int*   edge_index = (const int*)d_in[0];
    const int*   src   = edge_index;
    const int*   dstv  = edge_index + N_EDGES;
    const int*   et    = (const int*)d_in[1];
    const float* x0    = (const float*)d_in[2];
    const float* W1    = (const float*)d_in[3];
    const float* root1 = (const float*)d_in[4];
    const float* bias1 = (const float*)d_in[5];
    const float* W2    = (const float*)d_in[6];
    const float* root2 = (const float*)d_in[7];
    const float* bias2 = (const float*)d_in[8];
    float* out = (float*)d_out;

    // ---- fast-path workspace layout (131.8 MB total; LLC-resident) ----
    char* ws = (char*)d_ws;
    ushort* h    = (ushort*)ws;                             // 12,800,000 (bf16)
    int*    cnt  = (int*)   (ws + 12800000);                //  3,200,000
    int*    off  = (int*)   (ws + 16000000);                //  3,200,000
    int2*   evec = (int2*)  (ws + 19200000);                //  6,400,000
    int*    bsum = (int*)   (ws + 25600000);                //      4,096
    ushort* WB1  = (ushort*)(ws + 25604096);                //    262,144
    ushort* WB2  = (ushort*)(ws + 25866240);                //    262,144
    ushort* RB1  = (ushort*)(ws + 26128384);                //     32,768
    ushort* RB2  = (ushort*)(ws + 26161152);                //     32,768
    float*  scl  = (float*) (ws + 26193920);                //  3,200,000
    char*   tab  =          (ws + 29393920);                // 102,400,000
    const size_t FAST_NEED = 131793920ull;

    const int egrid = (N_EDGES + 255) / 256;     // 3125
    const int tgrid = (NWT + 3) / 4;             // 782

    if (ws_size >= FAST_NEED) {
        prep_kernel<<<1152, 256, 0, stream>>>(W1, W2, root1, root2, WB1, WB2, RB1, RB2);
        hipMemsetAsync(cnt, 0, (size_t)NSEG * sizeof(int), stream);
        count_kernel<<<egrid, 256, 0, stream>>>(dstv, et, cnt, N_EDGES);
        scan1_kernel<<<N_SCAN_BLKS, 256, 0, stream>>>(cnt, off, bsum, NSEG);
        scan2_kernel<<<1, 1024, 0, stream>>>(bsum, N_SCAN_BLKS);
        scan3_kernel<<<(NSEG + 255) / 256, 256, 0, stream>>>(off, bsum, NSEG);
        scatter_fast_kernel<<<egrid, 256, 0, stream>>>(src, dstv, et, off, cnt, evec, N_EDGES);

        dim3 agrid_r(tgrid, 4);                  // (782, rel-groups)
        const int ngrid = N_NODES / 8;           // 6250

        // ---- layer 1: h(bf16) = x0@root1 + bias1 ; += messages ----
        dense_rb_kernel<false, true, false><<<tgrid, 256, 0, stream>>>(x0, RB1, bias1, h);
        allr8_kernel<false, false><<<agrid_r, 256, 0, stream>>>(x0, WB1, tab, scl);
        agg8_kernel<true><<<ngrid, 256, 0, stream>>>(evec, off, tab, scl, h);

        // ---- layer 2: out(fp32) = relu(h)@root2 + bias2 ; += messages ----
        dense_rb_kernel<true, false, true><<<tgrid, 256, 0, stream>>>(h, RB2, bias2, out);
        allr8_kernel<true, true><<<agrid_r, 256, 0, stream>>>(h, WB2, tab, scl);
        agg8_kernel<false><<<ngrid, 256, 0, stream>>>(evec, off, tab, scl, out);
    } else {
        // ---- slow fallback (ws >= 35.3 MB): fp32 h + direct gather-agg ----
        float* hf    = (float*)d_ws;
        int*   cntf  = (int*)((char*)d_ws + 25600000);
        int*   offf  = (int*)((char*)d_ws + 28800000);
        int*   srcsf = (int*)((char*)d_ws + 32000000);
        int*   bsumf = (int*)((char*)d_ws + 35200000);

        hipMemsetAsync(cntf, 0, (size_t)NSEG * sizeof(int), stream);
        count_kernel<<<egrid, 256, 0, stream>>>(dstv, et, cntf, N_EDGES);
        scan1_kernel<<<N_SCAN_BLKS, 256, 0, stream>>>(cntf, offf, bsumf, NSEG);
        scan2_kernel<<<1, 1024, 0, stream>>>(bsumf, N_SCAN_BLKS);
        scan3_kernel<<<(NSEG + 255) / 256, 256, 0, stream>>>(offf, bsumf, NSEG);
        scatter_old_kernel<<<egrid, 256, 0, stream>>>(src, dstv, et, offf, srcsf, N_EDGES);

        dim3 fgrid(N_NODES / 8, NBLK);
        dense_old_kernel<false><<<tgrid, 256, 0, stream>>>(x0, root1, bias1, hf);
        agg_fallback_kernel<false><<<fgrid, 256, 0, stream>>>(srcsf, offf, cntf, x0, W1, hf);
        dense_old_kernel<true><<<tgrid, 256, 0, stream>>>(hf, root2, bias2, out);
        agg_fallback_kernel<true><<<fgrid, 256, 0, stream>>>(srcsf, offf, cntf, hf, W2, out);
    }
}

// Round 7
// 273.453 us; speedup vs baseline: 9.3232x; 1.0563x over previous
//
#include <hip/hip_runtime.h>
#include <hip/hip_bf16.h>

#define N_NODES 50000
#define N_REL   16
#define DIM     128
#define NBLK    4
#define BS      32
#define N_EDGES 800000
#define NSEG    (N_NODES * N_REL)
#define SCAN_BLK 1024
#define N_SCAN_BLKS ((NSEG + SCAN_BLK - 1) / SCAN_BLK)
#define NWT     (N_NODES / 16)        // 3125 wave-tiles of 16 nodes

typedef __attribute__((ext_vector_type(8))) short s8v;            // 8 bf16
typedef __attribute__((ext_vector_type(8))) unsigned short u8v;   // 8 bf16 bits
typedef __attribute__((ext_vector_type(4))) float f4v;            // mfma C/D

__device__ __forceinline__ float bf2f(unsigned short u) {
    return __uint_as_float(((unsigned int)u) << 16);
}
__device__ __forceinline__ unsigned short f2bfbits(float f) {   // RNE
    unsigned int u = __float_as_uint(f);
    return (unsigned short)((u + 0x7fffu + ((u >> 16) & 1u)) >> 16);
}

// ---------------------------------------------------------------------------
// CSR build: count -> scan -> scatter(evec = {gidx, inv})
// ---------------------------------------------------------------------------
__global__ __launch_bounds__(256) void count_kernel(const int* __restrict__ dst,
                                                    const int* __restrict__ et,
                                                    int* __restrict__ cnt, int E) {
    int e = blockIdx.x * 256 + threadIdx.x;
    if (e < E) atomicAdd(&cnt[dst[e] * N_REL + et[e]], 1);
}

__global__ __launch_bounds__(256) void scan1_kernel(const int* __restrict__ in,
                                                    int* __restrict__ out,
                                                    int* __restrict__ bsum, int M) {
    const int t = threadIdx.x;
    const int base = blockIdx.x * SCAN_BLK + t * 4;
    int v0 = (base + 0 < M) ? in[base + 0] : 0;
    int v1 = (base + 1 < M) ? in[base + 1] : 0;
    int v2 = (base + 2 < M) ? in[base + 2] : 0;
    int v3 = (base + 3 < M) ? in[base + 3] : 0;
    const int s = v0 + v1 + v2 + v3;
    const int lane = t & 63, wid = t >> 6;
    int inc = s;
    for (int d = 1; d < 64; d <<= 1) {
        int u = __shfl_up(inc, d, 64);
        if (lane >= d) inc += u;
    }
    __shared__ int wsum[5];
    if (lane == 63) wsum[wid] = inc;
    __syncthreads();
    if (t == 0) {
        int a = 0;
        for (int w = 0; w < 4; ++w) { int u = wsum[w]; wsum[w] = a; a += u; }
        wsum[4] = a;
    }
    __syncthreads();
    const int ex = inc - s + wsum[wid];
    if (base + 0 < M) out[base + 0] = ex;
    if (base + 1 < M) out[base + 1] = ex + v0;
    if (base + 2 < M) out[base + 2] = ex + v0 + v1;
    if (base + 3 < M) out[base + 3] = ex + v0 + v1 + v2;
    if (t == 0) bsum[blockIdx.x] = wsum[4];
}

__global__ __launch_bounds__(1024) void scan2_kernel(int* __restrict__ bsum, int nb) {
    const int t = threadIdx.x;
    int s = (t < nb) ? bsum[t] : 0;
    const int lane = t & 63, wid = t >> 6;
    int inc = s;
    for (int d = 1; d < 64; d <<= 1) {
        int u = __shfl_up(inc, d, 64);
        if (lane >= d) inc += u;
    }
    __shared__ int wsum[16];
    if (lane == 63) wsum[wid] = inc;
    __syncthreads();
    if (t == 0) {
        int a = 0;
        for (int w = 0; w < 16; ++w) { int u = wsum[w]; wsum[w] = a; a += u; }
    }
    __syncthreads();
    const int ex = inc - s + wsum[wid];
    if (t < nb) bsum[t] = ex;
}

__global__ __launch_bounds__(256) void scan3_kernel(int* __restrict__ out,
                                                    const int* __restrict__ bsum, int M) {
    int i = blockIdx.x * 256 + threadIdx.x;
    if (i < M) out[i] += bsum[i / SCAN_BLK];
}

// fast path: emit per-edge {gather-row, 1/c} in CSR position; row = r*N + src
__global__ __launch_bounds__(256) void scatter_fast_kernel(const int* __restrict__ src,
                                                           const int* __restrict__ dst,
                                                           const int* __restrict__ et,
                                                           int* __restrict__ off,
                                                           const int* __restrict__ cnt,
                                                           int2* __restrict__ evec, int E) {
    int e = blockIdx.x * 256 + threadIdx.x;
    if (e < E) {
        int r = et[e];
        int seg = dst[e] * N_REL + r;
        int pos = atomicAdd(&off[seg], 1);
        float inv = 1.0f / (float)cnt[seg];
        evec[pos] = make_int2(r * N_NODES + src[e], __float_as_int(inv));
    }
}

// slow-fallback scatter (srcs list)
__global__ __launch_bounds__(256) void scatter_old_kernel(const int* __restrict__ src,
                                                          const int* __restrict__ dst,
                                                          const int* __restrict__ et,
                                                          int* __restrict__ off,
                                                          int* __restrict__ srcs, int E) {
    int e = blockIdx.x * 256 + threadIdx.x;
    if (e < E) {
        int seg = dst[e] * N_REL + et[e];
        int pos = atomicAdd(&off[seg], 1);
        srcs[pos] = src[e];
    }
}

// ---------------------------------------------------------------------------
// Prep: convert W1,W2,root1,root2 to bf16 in A-fragment lane order.
// WB idx = ((((r*4+b)*2+mt)*4+kg)*16+lm)*8+i  <- W[r][b][kg*8+i][mt*16+lm]
// RB idx = (((mt*4+kc)*4+kg)*16+lm)*8+i       <- root[kc*32+kg*8+i][mt*16+lm]
// ---------------------------------------------------------------------------
__global__ __launch_bounds__(256) void prep_kernel(const float* __restrict__ W1,
                                                   const float* __restrict__ W2,
                                                   const float* __restrict__ r1,
                                                   const float* __restrict__ r2,
                                                   ushort* __restrict__ WB1,
                                                   ushort* __restrict__ WB2,
                                                   ushort* __restrict__ RB1,
                                                   ushort* __restrict__ RB2) {
    int t = blockIdx.x * 256 + threadIdx.x;
    if (t < 262144) {                               // WB1 / WB2
        const float* W = (t < 131072) ? W1 : W2;
        ushort* WB     = (t < 131072) ? WB1 : WB2;
        int idx = t & 131071;
        int i  = idx & 7;
        int lm = (idx >> 3) & 15;
        int kg = (idx >> 7) & 3;
        int mt = (idx >> 9) & 1;
        int b  = (idx >> 10) & 3;
        int r  = idx >> 12;
        WB[idx] = f2bfbits(W[((size_t)(r * 4 + b) * 32 + kg * 8 + i) * 32 + mt * 16 + lm]);
    } else if (t < 294912) {                        // RB1 / RB2
        int u = t - 262144;
        const float* R = (u < 16384) ? r1 : r2;
        ushort* RB     = (u < 16384) ? RB1 : RB2;
        int idx = u & 16383;
        int i  = idx & 7;
        int lm = (idx >> 3) & 15;
        int kg = (idx >> 7) & 3;
        int kc = (idx >> 9) & 3;
        int mt = (idx >> 11) & 7;
        RB[idx] = f2bfbits(R[(size_t)(kc * 32 + kg * 8 + i) * DIM + mt * 16 + lm]);
    }
}

// ---------------------------------------------------------------------------
// allR transform -> per-row-scaled int8 table, MFMA-natural byte order:
// tab[(r*N+node)*128 + kg*32 + (b*8 + mt*4 + j)]  <=>  dim b*32+mt*16+kg*4+j.
// Each lane quantizes and stores ITS OWN 32 bytes (2x uint4) -- no LDS, no
// clamp (values bounded by rowmax), rowmax = 2 shfl_xor, pack via v_perm.
// ---------------------------------------------------------------------------
template<bool IN_BF16, bool RELU>
__global__ __launch_bounds__(256) void allr8_kernel(const void* __restrict__ xin,
                                                    const ushort* __restrict__ WB,
                                                    char* __restrict__ tab,
                                                    float* __restrict__ scl) {
    const int wv = threadIdx.x >> 6;
    const int l  = threadIdx.x & 63;
    const int wt = blockIdx.x * 4 + wv;
    if (wt >= NWT) return;
    const int rg = blockIdx.y;                  // relation group 0..3
    const int nbase = wt * 16;
    const int lm = l & 15;
    const int kg = l >> 4;
    const int node = nbase + lm;

    // load B-fragments for all 4 blocks (x row of node lm)
    s8v bfr[4];
#pragma unroll
    for (int b = 0; b < 4; ++b) {
        if (IN_BF16) {
            const ushort* xp = (const ushort*)xin + (size_t)node * DIM + b * BS + kg * 8;
            u8v u = *(const u8v*)xp;
#pragma unroll
            for (int i = 0; i < 8; ++i) {
                unsigned short us = u[i];
                if (RELU) us = (us & 0x8000u) ? (unsigned short)0 : us;
                bfr[b][i] = (short)us;
            }
        } else {
            const float* xp = (const float*)xin + (size_t)node * DIM + b * BS + kg * 8;
#pragma unroll
            for (int i = 0; i < 8; ++i) {
                float v = xp[i];
                if (RELU) v = fmaxf(v, 0.f);
                bfr[b][i] = (short)f2bfbits(v);
            }
        }
    }

    for (int ri = 0; ri < 4; ++ri) {
        const int rr = rg * 4 + ri;
        f4v acc[4][2];
#pragma unroll
        for (int b = 0; b < 4; ++b) {
#pragma unroll
            for (int mt = 0; mt < 2; ++mt) {
                s8v afrag = *(const s8v*)&WB[((((rr * 4 + b) * 2 + mt) * 4 + kg) * 16 + lm) * 8];
                f4v z = {0.f, 0.f, 0.f, 0.f};
                acc[b][mt] = __builtin_amdgcn_mfma_f32_16x16x32_bf16(afrag, bfr[b], z, 0, 0, 0);
            }
        }
        // rowmax over the node's 128 values (32 in-lane + across 4 kg lanes)
        float m = 0.f;
#pragma unroll
        for (int b = 0; b < 4; ++b)
#pragma unroll
            for (int mt = 0; mt < 2; ++mt)
#pragma unroll
                for (int j = 0; j < 4; ++j)
                    m = fmaxf(m, fabsf(acc[b][mt][j]));
        m = fmaxf(m, __shfl_xor(m, 16, 64));
        m = fmaxf(m, __shfl_xor(m, 32, 64));
        m = fmaxf(m, 1e-30f);
        const float qs = 127.0f / m;

        // quantize own 32 values; |v*qs| <= 127 by construction -> no clamp.
        unsigned int d[8];
#pragma unroll
        for (int b = 0; b < 4; ++b) {
#pragma unroll
            for (int mt = 0; mt < 2; ++mt) {
                int q0 = __float2int_rn(acc[b][mt][0] * qs);
                int q1 = __float2int_rn(acc[b][mt][1] * qs);
                int q2 = __float2int_rn(acc[b][mt][2] * qs);
                int q3 = __float2int_rn(acc[b][mt][3] * qs);
                unsigned int t01 = __builtin_amdgcn_perm((unsigned)q1, (unsigned)q0, 0x00000400u);
                unsigned int t23 = __builtin_amdgcn_perm((unsigned)q3, (unsigned)q2, 0x00000400u);
                d[b * 2 + mt] = __builtin_amdgcn_perm(t23, t01, 0x05040100u);
            }
        }
        char* gp = tab + ((size_t)rr * N_NODES + node) * 128 + kg * 32;
        *(uint4*)gp        = make_uint4(d[0], d[1], d[2], d[3]);
        *(uint4*)(gp + 16) = make_uint4(d[4], d[5], d[6], d[7]);
        if (kg == 0) scl[rr * N_NODES + node] = m * (1.0f / 127.0f);
    }
}

// ---------------------------------------------------------------------------
// Dense root GEMM via MFMA, pre-swizzled bf16 root.
// ---------------------------------------------------------------------------
template<bool IN_BF16, bool OUT_BF16, bool RELU>
__global__ __launch_bounds__(256) void dense_rb_kernel(const void* __restrict__ xin,
                                                       const ushort* __restrict__ RB,
                                                       const float* __restrict__ bias,
                                                       void* __restrict__ outv) {
    const int wv = threadIdx.x >> 6;
    const int l  = threadIdx.x & 63;
    const int wt = blockIdx.x * 4 + wv;
    if (wt >= NWT) return;
    const int nbase = wt * 16;
    const int lm = l & 15;
    const int kg = l >> 4;
    const int node = nbase + lm;

    s8v bfr[4];
#pragma unroll
    for (int kc = 0; kc < 4; ++kc) {
        if (IN_BF16) {
            const ushort* xp = (const ushort*)xin + (size_t)node * DIM + kc * BS + kg * 8;
            u8v u = *(const u8v*)xp;
#pragma unroll
            for (int i = 0; i < 8; ++i) {
                unsigned short us = u[i];
                if (RELU) us = (us & 0x8000u) ? (unsigned short)0 : us;
                bfr[kc][i] = (short)us;
            }
        } else {
            const float* xp = (const float*)xin + (size_t)node * DIM + kc * BS + kg * 8;
#pragma unroll
            for (int i = 0; i < 8; ++i) {
                float v = xp[i];
                if (RELU) v = fmaxf(v, 0.f);
                bfr[kc][i] = (short)f2bfbits(v);
            }
        }
    }
#pragma unroll 2
    for (int mt = 0; mt < 8; ++mt) {
        const int col0 = mt * 16 + kg * 4;
        f4v acc = *(const f4v*)&bias[col0];
#pragma unroll
        for (int kc = 0; kc < 4; ++kc) {
            s8v afrag = *(const s8v*)&RB[(((mt * 4 + kc) * 4 + kg) * 16 + lm) * 8];
            acc = __builtin_amdgcn_mfma_f32_16x16x32_bf16(afrag, bfr[kc], acc, 0, 0, 0);
        }
        if (OUT_BF16) {
            unsigned int p0 = (unsigned int)f2bfbits(acc[0]) |
                              ((unsigned int)f2bfbits(acc[1]) << 16);
            unsigned int p1 = (unsigned int)f2bfbits(acc[2]) |
                              ((unsigned int)f2bfbits(acc[3]) << 16);
            *(uint2*)((ushort*)outv + (size_t)node * DIM + col0) = make_uint2(p0, p1);
        } else {
            *(f4v*)((float*)outv + (size_t)node * DIM + col0) = acc;
        }
    }
}

// ---------------------------------------------------------------------------
// Edge-stream aggregate over int8 table: half-wave per dst node; evec read
// directly (16-lane broadcast, no shuffles); 4 edges in flight per iter;
// per edge one 128B contiguous row + 1 scale; dequant fma; final RMW maps
// the MFMA-natural byte order back to dims: lane w -> dims
// (w&3)*32+(w>>2)*4 +{0..3} and +16+{0..3}.
// ---------------------------------------------------------------------------
template<bool OUT_BF16>
__global__ __launch_bounds__(256) void agg8_kernel(const int2* __restrict__ evec,
                                                   const int* __restrict__ off,
                                                   const char* __restrict__ tab,
                                                   const float* __restrict__ scl,
                                                   void* __restrict__ outv) {
    const int hw = threadIdx.x >> 5;
    const int o  = threadIdx.x & 31;
    const int v  = blockIdx.x * 8 + hw;

    const int start = (v == 0) ? 0 : off[v * N_REL - 1];
    const int end   = off[v * N_REL + N_REL - 1];

    const int p = o >> 4;            // edge parity within the quad (0/1)
    const int w = o & 15;            // 8-byte sub-chunk of the 128B row

    float acc[8];
#pragma unroll
    for (int j = 0; j < 8; ++j) acc[j] = 0.f;

    for (int base = start; base < end; base += 4) {
        const int k0 = base + p;
        const int k1 = base + 2 + p;
        const int2 e0 = evec[min(k0, end - 1)];
        const int2 e1 = evec[min(k1, end - 1)];
        const int g0 = e0.x, g1 = e1.x;
        const float i0 = (k0 < end) ? __int_as_float(e0.y) : 0.f;
        const float i1 = (k1 < end) ? __int_as_float(e1.y) : 0.f;
        const uint2 q0 = *(const uint2*)(tab + (size_t)g0 * 128 + w * 8);
        const uint2 q1 = *(const uint2*)(tab + (size_t)g1 * 128 + w * 8);
        const float s0 = scl[g0] * i0;
        const float s1 = scl[g1] * i1;
#pragma unroll
        for (int j = 0; j < 4; ++j) {
            acc[j]     = fmaf((float)(int)(signed char)(q0.x >> (8 * j)), s0, acc[j]);
            acc[4 + j] = fmaf((float)(int)(signed char)(q0.y >> (8 * j)), s0, acc[4 + j]);
        }
#pragma unroll
        for (int j = 0; j < 4; ++j) {
            acc[j]     = fmaf((float)(int)(signed char)(q1.x >> (8 * j)), s1, acc[j]);
            acc[4 + j] = fmaf((float)(int)(signed char)(q1.y >> (8 * j)), s1, acc[4 + j]);
        }
    }
#pragma unroll
    for (int j = 0; j < 8; ++j)
        acc[j] += __shfl_xor(acc[j], 16, 32);

    if (o < 16) {
        const int base0 = (o & 3) * 32 + (o >> 2) * 4;     // dim of acc[0]
        if (OUT_BF16) {
            ushort* hp = (ushort*)outv + (size_t)v * DIM + base0;
            ushort4 a0 = *(ushort4*)hp;
            ushort4 a1 = *(ushort4*)(hp + 16);
            a0.x = f2bfbits(bf2f(a0.x) + acc[0]);
            a0.y = f2bfbits(bf2f(a0.y) + acc[1]);
            a0.z = f2bfbits(bf2f(a0.z) + acc[2]);
            a0.w = f2bfbits(bf2f(a0.w) + acc[3]);
            a1.x = f2bfbits(bf2f(a1.x) + acc[4]);
            a1.y = f2bfbits(bf2f(a1.y) + acc[5]);
            a1.z = f2bfbits(bf2f(a1.z) + acc[6]);
            a1.w = f2bfbits(bf2f(a1.w) + acc[7]);
            *(ushort4*)hp        = a0;
            *(ushort4*)(hp + 16) = a1;
        } else {
            float* op = (float*)outv + (size_t)v * DIM + base0;
            float4 r0 = *(float4*)op;
            float4 r1 = *(float4*)(op + 16);
            r0.x += acc[0]; r0.y += acc[1]; r0.z += acc[2]; r0.w += acc[3];
            r1.x += acc[4]; r1.y += acc[5]; r1.z += acc[6]; r1.w += acc[7];
            *(float4*)op        = r0;
            *(float4*)(op + 16) = r1;
        }
    }
}

// ---------------------------------------------------------------------------
// Slow fallback (tiny ws): fp32 dense + gather-aggregate on x directly.
// ---------------------------------------------------------------------------
template<bool RELU>
__global__ __launch_bounds__(256) void dense_old_kernel(const float* __restrict__ x,
                                                        const float* __restrict__ root,
                                                        const float* __restrict__ bias,
                                                        float* __restrict__ out) {
    const int wv = threadIdx.x >> 6;
    const int l  = threadIdx.x & 63;
    const int wt = blockIdx.x * 4 + wv;
    if (wt >= NWT) return;
    const int nbase = wt * 16;
    const int lm = l & 15;
    const int kg = l >> 4;
    const int node = nbase + lm;

    s8v bfr[4];
#pragma unroll
    for (int kc = 0; kc < 4; ++kc) {
        const float* xp = &x[(size_t)node * DIM + kc * BS + kg * 8];
#pragma unroll
        for (int i = 0; i < 8; ++i) {
            float v = xp[i];
            if (RELU) v = fmaxf(v, 0.f);
            bfr[kc][i] = (short)f2bfbits(v);
        }
    }
#pragma unroll 2
    for (int mt = 0; mt < 8; ++mt) {
        const int col0 = mt * 16 + kg * 4;
        f4v acc = *(const f4v*)&bias[col0];
#pragma unroll
        for (int kc = 0; kc < 4; ++kc) {
            const float* rp = &root[(size_t)(kc * BS + kg * 8) * DIM + mt * 16 + lm];
            s8v afrag;
#pragma unroll
            for (int i = 0; i < 8; ++i)
                afrag[i] = (short)f2bfbits(rp[i * DIM]);
            acc = __builtin_amdgcn_mfma_f32_16x16x32_bf16(afrag, bfr[kc], acc, 0, 0, 0);
        }
        *(f4v*)&out[(size_t)node * DIM + col0] = acc;
    }
}

template<bool RELU>
__global__ __launch_bounds__(256) void agg_fallback_kernel(const int* __restrict__ srcs,
                                                           const int* __restrict__ off,
                                                           const int* __restrict__ cnt,
                                                           const float* __restrict__ x,
                                                           const float* __restrict__ W,
                                                           float* __restrict__ out) {
    __shared__ float Wsh[N_REL * BS * BS];
    const int bblk = blockIdx.y;
    for (int idx = threadIdx.x * 4; idx < N_REL * BS * BS; idx += 1024) {
        int r = idx >> 10, rest = idx & 1023;
        *(float4*)&Wsh[idx] = *(const float4*)&W[(r * NBLK + bblk) * 1024 + rest];
    }
    __syncthreads();
    const int hw = threadIdx.x >> 5;
    const int o  = threadIdx.x & 31;
    const int v  = blockIdx.x * 8 + hw;
    int endv = 0, cv = 0;
    if (o < N_REL) { endv = off[v * N_REL + o]; cv = cnt[v * N_REL + o]; }
    float acc = out[v * DIM + bblk * BS + o];
    for (int r = 0; r < N_REL; ++r) {
        const int c = __shfl(cv, r, 32);
        if (c == 0) continue;
        const int end = __shfl(endv, r, 32);
        float xs = 0.f;
        for (int k = end - c; k < end; ++k) {
            const int s = srcs[k];
            float xv = x[s * DIM + bblk * BS + o];
            if (RELU) xv = fmaxf(xv, 0.f);
            xs += xv;
        }
        xs *= (1.0f / (float)c);
        const float* wr = &Wsh[r * (BS * BS)];
#pragma unroll
        for (int i = 0; i < BS; i += 2) {
            float xi0 = __shfl(xs, i, 32);
            float xi1 = __shfl(xs, i + 1, 32);
            acc = fmaf(xi0, wr[i * BS + o], acc);
            acc = fmaf(xi1, wr[(i + 1) * BS + o], acc);
        }
    }
    out[v * DIM + bblk * BS + o] = acc;
}

// ---------------------------------------------------------------------------
extern "C" void kernel_launch(void* const* d_in, const int* in_sizes, int n_in,
                              void* d_out, int out_size, void* d_ws, size_t ws_size,
                              hipStream_t stream) {
    const int*   edge_index = (const int*)d_in[0];
    const int*   src   = edge_index;
    const int*   dstv  = edge_index + N_EDGES;
    const int*   et    = (const int*)d_in[1];
    const float* x0    = (const float*)d_in[2];
    const float* W1    = (const float*)d_in[3];
    const float* root1 = (const float*)d_in[4];
    const float* bias1 = (const float*)d_in[5];
    const float* W2    = (const float*)d_in[6];
    const float* root2 = (const float*)d_in[7];
    const float* bias2 = (const float*)d_in[8];
    float* out = (float*)d_out;

    // ---- fast-path workspace layout (131.8 MB total; LLC-resident) ----
    char* ws = (char*)d_ws;
    ushort* h    = (ushort*)ws;                             // 12,800,000 (bf16)
    int*    cnt  = (int*)   (ws + 12800000);                //  3,200,000
    int*    off  = (int*)   (ws + 16000000);                //  3,200,000
    int2*   evec = (int2*)  (ws + 19200000);                //  6,400,000
    int*    bsum = (int*)   (ws + 25600000);                //      4,096
    ushort* WB1  = (ushort*)(ws + 25604096);                //    262,144
    ushort* WB2  = (ushort*)(ws + 25866240);                //    262,144
    ushort* RB1  = (ushort*)(ws + 26128384);                //     32,768
    ushort* RB2  = (ushort*)(ws + 26161152);                //     32,768
    float*  scl  = (float*) (ws + 26193920);                //  3,200,000
    char*   tab  =          (ws + 29393920);                // 102,400,000
    const size_t FAST_NEED = 131793920ull;

    const int egrid = (N_EDGES + 255) / 256;     // 3125
    const int tgrid = (NWT + 3) / 4;             // 782

    if (ws_size >= FAST_NEED) {
        prep_kernel<<<1152, 256, 0, stream>>>(W1, W2, root1, root2, WB1, WB2, RB1, RB2);
        hipMemsetAsync(cnt, 0, (size_t)NSEG * sizeof(int), stream);
        count_kernel<<<egrid, 256, 0, stream>>>(dstv, et, cnt, N_EDGES);
        scan1_kernel<<<N_SCAN_BLKS, 256, 0, stream>>>(cnt, off, bsum, NSEG);
        scan2_kernel<<<1, 1024, 0, stream>>>(bsum, N_SCAN_BLKS);
        scan3_kernel<<<(NSEG + 255) / 256, 256, 0, stream>>>(off, bsum, NSEG);
        scatter_fast_kernel<<<egrid, 256, 0, stream>>>(src, dstv, et, off, cnt, evec, N_EDGES);

        dim3 agrid_r(tgrid, 4);                  // (782, rel-groups)
        const int ngrid = N_NODES / 8;           // 6250

        // ---- layer 1: h(bf16) = x0@root1 + bias1 ; += messages ----
        dense_rb_kernel<false, true, false><<<tgrid, 256, 0, stream>>>(x0, RB1, bias1, h);
        allr8_kernel<false, false><<<agrid_r, 256, 0, stream>>>(x0, WB1, tab, scl);
        agg8_kernel<true><<<ngrid, 256, 0, stream>>>(evec, off, tab, scl, h);

        // ---- layer 2: out(fp32) = relu(h)@root2 + bias2 ; += messages ----
        dense_rb_kernel<true, false, true><<<tgrid, 256, 0, stream>>>(h, RB2, bias2, out);
        allr8_kernel<true, true><<<agrid_r, 256, 0, stream>>>(h, WB2, tab, scl);
        agg8_kernel<false><<<ngrid, 256, 0, stream>>>(evec, off, tab, scl, out);
    } else {
        // ---- slow fallback (ws >= 35.3 MB): fp32 h + direct gather-agg ----
        float* hf    = (float*)d_ws;
        int*   cntf  = (int*)((char*)d_ws + 25600000);
        int*   offf  = (int*)((char*)d_ws + 28800000);
        int*   srcsf = (int*)((char*)d_ws + 32000000);
        int*   bsumf = (int*)((char*)d_ws + 35200000);

        hipMemsetAsync(cntf, 0, (size_t)NSEG * sizeof(int), stream);
        count_kernel<<<egrid, 256, 0, stream>>>(dstv, et, cntf, N_EDGES);
        scan1_kernel<<<N_SCAN_BLKS, 256, 0, stream>>>(cntf, offf, bsumf, NSEG);
        scan2_kernel<<<1, 1024, 0, stream>>>(bsumf, N_SCAN_BLKS);
        scan3_kernel<<<(NSEG + 255) / 256, 256, 0, stream>>>(offf, bsumf, NSEG);
        scatter_old_kernel<<<egrid, 256, 0, stream>>>(src, dstv, et, offf, srcsf, N_EDGES);

        dim3 fgrid(N_NODES / 8, NBLK);
        dense_old_kernel<false><<<tgrid, 256, 0, stream>>>(x0, root1, bias1, hf);
        agg_fallback_kernel<false><<<fgrid, 256, 0, stream>>>(srcsf, offf, cntf, x0, W1, hf);
        dense_old_kernel<true><<<tgrid, 256, 0, stream>>>(hf, root2, bias2, out);
        agg_fallback_kernel<true><<<fgrid, 256, 0, stream>>>(srcsf, offf, cntf, hf, W2, out);
    }
}

// Round 8
// 253.368 us; speedup vs baseline: 10.0622x; 1.0793x over previous
//
#include <hip/hip_runtime.h>
#include <hip/hip_bf16.h>

#define N_NODES 50000
#define N_REL   16
#define DIM     128
#define NBLK    4
#define BS      32
#define N_EDGES 800000
#define NSEG    (N_NODES * N_REL)
#define SCAN_BLK 1024
#define N_SCAN_BLKS ((NSEG + SCAN_BLK - 1) / SCAN_BLK)
#define NWT     (N_NODES / 16)        // 3125 wave-tiles of 16 nodes

typedef __attribute__((ext_vector_type(8))) short s8v;            // 8 bf16
typedef __attribute__((ext_vector_type(8))) unsigned short u8v;   // 8 bf16 bits
typedef __attribute__((ext_vector_type(4))) float f4v;            // mfma C/D

__device__ __forceinline__ float bf2f(unsigned short u) {
    return __uint_as_float(((unsigned int)u) << 16);
}
__device__ __forceinline__ unsigned short f2bfbits(float f) {   // RNE
    unsigned int u = __float_as_uint(f);
    return (unsigned short)((u + 0x7fffu + ((u >> 16) & 1u)) >> 16);
}

// ---------------------------------------------------------------------------
// CSR build: count -> scan -> scatter(evec = {gidx, inv})
// ---------------------------------------------------------------------------
__global__ __launch_bounds__(256) void count_kernel(const int* __restrict__ dst,
                                                    const int* __restrict__ et,
                                                    int* __restrict__ cnt, int E) {
    int e = blockIdx.x * 256 + threadIdx.x;
    if (e < E) atomicAdd(&cnt[dst[e] * N_REL + et[e]], 1);
}

__global__ __launch_bounds__(256) void scan1_kernel(const int* __restrict__ in,
                                                    int* __restrict__ out,
                                                    int* __restrict__ bsum, int M) {
    const int t = threadIdx.x;
    const int base = blockIdx.x * SCAN_BLK + t * 4;
    int v0 = (base + 0 < M) ? in[base + 0] : 0;
    int v1 = (base + 1 < M) ? in[base + 1] : 0;
    int v2 = (base + 2 < M) ? in[base + 2] : 0;
    int v3 = (base + 3 < M) ? in[base + 3] : 0;
    const int s = v0 + v1 + v2 + v3;
    const int lane = t & 63, wid = t >> 6;
    int inc = s;
    for (int d = 1; d < 64; d <<= 1) {
        int u = __shfl_up(inc, d, 64);
        if (lane >= d) inc += u;
    }
    __shared__ int wsum[5];
    if (lane == 63) wsum[wid] = inc;
    __syncthreads();
    if (t == 0) {
        int a = 0;
        for (int w = 0; w < 4; ++w) { int u = wsum[w]; wsum[w] = a; a += u; }
        wsum[4] = a;
    }
    __syncthreads();
    const int ex = inc - s + wsum[wid];
    if (base + 0 < M) out[base + 0] = ex;
    if (base + 1 < M) out[base + 1] = ex + v0;
    if (base + 2 < M) out[base + 2] = ex + v0 + v1;
    if (base + 3 < M) out[base + 3] = ex + v0 + v1 + v2;
    if (t == 0) bsum[blockIdx.x] = wsum[4];
}

__global__ __launch_bounds__(1024) void scan2_kernel(int* __restrict__ bsum, int nb) {
    const int t = threadIdx.x;
    int s = (t < nb) ? bsum[t] : 0;
    const int lane = t & 63, wid = t >> 6;
    int inc = s;
    for (int d = 1; d < 64; d <<= 1) {
        int u = __shfl_up(inc, d, 64);
        if (lane >= d) inc += u;
    }
    __shared__ int wsum[16];
    if (lane == 63) wsum[wid] = inc;
    __syncthreads();
    if (t == 0) {
        int a = 0;
        for (int w = 0; w < 16; ++w) { int u = wsum[w]; wsum[w] = a; a += u; }
    }
    __syncthreads();
    const int ex = inc - s + wsum[wid];
    if (t < nb) bsum[t] = ex;
}

__global__ __launch_bounds__(256) void scan3_kernel(int* __restrict__ out,
                                                    const int* __restrict__ bsum, int M) {
    int i = blockIdx.x * 256 + threadIdx.x;
    if (i < M) out[i] += bsum[i / SCAN_BLK];
}

// fast path: emit per-edge {gather-row, 1/c} in CSR position; row = r*N + src
__global__ __launch_bounds__(256) void scatter_fast_kernel(const int* __restrict__ src,
                                                           const int* __restrict__ dst,
                                                           const int* __restrict__ et,
                                                           int* __restrict__ off,
                                                           const int* __restrict__ cnt,
                                                           int2* __restrict__ evec, int E) {
    int e = blockIdx.x * 256 + threadIdx.x;
    if (e < E) {
        int r = et[e];
        int seg = dst[e] * N_REL + r;
        int pos = atomicAdd(&off[seg], 1);
        float inv = 1.0f / (float)cnt[seg];
        evec[pos] = make_int2(r * N_NODES + src[e], __float_as_int(inv));
    }
}

// slow-fallback scatter (srcs list)
__global__ __launch_bounds__(256) void scatter_old_kernel(const int* __restrict__ src,
                                                          const int* __restrict__ dst,
                                                          const int* __restrict__ et,
                                                          int* __restrict__ off,
                                                          int* __restrict__ srcs, int E) {
    int e = blockIdx.x * 256 + threadIdx.x;
    if (e < E) {
        int seg = dst[e] * N_REL + et[e];
        int pos = atomicAdd(&off[seg], 1);
        srcs[pos] = src[e];
    }
}

// ---------------------------------------------------------------------------
// Prep: convert W1,W2,root1,root2 to bf16 in A-fragment lane order.
// WB idx = ((((r*4+b)*2+mt)*4+kg)*16+lm)*8+i  <- W[r][b][kg*8+i][mt*16+lm]
// RB idx = (((mt*4+kc)*4+kg)*16+lm)*8+i       <- root[kc*32+kg*8+i][mt*16+lm]
// ---------------------------------------------------------------------------
__global__ __launch_bounds__(256) void prep_kernel(const float* __restrict__ W1,
                                                   const float* __restrict__ W2,
                                                   const float* __restrict__ r1,
                                                   const float* __restrict__ r2,
                                                   ushort* __restrict__ WB1,
                                                   ushort* __restrict__ WB2,
                                                   ushort* __restrict__ RB1,
                                                   ushort* __restrict__ RB2) {
    int t = blockIdx.x * 256 + threadIdx.x;
    if (t < 262144) {                               // WB1 / WB2
        const float* W = (t < 131072) ? W1 : W2;
        ushort* WB     = (t < 131072) ? WB1 : WB2;
        int idx = t & 131071;
        int i  = idx & 7;
        int lm = (idx >> 3) & 15;
        int kg = (idx >> 7) & 3;
        int mt = (idx >> 9) & 1;
        int b  = (idx >> 10) & 3;
        int r  = idx >> 12;
        WB[idx] = f2bfbits(W[((size_t)(r * 4 + b) * 32 + kg * 8 + i) * 32 + mt * 16 + lm]);
    } else if (t < 294912) {                        // RB1 / RB2
        int u = t - 262144;
        const float* R = (u < 16384) ? r1 : r2;
        ushort* RB     = (u < 16384) ? RB1 : RB2;
        int idx = u & 16383;
        int i  = idx & 7;
        int lm = (idx >> 3) & 15;
        int kg = (idx >> 7) & 3;
        int kc = (idx >> 9) & 3;
        int mt = (idx >> 11) & 7;
        RB[idx] = f2bfbits(R[(size_t)(kc * 32 + kg * 8 + i) * DIM + mt * 16 + lm]);
    }
}

// ---------------------------------------------------------------------------
// FUSED transform: per wave-tile of 16 nodes, load x-row fragments ONCE, then
// (a) produce the per-row-scaled int8 message table for ALL 16 relations
//     (MFMA-natural byte order: tab[(r*N+node)*128 + kg*32 + b*8+mt*4+j]),
// (b) root GEMM + bias -> dense part of the layer output (h or out).
// No LDS, no clamp (|v*qs|<=127 by construction), rowmax = 2 shfl_xor.
// ---------------------------------------------------------------------------
template<bool IN_BF16, bool OUT_BF16, bool RELU>
__global__ __launch_bounds__(256) void fused_kernel(const void* __restrict__ xin,
                                                    const ushort* __restrict__ WB,
                                                    const ushort* __restrict__ RB,
                                                    const float* __restrict__ bias,
                                                    char* __restrict__ tab,
                                                    float* __restrict__ scl,
                                                    void* __restrict__ outv) {
    const int wv = threadIdx.x >> 6;
    const int l  = threadIdx.x & 63;
    const int wt = blockIdx.x * 4 + wv;
    if (wt >= NWT) return;
    const int nbase = wt * 16;
    const int lm = l & 15;
    const int kg = l >> 4;
    const int node = nbase + lm;

    // x row fragments for all 4 K-blocks (shared by both parts)
    s8v bfr[4];
#pragma unroll
    for (int b = 0; b < 4; ++b) {
        if (IN_BF16) {
            const ushort* xp = (const ushort*)xin + (size_t)node * DIM + b * BS + kg * 8;
            u8v u = *(const u8v*)xp;
#pragma unroll
            for (int i = 0; i < 8; ++i) {
                unsigned short us = u[i];
                if (RELU) us = (us & 0x8000u) ? (unsigned short)0 : us;
                bfr[b][i] = (short)us;
            }
        } else {
            const float* xp = (const float*)xin + (size_t)node * DIM + b * BS + kg * 8;
#pragma unroll
            for (int i = 0; i < 8; ++i) {
                float v = xp[i];
                if (RELU) v = fmaxf(v, 0.f);
                bfr[b][i] = (short)f2bfbits(v);
            }
        }
    }

    // ---- part 1: int8 message table, all 16 relations ----
#pragma unroll 2
    for (int rr = 0; rr < N_REL; ++rr) {
        f4v acc[4][2];
#pragma unroll
        for (int b = 0; b < 4; ++b) {
#pragma unroll
            for (int mt = 0; mt < 2; ++mt) {
                s8v afrag = *(const s8v*)&WB[((((rr * 4 + b) * 2 + mt) * 4 + kg) * 16 + lm) * 8];
                f4v z = {0.f, 0.f, 0.f, 0.f};
                acc[b][mt] = __builtin_amdgcn_mfma_f32_16x16x32_bf16(afrag, bfr[b], z, 0, 0, 0);
            }
        }
        // rowmax over the node's 128 values (32 in-lane + across 4 kg lanes)
        float m = 0.f;
#pragma unroll
        for (int b = 0; b < 4; ++b)
#pragma unroll
            for (int mt = 0; mt < 2; ++mt)
#pragma unroll
                for (int j = 0; j < 4; ++j)
                    m = fmaxf(m, fabsf(acc[b][mt][j]));
        m = fmaxf(m, __shfl_xor(m, 16, 64));
        m = fmaxf(m, __shfl_xor(m, 32, 64));
        m = fmaxf(m, 1e-30f);
        const float qs = 127.0f / m;

        unsigned int d[8];
#pragma unroll
        for (int b = 0; b < 4; ++b) {
#pragma unroll
            for (int mt = 0; mt < 2; ++mt) {
                int q0 = __float2int_rn(acc[b][mt][0] * qs);
                int q1 = __float2int_rn(acc[b][mt][1] * qs);
                int q2 = __float2int_rn(acc[b][mt][2] * qs);
                int q3 = __float2int_rn(acc[b][mt][3] * qs);
                unsigned int t01 = __builtin_amdgcn_perm((unsigned)q1, (unsigned)q0, 0x00000400u);
                unsigned int t23 = __builtin_amdgcn_perm((unsigned)q3, (unsigned)q2, 0x00000400u);
                d[b * 2 + mt] = __builtin_amdgcn_perm(t23, t01, 0x05040100u);
            }
        }
        char* gp = tab + ((size_t)rr * N_NODES + node) * 128 + kg * 32;
        *(uint4*)gp        = make_uint4(d[0], d[1], d[2], d[3]);
        *(uint4*)(gp + 16) = make_uint4(d[4], d[5], d[6], d[7]);
        if (kg == 0) scl[rr * N_NODES + node] = m * (1.0f / 127.0f);
    }

    // ---- part 2: root GEMM + bias -> dense layer output ----
#pragma unroll 2
    for (int mt = 0; mt < 8; ++mt) {
        const int col0 = mt * 16 + kg * 4;
        f4v acc = *(const f4v*)&bias[col0];
#pragma unroll
        for (int kc = 0; kc < 4; ++kc) {
            s8v afrag = *(const s8v*)&RB[(((mt * 4 + kc) * 4 + kg) * 16 + lm) * 8];
            acc = __builtin_amdgcn_mfma_f32_16x16x32_bf16(afrag, bfr[kc], acc, 0, 0, 0);
        }
        if (OUT_BF16) {
            unsigned int p0 = (unsigned int)f2bfbits(acc[0]) |
                              ((unsigned int)f2bfbits(acc[1]) << 16);
            unsigned int p1 = (unsigned int)f2bfbits(acc[2]) |
                              ((unsigned int)f2bfbits(acc[3]) << 16);
            *(uint2*)((ushort*)outv + (size_t)node * DIM + col0) = make_uint2(p0, p1);
        } else {
            *(f4v*)((float*)outv + (size_t)node * DIM + col0) = acc;
        }
    }
}

// ---------------------------------------------------------------------------
// Edge-stream aggregate over int8 table: half-wave per dst node; evec read
// directly (16-lane broadcast); 4 edges in flight x unroll 2; per edge one
// 128B contiguous row + 1 scale; dequant fma; final RMW maps the MFMA-
// natural byte order back to dims: lane w -> dims (w&3)*32+(w>>2)*4 (+16).
// ---------------------------------------------------------------------------
template<bool OUT_BF16>
__global__ __launch_bounds__(256) void agg8_kernel(const int2* __restrict__ evec,
                                                   const int* __restrict__ off,
                                                   const char* __restrict__ tab,
                                                   const float* __restrict__ scl,
                                                   void* __restrict__ outv) {
    const int hw = threadIdx.x >> 5;
    const int o  = threadIdx.x & 31;
    const int v  = blockIdx.x * 8 + hw;

    const int start = (v == 0) ? 0 : off[v * N_REL - 1];
    const int end   = off[v * N_REL + N_REL - 1];

    const int p = o >> 4;            // edge parity within the quad (0/1)
    const int w = o & 15;            // 8-byte sub-chunk of the 128B row

    float acc[8];
#pragma unroll
    for (int j = 0; j < 8; ++j) acc[j] = 0.f;

#pragma unroll 2
    for (int base = start; base < end; base += 4) {
        const int k0 = base + p;
        const int k1 = base + 2 + p;
        const int2 e0 = evec[min(k0, end - 1)];
        const int2 e1 = evec[min(k1, end - 1)];
        const int g0 = e0.x, g1 = e1.x;
        const float i0 = (k0 < end) ? __int_as_float(e0.y) : 0.f;
        const float i1 = (k1 < end) ? __int_as_float(e1.y) : 0.f;
        const uint2 q0 = *(const uint2*)(tab + (size_t)g0 * 128 + w * 8);
        const uint2 q1 = *(const uint2*)(tab + (size_t)g1 * 128 + w * 8);
        const float s0 = scl[g0] * i0;
        const float s1 = scl[g1] * i1;
#pragma unroll
        for (int j = 0; j < 4; ++j) {
            acc[j]     = fmaf((float)(int)(signed char)(q0.x >> (8 * j)), s0, acc[j]);
            acc[4 + j] = fmaf((float)(int)(signed char)(q0.y >> (8 * j)), s0, acc[4 + j]);
        }
#pragma unroll
        for (int j = 0; j < 4; ++j) {
            acc[j]     = fmaf((float)(int)(signed char)(q1.x >> (8 * j)), s1, acc[j]);
            acc[4 + j] = fmaf((float)(int)(signed char)(q1.y >> (8 * j)), s1, acc[4 + j]);
        }
    }
#pragma unroll
    for (int j = 0; j < 8; ++j)
        acc[j] += __shfl_xor(acc[j], 16, 32);

    if (o < 16) {
        const int base0 = (o & 3) * 32 + (o >> 2) * 4;     // dim of acc[0]
        if (OUT_BF16) {
            ushort* hp = (ushort*)outv + (size_t)v * DIM + base0;
            ushort4 a0 = *(ushort4*)hp;
            ushort4 a1 = *(ushort4*)(hp + 16);
            a0.x = f2bfbits(bf2f(a0.x) + acc[0]);
            a0.y = f2bfbits(bf2f(a0.y) + acc[1]);
            a0.z = f2bfbits(bf2f(a0.z) + acc[2]);
            a0.w = f2bfbits(bf2f(a0.w) + acc[3]);
            a1.x = f2bfbits(bf2f(a1.x) + acc[4]);
            a1.y = f2bfbits(bf2f(a1.y) + acc[5]);
            a1.z = f2bfbits(bf2f(a1.z) + acc[6]);
            a1.w = f2bfbits(bf2f(a1.w) + acc[7]);
            *(ushort4*)hp        = a0;
            *(ushort4*)(hp + 16) = a1;
        } else {
            float* op = (float*)outv + (size_t)v * DIM + base0;
            float4 r0 = *(float4*)op;
            float4 r1 = *(float4*)(op + 16);
            r0.x += acc[0]; r0.y += acc[1]; r0.z += acc[2]; r0.w += acc[3];
            r1.x += acc[4]; r1.y += acc[5]; r1.z += acc[6]; r1.w += acc[7];
            *(float4*)op        = r0;
            *(float4*)(op + 16) = r1;
        }
    }
}

// ---------------------------------------------------------------------------
// Slow fallback (tiny ws): fp32 dense + gather-aggregate on x directly.
// ---------------------------------------------------------------------------
template<bool RELU>
__global__ __launch_bounds__(256) void dense_old_kernel(const float* __restrict__ x,
                                                        const float* __restrict__ root,
                                                        const float* __restrict__ bias,
                                                        float* __restrict__ out) {
    const int wv = threadIdx.x >> 6;
    const int l  = threadIdx.x & 63;
    const int wt = blockIdx.x * 4 + wv;
    if (wt >= NWT) return;
    const int nbase = wt * 16;
    const int lm = l & 15;
    const int kg = l >> 4;
    const int node = nbase + lm;

    s8v bfr[4];
#pragma unroll
    for (int kc = 0; kc < 4; ++kc) {
        const float* xp = &x[(size_t)node * DIM + kc * BS + kg * 8];
#pragma unroll
        for (int i = 0; i < 8; ++i) {
            float v = xp[i];
            if (RELU) v = fmaxf(v, 0.f);
            bfr[kc][i] = (short)f2bfbits(v);
        }
    }
#pragma unroll 2
    for (int mt = 0; mt < 8; ++mt) {
        const int col0 = mt * 16 + kg * 4;
        f4v acc = *(const f4v*)&bias[col0];
#pragma unroll
        for (int kc = 0; kc < 4; ++kc) {
            const float* rp = &root[(size_t)(kc * BS + kg * 8) * DIM + mt * 16 + lm];
            s8v afrag;
#pragma unroll
            for (int i = 0; i < 8; ++i)
                afrag[i] = (short)f2bfbits(rp[i * DIM]);
            acc = __builtin_amdgcn_mfma_f32_16x16x32_bf16(afrag, bfr[kc], acc, 0, 0, 0);
        }
        *(f4v*)&out[(size_t)node * DIM + col0] = acc;
    }
}

template<bool RELU>
__global__ __launch_bounds__(256) void agg_fallback_kernel(const int* __restrict__ srcs,
                                                           const int* __restrict__ off,
                                                           const int* __restrict__ cnt,
                                                           const float* __restrict__ x,
                                                           const float* __restrict__ W,
                                                           float* __restrict__ out) {
    __shared__ float Wsh[N_REL * BS * BS];
    const int bblk = blockIdx.y;
    for (int idx = threadIdx.x * 4; idx < N_REL * BS * BS; idx += 1024) {
        int r = idx >> 10, rest = idx & 1023;
        *(float4*)&Wsh[idx] = *(const float4*)&W[(r * NBLK + bblk) * 1024 + rest];
    }
    __syncthreads();
    const int hw = threadIdx.x >> 5;
    const int o  = threadIdx.x & 31;
    const int v  = blockIdx.x * 8 + hw;
    int endv = 0, cv = 0;
    if (o < N_REL) { endv = off[v * N_REL + o]; cv = cnt[v * N_REL + o]; }
    float acc = out[v * DIM + bblk * BS + o];
    for (int r = 0; r < N_REL; ++r) {
        const int c = __shfl(cv, r, 32);
        if (c == 0) continue;
        const int end = __shfl(endv, r, 32);
        float xs = 0.f;
        for (int k = end - c; k < end; ++k) {
            const int s = srcs[k];
            float xv = x[s * DIM + bblk * BS + o];
            if (RELU) xv = fmaxf(xv, 0.f);
            xs += xv;
        }
        xs *= (1.0f / (float)c);
        const float* wr = &Wsh[r * (BS * BS)];
#pragma unroll
        for (int i = 0; i < BS; i += 2) {
            float xi0 = __shfl(xs, i, 32);
            float xi1 = __shfl(xs, i + 1, 32);
            acc = fmaf(xi0, wr[i * BS + o], acc);
            acc = fmaf(xi1, wr[(i + 1) * BS + o], acc);
        }
    }
    out[v * DIM + bblk * BS + o] = acc;
}

// ---------------------------------------------------------------------------
extern "C" void kernel_launch(void* const* d_in, const int* in_sizes, int n_in,
                              void* d_out, int out_size, void* d_ws, size_t ws_size,
                              hipStream_t stream) {
    const int*   edge_index = (const int*)d_in[0];
    const int*   src   = edge_index;
    const int*   dstv  = edge_index + N_EDGES;
    const int*   et    = (const int*)d_in[1];
    const float* x0    = (const float*)d_in[2];
    const float* W1    = (const float*)d_in[3];
    const float* root1 = (const float*)d_in[4];
    const float* bias1 = (const float*)d_in[5];
    const float* W2    = (const float*)d_in[6];
    const float* root2 = (const float*)d_in[7];
    const float* bias2 = (const float*)d_in[8];
    float* out = (float*)d_out;

    // ---- fast-path workspace layout (131.8 MB total; LLC-resident) ----
    char* ws = (char*)d_ws;
    ushort* h    = (ushort*)ws;                             // 12,800,000 (bf16)
    int*    cnt  = (int*)   (ws + 12800000);                //  3,200,000
    int*    off  = (int*)   (ws + 16000000);                //  3,200,000
    int2*   evec = (int2*)  (ws + 19200000);                //  6,400,000
    int*    bsum = (int*)   (ws + 25600000);                //      4,096
    ushort* WB1  = (ushort*)(ws + 25604096);                //    262,144
    ushort* WB2  = (ushort*)(ws + 25866240);                //    262,144
    ushort* RB1  = (ushort*)(ws + 26128384);                //     32,768
    ushort* RB2  = (ushort*)(ws + 26161152);                //     32,768
    float*  scl  = (float*) (ws + 26193920);                //  3,200,000
    char*   tab  =          (ws + 29393920);                // 102,400,000
    const size_t FAST_NEED = 131793920ull;

    const int egrid = (N_EDGES + 255) / 256;     // 3125
    const int tgrid = (NWT + 3) / 4;             // 782

    if (ws_size >= FAST_NEED) {
        prep_kernel<<<1152, 256, 0, stream>>>(W1, W2, root1, root2, WB1, WB2, RB1, RB2);
        hipMemsetAsync(cnt, 0, (size_t)NSEG * sizeof(int), stream);
        count_kernel<<<egrid, 256, 0, stream>>>(dstv, et, cnt, N_EDGES);
        scan1_kernel<<<N_SCAN_BLKS, 256, 0, stream>>>(cnt, off, bsum, NSEG);
        scan2_kernel<<<1, 1024, 0, stream>>>(bsum, N_SCAN_BLKS);
        scan3_kernel<<<(NSEG + 255) / 256, 256, 0, stream>>>(off, bsum, NSEG);
        scatter_fast_kernel<<<egrid, 256, 0, stream>>>(src, dstv, et, off, cnt, evec, N_EDGES);

        const int ngrid = N_NODES / 8;           // 6250

        // ---- layer 1: h(bf16) = x0@root1 + bias1 (dense) + int8 table ----
        fused_kernel<false, true, false><<<tgrid, 256, 0, stream>>>(
            x0, WB1, RB1, bias1, tab, scl, h);
        agg8_kernel<true><<<ngrid, 256, 0, stream>>>(evec, off, tab, scl, h);

        // ---- layer 2: out(fp32) = relu(h)@root2 + bias2 (dense) + table ----
        fused_kernel<true, false, true><<<tgrid, 256, 0, stream>>>(
            h, WB2, RB2, bias2, tab, scl, out);
        agg8_kernel<false><<<ngrid, 256, 0, stream>>>(evec, off, tab, scl, out);
    } else {
        // ---- slow fallback (ws >= 35.3 MB): fp32 h + direct gather-agg ----
        float* hf    = (float*)d_ws;
        int*   cntf  = (int*)((char*)d_ws + 25600000);
        int*   offf  = (int*)((char*)d_ws + 28800000);
        int*   srcsf = (int*)((char*)d_ws + 32000000);
        int*   bsumf = (int*)((char*)d_ws + 35200000);

        hipMemsetAsync(cntf, 0, (size_t)NSEG * sizeof(int), stream);
        count_kernel<<<egrid, 256, 0, stream>>>(dstv, et, cntf, N_EDGES);
        scan1_kernel<<<N_SCAN_BLKS, 256, 0, stream>>>(cntf, offf, bsumf, NSEG);
        scan2_kernel<<<1, 1024, 0, stream>>>(bsumf, N_SCAN_BLKS);
        scan3_kernel<<<(NSEG + 255) / 256, 256, 0, stream>>>(offf, bsumf, NSEG);
        scatter_old_kernel<<<egrid, 256, 0, stream>>>(src, dstv, et, offf, srcsf, N_EDGES);

        dim3 fgrid(N_NODES / 8, NBLK);
        dense_old_kernel<false><<<tgrid, 256, 0, stream>>>(x0, root1, bias1, hf);
        agg_fallback_kernel<false><<<fgrid, 256, 0, stream>>>(srcsf, offf, cntf, x0, W1, hf);
        dense_old_kernel<true><<<tgrid, 256, 0, stream>>>(hf, root2, bias2, out);
        agg_fallback_kernel<true><<<fgrid, 256, 0, stream>>>(srcsf, offf, cntf, hf, W2, out);
    }
}

// Round 9
// 248.680 us; speedup vs baseline: 10.2519x; 1.0188x over previous
//
#include <hip/hip_runtime.h>
#include <hip/hip_bf16.h>

#define N_NODES 50000
#define N_REL   16
#define DIM     128
#define NBLK    4
#define BS      32
#define N_EDGES 800000
#define NSEG    (N_NODES * N_REL)
#define SCAN_BLK 1024
#define N_SCAN_BLKS ((NSEG + SCAN_BLK - 1) / SCAN_BLK)
#define NWT     (N_NODES / 16)        // 3125 wave-tiles of 16 nodes

typedef __attribute__((ext_vector_type(8))) short s8v;            // 8 bf16
typedef __attribute__((ext_vector_type(8))) unsigned short u8v;   // 8 bf16 bits
typedef __attribute__((ext_vector_type(4))) float f4v;            // mfma C/D

__device__ __forceinline__ float bf2f(unsigned short u) {
    return __uint_as_float(((unsigned int)u) << 16);
}
__device__ __forceinline__ unsigned short f2bfbits(float f) {   // RNE
    unsigned int u = __float_as_uint(f);
    return (unsigned short)((u + 0x7fffu + ((u >> 16) & 1u)) >> 16);
}

// ---------------------------------------------------------------------------
// CSR build: count -> scan -> scatter(evec = {gidx, inv})
// ---------------------------------------------------------------------------
__global__ __launch_bounds__(256) void count_kernel(const int* __restrict__ dst,
                                                    const int* __restrict__ et,
                                                    int* __restrict__ cnt, int E) {
    int e = blockIdx.x * 256 + threadIdx.x;
    if (e < E) atomicAdd(&cnt[dst[e] * N_REL + et[e]], 1);
}

__global__ __launch_bounds__(256) void scan1_kernel(const int* __restrict__ in,
                                                    int* __restrict__ out,
                                                    int* __restrict__ bsum, int M) {
    const int t = threadIdx.x;
    const int base = blockIdx.x * SCAN_BLK + t * 4;
    int v0 = (base + 0 < M) ? in[base + 0] : 0;
    int v1 = (base + 1 < M) ? in[base + 1] : 0;
    int v2 = (base + 2 < M) ? in[base + 2] : 0;
    int v3 = (base + 3 < M) ? in[base + 3] : 0;
    const int s = v0 + v1 + v2 + v3;
    const int lane = t & 63, wid = t >> 6;
    int inc = s;
    for (int d = 1; d < 64; d <<= 1) {
        int u = __shfl_up(inc, d, 64);
        if (lane >= d) inc += u;
    }
    __shared__ int wsum[5];
    if (lane == 63) wsum[wid] = inc;
    __syncthreads();
    if (t == 0) {
        int a = 0;
        for (int w = 0; w < 4; ++w) { int u = wsum[w]; wsum[w] = a; a += u; }
        wsum[4] = a;
    }
    __syncthreads();
    const int ex = inc - s + wsum[wid];
    if (base + 0 < M) out[base + 0] = ex;
    if (base + 1 < M) out[base + 1] = ex + v0;
    if (base + 2 < M) out[base + 2] = ex + v0 + v1;
    if (base + 3 < M) out[base + 3] = ex + v0 + v1 + v2;
    if (t == 0) bsum[blockIdx.x] = wsum[4];
}

__global__ __launch_bounds__(1024) void scan2_kernel(int* __restrict__ bsum, int nb) {
    const int t = threadIdx.x;
    int s = (t < nb) ? bsum[t] : 0;
    const int lane = t & 63, wid = t >> 6;
    int inc = s;
    for (int d = 1; d < 64; d <<= 1) {
        int u = __shfl_up(inc, d, 64);
        if (lane >= d) inc += u;
    }
    __shared__ int wsum[16];
    if (lane == 63) wsum[wid] = inc;
    __syncthreads();
    if (t == 0) {
        int a = 0;
        for (int w = 0; w < 16; ++w) { int u = wsum[w]; wsum[w] = a; a += u; }
    }
    __syncthreads();
    const int ex = inc - s + wsum[wid];
    if (t < nb) bsum[t] = ex;
}

__global__ __launch_bounds__(256) void scan3_kernel(int* __restrict__ out,
                                                    const int* __restrict__ bsum, int M) {
    int i = blockIdx.x * 256 + threadIdx.x;
    if (i < M) out[i] += bsum[i / SCAN_BLK];
}

// fast path: emit per-edge {gather-row, 1/c} in CSR position; row = r*N + src
__global__ __launch_bounds__(256) void scatter_fast_kernel(const int* __restrict__ src,
                                                           const int* __restrict__ dst,
                                                           const int* __restrict__ et,
                                                           int* __restrict__ off,
                                                           const int* __restrict__ cnt,
                                                           int2* __restrict__ evec, int E) {
    int e = blockIdx.x * 256 + threadIdx.x;
    if (e < E) {
        int r = et[e];
        int seg = dst[e] * N_REL + r;
        int pos = atomicAdd(&off[seg], 1);
        float inv = 1.0f / (float)cnt[seg];
        evec[pos] = make_int2(r * N_NODES + src[e], __float_as_int(inv));
    }
}

// slow-fallback scatter (srcs list)
__global__ __launch_bounds__(256) void scatter_old_kernel(const int* __restrict__ src,
                                                          const int* __restrict__ dst,
                                                          const int* __restrict__ et,
                                                          int* __restrict__ off,
                                                          int* __restrict__ srcs, int E) {
    int e = blockIdx.x * 256 + threadIdx.x;
    if (e < E) {
        int seg = dst[e] * N_REL + et[e];
        int pos = atomicAdd(&off[seg], 1);
        srcs[pos] = src[e];
    }
}

// ---------------------------------------------------------------------------
// Prep: convert W1,W2,root1,root2 to bf16 in A-fragment lane order.
// WB idx = ((((r*4+b)*2+mt)*4+kg)*16+lm)*8+i  <- W[r][b][kg*8+i][mt*16+lm]
// RB idx = (((mt*4+kc)*4+kg)*16+lm)*8+i       <- root[kc*32+kg*8+i][mt*16+lm]
// ---------------------------------------------------------------------------
__global__ __launch_bounds__(256) void prep_kernel(const float* __restrict__ W1,
                                                   const float* __restrict__ W2,
                                                   const float* __restrict__ r1,
                                                   const float* __restrict__ r2,
                                                   ushort* __restrict__ WB1,
                                                   ushort* __restrict__ WB2,
                                                   ushort* __restrict__ RB1,
                                                   ushort* __restrict__ RB2) {
    int t = blockIdx.x * 256 + threadIdx.x;
    if (t < 262144) {                               // WB1 / WB2
        const float* W = (t < 131072) ? W1 : W2;
        ushort* WB     = (t < 131072) ? WB1 : WB2;
        int idx = t & 131071;
        int i  = idx & 7;
        int lm = (idx >> 3) & 15;
        int kg = (idx >> 7) & 3;
        int mt = (idx >> 9) & 1;
        int b  = (idx >> 10) & 3;
        int r  = idx >> 12;
        WB[idx] = f2bfbits(W[((size_t)(r * 4 + b) * 32 + kg * 8 + i) * 32 + mt * 16 + lm]);
    } else if (t < 294912) {                        // RB1 / RB2
        int u = t - 262144;
        const float* R = (u < 16384) ? r1 : r2;
        ushort* RB     = (u < 16384) ? RB1 : RB2;
        int idx = u & 16383;
        int i  = idx & 7;
        int lm = (idx >> 3) & 15;
        int kg = (idx >> 7) & 3;
        int kc = (idx >> 9) & 3;
        int mt = (idx >> 11) & 7;
        RB[idx] = f2bfbits(R[(size_t)(kc * 32 + kg * 8 + i) * DIM + mt * 16 + lm]);
    }
}

// ---------------------------------------------------------------------------
// FUSED transform, relation-split across blockIdx.y (8 rels per y) to double
// resident waves. Per wave-tile of 16 nodes: load x-row fragments once, then
// (a) int8 message table for rels [y*8, y*8+8)  (MFMA-natural byte order:
//     tab[(r*N+node)*128 + kg*32 + b*8+mt*4+j]),
// (b) y==0 only: root GEMM + bias -> dense part of the layer output.
// No LDS, no clamp (|v*qs|<=127 by construction), rowmax = 2 shfl_xor.
// ---------------------------------------------------------------------------
template<bool IN_BF16, bool OUT_BF16, bool RELU>
__global__ __launch_bounds__(256) void fused_kernel(const void* __restrict__ xin,
                                                    const ushort* __restrict__ WB,
                                                    const ushort* __restrict__ RB,
                                                    const float* __restrict__ bias,
                                                    char* __restrict__ tab,
                                                    float* __restrict__ scl,
                                                    void* __restrict__ outv) {
    const int wv = threadIdx.x >> 6;
    const int l  = threadIdx.x & 63;
    const int wt = blockIdx.x * 4 + wv;
    if (wt >= NWT) return;
    const int rbase = blockIdx.y * 8;
    const int nbase = wt * 16;
    const int lm = l & 15;
    const int kg = l >> 4;
    const int node = nbase + lm;

    // x row fragments for all 4 K-blocks (shared by both parts)
    s8v bfr[4];
#pragma unroll
    for (int b = 0; b < 4; ++b) {
        if (IN_BF16) {
            const ushort* xp = (const ushort*)xin + (size_t)node * DIM + b * BS + kg * 8;
            u8v u = *(const u8v*)xp;
#pragma unroll
            for (int i = 0; i < 8; ++i) {
                unsigned short us = u[i];
                if (RELU) us = (us & 0x8000u) ? (unsigned short)0 : us;
                bfr[b][i] = (short)us;
            }
        } else {
            const float* xp = (const float*)xin + (size_t)node * DIM + b * BS + kg * 8;
#pragma unroll
            for (int i = 0; i < 8; ++i) {
                float v = xp[i];
                if (RELU) v = fmaxf(v, 0.f);
                bfr[b][i] = (short)f2bfbits(v);
            }
        }
    }

    // ---- part 1: int8 message table, 8 relations for this y ----
#pragma unroll 2
    for (int ri = 0; ri < 8; ++ri) {
        const int rr = rbase + ri;
        f4v acc[4][2];
#pragma unroll
        for (int b = 0; b < 4; ++b) {
#pragma unroll
            for (int mt = 0; mt < 2; ++mt) {
                s8v afrag = *(const s8v*)&WB[((((rr * 4 + b) * 2 + mt) * 4 + kg) * 16 + lm) * 8];
                f4v z = {0.f, 0.f, 0.f, 0.f};
                acc[b][mt] = __builtin_amdgcn_mfma_f32_16x16x32_bf16(afrag, bfr[b], z, 0, 0, 0);
            }
        }
        // rowmax over the node's 128 values (32 in-lane + across 4 kg lanes)
        float m = 0.f;
#pragma unroll
        for (int b = 0; b < 4; ++b)
#pragma unroll
            for (int mt = 0; mt < 2; ++mt)
#pragma unroll
                for (int j = 0; j < 4; ++j)
                    m = fmaxf(m, fabsf(acc[b][mt][j]));
        m = fmaxf(m, __shfl_xor(m, 16, 64));
        m = fmaxf(m, __shfl_xor(m, 32, 64));
        m = fmaxf(m, 1e-30f);
        const float qs = 127.0f / m;

        unsigned int d[8];
#pragma unroll
        for (int b = 0; b < 4; ++b) {
#pragma unroll
            for (int mt = 0; mt < 2; ++mt) {
                int q0 = __float2int_rn(acc[b][mt][0] * qs);
                int q1 = __float2int_rn(acc[b][mt][1] * qs);
                int q2 = __float2int_rn(acc[b][mt][2] * qs);
                int q3 = __float2int_rn(acc[b][mt][3] * qs);
                unsigned int t01 = __builtin_amdgcn_perm((unsigned)q1, (unsigned)q0, 0x00000400u);
                unsigned int t23 = __builtin_amdgcn_perm((unsigned)q3, (unsigned)q2, 0x00000400u);
                d[b * 2 + mt] = __builtin_amdgcn_perm(t23, t01, 0x05040100u);
            }
        }
        char* gp = tab + ((size_t)rr * N_NODES + node) * 128 + kg * 32;
        *(uint4*)gp        = make_uint4(d[0], d[1], d[2], d[3]);
        *(uint4*)(gp + 16) = make_uint4(d[4], d[5], d[6], d[7]);
        if (kg == 0) scl[rr * N_NODES + node] = m * (1.0f / 127.0f);
    }

    // ---- part 2 (y==0 only): root GEMM + bias -> dense layer output ----
    if (blockIdx.y == 0) {
#pragma unroll 2
        for (int mt = 0; mt < 8; ++mt) {
            const int col0 = mt * 16 + kg * 4;
            f4v acc = *(const f4v*)&bias[col0];
#pragma unroll
            for (int kc = 0; kc < 4; ++kc) {
                s8v afrag = *(const s8v*)&RB[(((mt * 4 + kc) * 4 + kg) * 16 + lm) * 8];
                acc = __builtin_amdgcn_mfma_f32_16x16x32_bf16(afrag, bfr[kc], acc, 0, 0, 0);
            }
            if (OUT_BF16) {
                unsigned int p0 = (unsigned int)f2bfbits(acc[0]) |
                                  ((unsigned int)f2bfbits(acc[1]) << 16);
                unsigned int p1 = (unsigned int)f2bfbits(acc[2]) |
                                  ((unsigned int)f2bfbits(acc[3]) << 16);
                *(uint2*)((ushort*)outv + (size_t)node * DIM + col0) = make_uint2(p0, p1);
            } else {
                *(f4v*)((float*)outv + (size_t)node * DIM + col0) = acc;
            }
        }
    }
}

// ---------------------------------------------------------------------------
// Edge-stream aggregate over int8 table: half-wave per dst node; evec read
// directly (16-lane broadcast); 4 edges in flight x unroll 2; per edge one
// 128B contiguous row + 1 scale; dequant fma; final RMW maps the MFMA-
// natural byte order back to dims: lane w -> dims (w&3)*32+(w>>2)*4 (+16).
// ---------------------------------------------------------------------------
template<bool OUT_BF16>
__global__ __launch_bounds__(256) void agg8_kernel(const int2* __restrict__ evec,
                                                   const int* __restrict__ off,
                                                   const char* __restrict__ tab,
                                                   const float* __restrict__ scl,
                                                   void* __restrict__ outv) {
    const int hw = threadIdx.x >> 5;
    const int o  = threadIdx.x & 31;
    const int v  = blockIdx.x * 8 + hw;

    const int start = (v == 0) ? 0 : off[v * N_REL - 1];
    const int end   = off[v * N_REL + N_REL - 1];

    const int p = o >> 4;            // edge parity within the quad (0/1)
    const int w = o & 15;            // 8-byte sub-chunk of the 128B row

    float acc[8];
#pragma unroll
    for (int j = 0; j < 8; ++j) acc[j] = 0.f;

#pragma unroll 2
    for (int base = start; base < end; base += 4) {
        const int k0 = base + p;
        const int k1 = base + 2 + p;
        const int2 e0 = evec[min(k0, end - 1)];
        const int2 e1 = evec[min(k1, end - 1)];
        const int g0 = e0.x, g1 = e1.x;
        const float i0 = (k0 < end) ? __int_as_float(e0.y) : 0.f;
        const float i1 = (k1 < end) ? __int_as_float(e1.y) : 0.f;
        const uint2 q0 = *(const uint2*)(tab + (size_t)g0 * 128 + w * 8);
        const uint2 q1 = *(const uint2*)(tab + (size_t)g1 * 128 + w * 8);
        const float s0 = scl[g0] * i0;
        const float s1 = scl[g1] * i1;
#pragma unroll
        for (int j = 0; j < 4; ++j) {
            acc[j]     = fmaf((float)(int)(signed char)(q0.x >> (8 * j)), s0, acc[j]);
            acc[4 + j] = fmaf((float)(int)(signed char)(q0.y >> (8 * j)), s0, acc[4 + j]);
        }
#pragma unroll
        for (int j = 0; j < 4; ++j) {
            acc[j]     = fmaf((float)(int)(signed char)(q1.x >> (8 * j)), s1, acc[j]);
            acc[4 + j] = fmaf((float)(int)(signed char)(q1.y >> (8 * j)), s1, acc[4 + j]);
        }
    }
#pragma unroll
    for (int j = 0; j < 8; ++j)
        acc[j] += __shfl_xor(acc[j], 16, 32);

    if (o < 16) {
        const int base0 = (o & 3) * 32 + (o >> 2) * 4;     // dim of acc[0]
        if (OUT_BF16) {
            ushort* hp = (ushort*)outv + (size_t)v * DIM + base0;
            ushort4 a0 = *(ushort4*)hp;
            ushort4 a1 = *(ushort4*)(hp + 16);
            a0.x = f2bfbits(bf2f(a0.x) + acc[0]);
            a0.y = f2bfbits(bf2f(a0.y) + acc[1]);
            a0.z = f2bfbits(bf2f(a0.z) + acc[2]);
            a0.w = f2bfbits(bf2f(a0.w) + acc[3]);
            a1.x = f2bfbits(bf2f(a1.x) + acc[4]);
            a1.y = f2bfbits(bf2f(a1.y) + acc[5]);
            a1.z = f2bfbits(bf2f(a1.z) + acc[6]);
            a1.w = f2bfbits(bf2f(a1.w) + acc[7]);
            *(ushort4*)hp        = a0;
            *(ushort4*)(hp + 16) = a1;
        } else {
            float* op = (float*)outv + (size_t)v * DIM + base0;
            float4 r0 = *(float4*)op;
            float4 r1 = *(float4*)(op + 16);
            r0.x += acc[0]; r0.y += acc[1]; r0.z += acc[2]; r0.w += acc[3];
            r1.x += acc[4]; r1.y += acc[5]; r1.z += acc[6]; r1.w += acc[7];
            *(float4*)op        = r0;
            *(float4*)(op + 16) = r1;
        }
    }
}

// ---------------------------------------------------------------------------
// Slow fallback (tiny ws): fp32 dense + gather-aggregate on x directly.
// ---------------------------------------------------------------------------
template<bool RELU>
__global__ __launch_bounds__(256) void dense_old_kernel(const float* __restrict__ x,
                                                        const float* __restrict__ root,
                                                        const float* __restrict__ bias,
                                                        float* __restrict__ out) {
    const int wv = threadIdx.x >> 6;
    const int l  = threadIdx.x & 63;
    const int wt = blockIdx.x * 4 + wv;
    if (wt >= NWT) return;
    const int nbase = wt * 16;
    const int lm = l & 15;
    const int kg = l >> 4;
    const int node = nbase + lm;

    s8v bfr[4];
#pragma unroll
    for (int kc = 0; kc < 4; ++kc) {
        const float* xp = &x[(size_t)node * DIM + kc * BS + kg * 8];
#pragma unroll
        for (int i = 0; i < 8; ++i) {
            float v = xp[i];
            if (RELU) v = fmaxf(v, 0.f);
            bfr[kc][i] = (short)f2bfbits(v);
        }
    }
#pragma unroll 2
    for (int mt = 0; mt < 8; ++mt) {
        const int col0 = mt * 16 + kg * 4;
        f4v acc = *(const f4v*)&bias[col0];
#pragma unroll
        for (int kc = 0; kc < 4; ++kc) {
            const float* rp = &root[(size_t)(kc * BS + kg * 8) * DIM + mt * 16 + lm];
            s8v afrag;
#pragma unroll
            for (int i = 0; i < 8; ++i)
                afrag[i] = (short)f2bfbits(rp[i * DIM]);
            acc = __builtin_amdgcn_mfma_f32_16x16x32_bf16(afrag, bfr[kc], acc, 0, 0, 0);
        }
        *(f4v*)&out[(size_t)node * DIM + col0] = acc;
    }
}

template<bool RELU>
__global__ __launch_bounds__(256) void agg_fallback_kernel(const int* __restrict__ srcs,
                                                           const int* __restrict__ off,
                                                           const int* __restrict__ cnt,
                                                           const float* __restrict__ x,
                                                           const float* __restrict__ W,
                                                           float* __restrict__ out) {
    __shared__ float Wsh[N_REL * BS * BS];
    const int bblk = blockIdx.y;
    for (int idx = threadIdx.x * 4; idx < N_REL * BS * BS; idx += 1024) {
        int r = idx >> 10, rest = idx & 1023;
        *(float4*)&Wsh[idx] = *(const float4*)&W[(r * NBLK + bblk) * 1024 + rest];
    }
    __syncthreads();
    const int hw = threadIdx.x >> 5;
    const int o  = threadIdx.x & 31;
    const int v  = blockIdx.x * 8 + hw;
    int endv = 0, cv = 0;
    if (o < N_REL) { endv = off[v * N_REL + o]; cv = cnt[v * N_REL + o]; }
    float acc = out[v * DIM + bblk * BS + o];
    for (int r = 0; r < N_REL; ++r) {
        const int c = __shfl(cv, r, 32);
        if (c == 0) continue;
        const int end = __shfl(endv, r, 32);
        float xs = 0.f;
        for (int k = end - c; k < end; ++k) {
            const int s = srcs[k];
            float xv = x[s * DIM + bblk * BS + o];
            if (RELU) xv = fmaxf(xv, 0.f);
            xs += xv;
        }
        xs *= (1.0f / (float)c);
        const float* wr = &Wsh[r * (BS * BS)];
#pragma unroll
        for (int i = 0; i < BS; i += 2) {
            float xi0 = __shfl(xs, i, 32);
            float xi1 = __shfl(xs, i + 1, 32);
            acc = fmaf(xi0, wr[i * BS + o], acc);
            acc = fmaf(xi1, wr[(i + 1) * BS + o], acc);
        }
    }
    out[v * DIM + bblk * BS + o] = acc;
}

// ---------------------------------------------------------------------------
extern "C" void kernel_launch(void* const* d_in, const int* in_sizes, int n_in,
                              void* d_out, int out_size, void* d_ws, size_t ws_size,
                              hipStream_t stream) {
    const int*   edge_index = (const int*)d_in[0];
    const int*   src   = edge_index;
    const int*   dstv  = edge_index + N_EDGES;
    const int*   et    = (const int*)d_in[1];
    const float* x0    = (const float*)d_in[2];
    const float* W1    = (const float*)d_in[3];
    const float* root1 = (const float*)d_in[4];
    const float* bias1 = (const float*)d_in[5];
    const float* W2    = (const float*)d_in[6];
    const float* root2 = (const float*)d_in[7];
    const float* bias2 = (const float*)d_in[8];
    float* out = (float*)d_out;

    // ---- fast-path workspace layout (131.8 MB total; LLC-resident) ----
    char* ws = (char*)d_ws;
    ushort* h    = (ushort*)ws;                             // 12,800,000 (bf16)
    int*    cnt  = (int*)   (ws + 12800000);                //  3,200,000
    int*    off  = (int*)   (ws + 16000000);                //  3,200,000
    int2*   evec = (int2*)  (ws + 19200000);                //  6,400,000
    int*    bsum = (int*)   (ws + 25600000);                //      4,096
    ushort* WB1  = (ushort*)(ws + 25604096);                //    262,144
    ushort* WB2  = (ushort*)(ws + 25866240);                //    262,144
    ushort* RB1  = (ushort*)(ws + 26128384);                //     32,768
    ushort* RB2  = (ushort*)(ws + 26161152);                //     32,768
    float*  scl  = (float*) (ws + 26193920);                //  3,200,000
    char*   tab  =          (ws + 29393920);                // 102,400,000
    const size_t FAST_NEED = 131793920ull;

    const int egrid = (N_EDGES + 255) / 256;     // 3125
    const int tgrid = (NWT + 3) / 4;             // 782

    if (ws_size >= FAST_NEED) {
        prep_kernel<<<1152, 256, 0, stream>>>(W1, W2, root1, root2, WB1, WB2, RB1, RB2);
        hipMemsetAsync(cnt, 0, (size_t)NSEG * sizeof(int), stream);
        count_kernel<<<egrid, 256, 0, stream>>>(dstv, et, cnt, N_EDGES);
        scan1_kernel<<<N_SCAN_BLKS, 256, 0, stream>>>(cnt, off, bsum, NSEG);
        scan2_kernel<<<1, 1024, 0, stream>>>(bsum, N_SCAN_BLKS);
        scan3_kernel<<<(NSEG + 255) / 256, 256, 0, stream>>>(off, bsum, NSEG);
        scatter_fast_kernel<<<egrid, 256, 0, stream>>>(src, dstv, et, off, cnt, evec, N_EDGES);

        dim3 fgrid(tgrid, 2);                    // relation-split: 2x waves
        const int ngrid = N_NODES / 8;           // 6250

        // ---- layer 1: h(bf16) = x0@root1 + bias1 (dense) + int8 table ----
        fused_kernel<false, true, false><<<fgrid, 256, 0, stream>>>(
            x0, WB1, RB1, bias1, tab, scl, h);
        agg8_kernel<true><<<ngrid, 256, 0, stream>>>(evec, off, tab, scl, h);

        // ---- layer 2: out(fp32) = relu(h)@root2 + bias2 (dense) + table ----
        fused_kernel<true, false, true><<<fgrid, 256, 0, stream>>>(
            h, WB2, RB2, bias2, tab, scl, out);
        agg8_kernel<false><<<ngrid, 256, 0, stream>>>(evec, off, tab, scl, out);
    } else {
        // ---- slow fallback (ws >= 35.3 MB): fp32 h + direct gather-agg ----
        float* hf    = (float*)d_ws;
        int*   cntf  = (int*)((char*)d_ws + 25600000);
        int*   offf  = (int*)((char*)d_ws + 28800000);
        int*   srcsf = (int*)((char*)d_ws + 32000000);
        int*   bsumf = (int*)((char*)d_ws + 35200000);

        hipMemsetAsync(cntf, 0, (size_t)NSEG * sizeof(int), stream);
        count_kernel<<<egrid, 256, 0, stream>>>(dstv, et, cntf, N_EDGES);
        scan1_kernel<<<N_SCAN_BLKS, 256, 0, stream>>>(cntf, offf, bsumf, NSEG);
        scan2_kernel<<<1, 1024, 0, stream>>>(bsumf, N_SCAN_BLKS);
        scan3_kernel<<<(NSEG + 255) / 256, 256, 0, stream>>>(offf, bsumf, NSEG);
        scatter_old_kernel<<<egrid, 256, 0, stream>>>(src, dstv, et, offf, srcsf, N_EDGES);

        dim3 fgrid2(N_NODES / 8, NBLK);
        dense_old_kernel<false><<<tgrid, 256, 0, stream>>>(x0, root1, bias1, hf);
        agg_fallback_kernel<false><<<fgrid2, 256, 0, stream>>>(srcsf, offf, cntf, x0, W1, hf);
        dense_old_kernel<true><<<tgrid, 256, 0, stream>>>(hf, root2, bias2, out);
        agg_fallback_kernel<true><<<fgrid2, 256, 0, stream>>>(srcsf, offf, cntf, hf, W2, out);
    }
}

// Round 10
// 246.223 us; speedup vs baseline: 10.3542x; 1.0100x over previous
//
#include <hip/hip_runtime.h>
#include <hip/hip_bf16.h>

#define N_NODES 50000
#define N_REL   16
#define DIM     128
#define NBLK    4
#define BS      32
#define N_EDGES 800000
#define NSEG    (N_NODES * N_REL)
#define SCAN_BLK 1024
#define N_SCAN_BLKS ((NSEG + SCAN_BLK - 1) / SCAN_BLK)
#define NWT     (N_NODES / 16)        // 3125 wave-tiles of 16 nodes

typedef __attribute__((ext_vector_type(8))) short s8v;            // 8 bf16
typedef __attribute__((ext_vector_type(8))) unsigned short u8v;   // 8 bf16 bits
typedef __attribute__((ext_vector_type(4))) float f4v;            // mfma C/D

__device__ __forceinline__ float bf2f(unsigned short u) {
    return __uint_as_float(((unsigned int)u) << 16);
}
__device__ __forceinline__ unsigned short f2bfbits(float f) {   // RNE
    unsigned int u = __float_as_uint(f);
    return (unsigned short)((u + 0x7fffu + ((u >> 16) & 1u)) >> 16);
}

// ---------------------------------------------------------------------------
// CSR build: count (+used flag) -> joint scan {cnt,used} -> scatter(evec)
// ---------------------------------------------------------------------------
__global__ __launch_bounds__(256) void count_kernel(const int* __restrict__ src,
                                                    const int* __restrict__ dst,
                                                    const int* __restrict__ et,
                                                    int* __restrict__ cnt,
                                                    int* __restrict__ used, int E) {
    int e = blockIdx.x * 256 + threadIdx.x;
    if (e < E) {
        int r = et[e];
        atomicAdd(&cnt[dst[e] * N_REL + r], 1);
        used[r * N_NODES + src[e]] = 1;        // benign race, all write 1
    }
}

// joint exclusive scan of two int arrays (cnt -> off, used -> cmap)
__global__ __launch_bounds__(256) void scan1j_kernel(const int* __restrict__ cnt,
                                                     const int* __restrict__ used,
                                                     int* __restrict__ off,
                                                     int* __restrict__ cmap,
                                                     int2* __restrict__ bsum, int M) {
    const int t = threadIdx.x;
    const int base = blockIdx.x * SCAN_BLK + t * 4;
    int c[4], u[4];
#pragma unroll
    for (int i = 0; i < 4; ++i) {
        int idx = base + i;
        c[i] = (idx < M) ? cnt[idx] : 0;
        u[i] = (idx < M) ? used[idx] : 0;
    }
    int cs = c[0] + c[1] + c[2] + c[3];
    int us = u[0] + u[1] + u[2] + u[3];
    const int lane = t & 63, wid = t >> 6;
    int cinc = cs, uinc = us;
    for (int d = 1; d < 64; d <<= 1) {
        int a = __shfl_up(cinc, d, 64);
        int b = __shfl_up(uinc, d, 64);
        if (lane >= d) { cinc += a; uinc += b; }
    }
    __shared__ int cw[5], uw[5];
    if (lane == 63) { cw[wid] = cinc; uw[wid] = uinc; }
    __syncthreads();
    if (t == 0) {
        int a = 0, b = 0;
        for (int w = 0; w < 4; ++w) {
            int x = cw[w]; cw[w] = a; a += x;
            int y = uw[w]; uw[w] = b; b += y;
        }
        cw[4] = a; uw[4] = b;
    }
    __syncthreads();
    int cex = cinc - cs + cw[wid];
    int uex = uinc - us + uw[wid];
#pragma unroll
    for (int i = 0; i < 4; ++i) {
        int idx = base + i;
        if (idx < M) { off[idx] = cex; cmap[idx] = uex; }
        cex += c[i]; uex += u[i];
    }
    if (t == 0) bsum[blockIdx.x] = make_int2(cw[4], uw[4]);
}

__global__ __launch_bounds__(1024) void scan2j_kernel(int2* __restrict__ bsum, int nb) {
    const int t = threadIdx.x;
    int2 s = (t < nb) ? bsum[t] : make_int2(0, 0);
    const int lane = t & 63, wid = t >> 6;
    int ci = s.x, ui = s.y;
    for (int d = 1; d < 64; d <<= 1) {
        int a = __shfl_up(ci, d, 64);
        int b = __shfl_up(ui, d, 64);
        if (lane >= d) { ci += a; ui += b; }
    }
    __shared__ int cw[16], uw[16];
    if (lane == 63) { cw[wid] = ci; uw[wid] = ui; }
    __syncthreads();
    if (t == 0) {
        int a = 0, b = 0;
        for (int w = 0; w < 16; ++w) {
            int x = cw[w]; cw[w] = a; a += x;
            int y = uw[w]; uw[w] = b; b += y;
        }
    }
    __syncthreads();
    if (t < nb) bsum[t] = make_int2(ci - s.x + cw[wid], ui - s.y + uw[wid]);
}

__global__ __launch_bounds__(256) void scan3j_kernel(int* __restrict__ off,
                                                     int* __restrict__ cmap,
                                                     const int2* __restrict__ bsum, int M) {
    int i = blockIdx.x * 256 + threadIdx.x;
    if (i < M) {
        int2 b = bsum[i / SCAN_BLK];
        off[i] += b.x;
        cmap[i] += b.y;
    }
}

// emit per-edge {compact gather-row, 1/c} in CSR position
__global__ __launch_bounds__(256) void scatter_fast_kernel(const int* __restrict__ src,
                                                           const int* __restrict__ dst,
                                                           const int* __restrict__ et,
                                                           int* __restrict__ off,
                                                           const int* __restrict__ cnt,
                                                           const int* __restrict__ cmap,
                                                           int2* __restrict__ evec, int E) {
    int e = blockIdx.x * 256 + threadIdx.x;
    if (e < E) {
        int r = et[e];
        int seg = dst[e] * N_REL + r;
        int pos = atomicAdd(&off[seg], 1);
        float inv = 1.0f / (float)cnt[seg];
        int g = cmap[r * N_NODES + src[e]];
        evec[pos] = make_int2(g, __float_as_int(inv));
    }
}

// slow-fallback scan (single array) + scatter (srcs list)
__global__ __launch_bounds__(256) void scan1_kernel(const int* __restrict__ in,
                                                    int* __restrict__ out,
                                                    int* __restrict__ bsum, int M) {
    const int t = threadIdx.x;
    const int base = blockIdx.x * SCAN_BLK + t * 4;
    int v0 = (base + 0 < M) ? in[base + 0] : 0;
    int v1 = (base + 1 < M) ? in[base + 1] : 0;
    int v2 = (base + 2 < M) ? in[base + 2] : 0;
    int v3 = (base + 3 < M) ? in[base + 3] : 0;
    const int s = v0 + v1 + v2 + v3;
    const int lane = t & 63, wid = t >> 6;
    int inc = s;
    for (int d = 1; d < 64; d <<= 1) {
        int u = __shfl_up(inc, d, 64);
        if (lane >= d) inc += u;
    }
    __shared__ int wsum[5];
    if (lane == 63) wsum[wid] = inc;
    __syncthreads();
    if (t == 0) {
        int a = 0;
        for (int w = 0; w < 4; ++w) { int u = wsum[w]; wsum[w] = a; a += u; }
        wsum[4] = a;
    }
    __syncthreads();
    const int ex = inc - s + wsum[wid];
    if (base + 0 < M) out[base + 0] = ex;
    if (base + 1 < M) out[base + 1] = ex + v0;
    if (base + 2 < M) out[base + 2] = ex + v0 + v1;
    if (base + 3 < M) out[base + 3] = ex + v0 + v1 + v2;
    if (t == 0) bsum[blockIdx.x] = wsum[4];
}

__global__ __launch_bounds__(1024) void scan2_kernel(int* __restrict__ bsum, int nb) {
    const int t = threadIdx.x;
    int s = (t < nb) ? bsum[t] : 0;
    const int lane = t & 63, wid = t >> 6;
    int inc = s;
    for (int d = 1; d < 64; d <<= 1) {
        int u = __shfl_up(inc, d, 64);
        if (lane >= d) inc += u;
    }
    __shared__ int wsum[16];
    if (lane == 63) wsum[wid] = inc;
    __syncthreads();
    if (t == 0) {
        int a = 0;
        for (int w = 0; w < 16; ++w) { int u = wsum[w]; wsum[w] = a; a += u; }
    }
    __syncthreads();
    const int ex = inc - s + wsum[wid];
    if (t < nb) bsum[t] = ex;
}

__global__ __launch_bounds__(256) void scan3_kernel(int* __restrict__ out,
                                                    const int* __restrict__ bsum, int M) {
    int i = blockIdx.x * 256 + threadIdx.x;
    if (i < M) out[i] += bsum[i / SCAN_BLK];
}

__global__ __launch_bounds__(256) void scatter_old_kernel(const int* __restrict__ src,
                                                          const int* __restrict__ dst,
                                                          const int* __restrict__ et,
                                                          int* __restrict__ off,
                                                          int* __restrict__ srcs, int E) {
    int e = blockIdx.x * 256 + threadIdx.x;
    if (e < E) {
        int seg = dst[e] * N_REL + et[e];
        int pos = atomicAdd(&off[seg], 1);
        srcs[pos] = src[e];
    }
}

// ---------------------------------------------------------------------------
// Prep: convert W1,W2,root1,root2 to bf16 in A-fragment lane order.
// ---------------------------------------------------------------------------
__global__ __launch_bounds__(256) void prep_kernel(const float* __restrict__ W1,
                                                   const float* __restrict__ W2,
                                                   const float* __restrict__ r1,
                                                   const float* __restrict__ r2,
                                                   ushort* __restrict__ WB1,
                                                   ushort* __restrict__ WB2,
                                                   ushort* __restrict__ RB1,
                                                   ushort* __restrict__ RB2) {
    int t = blockIdx.x * 256 + threadIdx.x;
    if (t < 262144) {                               // WB1 / WB2
        const float* W = (t < 131072) ? W1 : W2;
        ushort* WB     = (t < 131072) ? WB1 : WB2;
        int idx = t & 131071;
        int i  = idx & 7;
        int lm = (idx >> 3) & 15;
        int kg = (idx >> 7) & 3;
        int mt = (idx >> 9) & 1;
        int b  = (idx >> 10) & 3;
        int r  = idx >> 12;
        WB[idx] = f2bfbits(W[((size_t)(r * 4 + b) * 32 + kg * 8 + i) * 32 + mt * 16 + lm]);
    } else if (t < 294912) {                        // RB1 / RB2
        int u = t - 262144;
        const float* R = (u < 16384) ? r1 : r2;
        ushort* RB     = (u < 16384) ? RB1 : RB2;
        int idx = u & 16383;
        int i  = idx & 7;
        int lm = (idx >> 3) & 15;
        int kg = (idx >> 7) & 3;
        int kc = (idx >> 9) & 3;
        int mt = (idx >> 11) & 7;
        RB[idx] = f2bfbits(R[(size_t)(kc * 32 + kg * 8 + i) * DIM + mt * 16 + lm]);
    }
}

// ---------------------------------------------------------------------------
// FUSED transform, relation-split across blockIdx.y; COMPACT table output:
// only rows with used[r*N+node]==1 are quantized+stored, at row cmap[...].
// ---------------------------------------------------------------------------
template<bool IN_BF16, bool OUT_BF16, bool RELU>
__global__ __launch_bounds__(256) void fused_kernel(const void* __restrict__ xin,
                                                    const ushort* __restrict__ WB,
                                                    const ushort* __restrict__ RB,
                                                    const float* __restrict__ bias,
                                                    const int* __restrict__ used,
                                                    const int* __restrict__ cmap,
                                                    char* __restrict__ tab,
                                                    float* __restrict__ scl,
                                                    void* __restrict__ outv) {
    const int wv = threadIdx.x >> 6;
    const int l  = threadIdx.x & 63;
    const int wt = blockIdx.x * 4 + wv;
    if (wt >= NWT) return;
    const int rbase = blockIdx.y * 8;
    const int nbase = wt * 16;
    const int lm = l & 15;
    const int kg = l >> 4;
    const int node = nbase + lm;

    // x row fragments for all 4 K-blocks (shared by both parts)
    s8v bfr[4];
#pragma unroll
    for (int b = 0; b < 4; ++b) {
        if (IN_BF16) {
            const ushort* xp = (const ushort*)xin + (size_t)node * DIM + b * BS + kg * 8;
            u8v u = *(const u8v*)xp;
#pragma unroll
            for (int i = 0; i < 8; ++i) {
                unsigned short us = u[i];
                if (RELU) us = (us & 0x8000u) ? (unsigned short)0 : us;
                bfr[b][i] = (short)us;
            }
        } else {
            const float* xp = (const float*)xin + (size_t)node * DIM + b * BS + kg * 8;
#pragma unroll
            for (int i = 0; i < 8; ++i) {
                float v = xp[i];
                if (RELU) v = fmaxf(v, 0.f);
                bfr[b][i] = (short)f2bfbits(v);
            }
        }
    }

    // ---- part 1: int8 message table, 8 relations for this y ----
#pragma unroll 2
    for (int ri = 0; ri < 8; ++ri) {
        const int rr = rbase + ri;
        const int grow = rr * N_NODES + node;
        const int flag = used[grow];            // hoisted: covers store latency
        const int cid  = cmap[grow];
        f4v acc[4][2];
#pragma unroll
        for (int b = 0; b < 4; ++b) {
#pragma unroll
            for (int mt = 0; mt < 2; ++mt) {
                s8v afrag = *(const s8v*)&WB[((((rr * 4 + b) * 2 + mt) * 4 + kg) * 16 + lm) * 8];
                f4v z = {0.f, 0.f, 0.f, 0.f};
                acc[b][mt] = __builtin_amdgcn_mfma_f32_16x16x32_bf16(afrag, bfr[b], z, 0, 0, 0);
            }
        }
        // rowmax over the node's 128 values (in-lane + across the 4 kg lanes)
        float m = 0.f;
#pragma unroll
        for (int b = 0; b < 4; ++b)
#pragma unroll
            for (int mt = 0; mt < 2; ++mt)
#pragma unroll
                for (int j = 0; j < 4; ++j)
                    m = fmaxf(m, fabsf(acc[b][mt][j]));
        m = fmaxf(m, __shfl_xor(m, 16, 64));
        m = fmaxf(m, __shfl_xor(m, 32, 64));
        m = fmaxf(m, 1e-30f);

        if (flag) {
            const float qs = 127.0f / m;
            unsigned int d[8];
#pragma unroll
            for (int b = 0; b < 4; ++b) {
#pragma unroll
                for (int mt = 0; mt < 2; ++mt) {
                    int q0 = __float2int_rn(acc[b][mt][0] * qs);
                    int q1 = __float2int_rn(acc[b][mt][1] * qs);
                    int q2 = __float2int_rn(acc[b][mt][2] * qs);
                    int q3 = __float2int_rn(acc[b][mt][3] * qs);
                    unsigned int t01 = __builtin_amdgcn_perm((unsigned)q1, (unsigned)q0, 0x00000400u);
                    unsigned int t23 = __builtin_amdgcn_perm((unsigned)q3, (unsigned)q2, 0x00000400u);
                    d[b * 2 + mt] = __builtin_amdgcn_perm(t23, t01, 0x05040100u);
                }
            }
            char* gp = tab + (size_t)cid * 128 + kg * 32;
            *(uint4*)gp        = make_uint4(d[0], d[1], d[2], d[3]);
            *(uint4*)(gp + 16) = make_uint4(d[4], d[5], d[6], d[7]);
            if (kg == 0) scl[cid] = m * (1.0f / 127.0f);
        }
    }

    // ---- part 2 (y==0 only): root GEMM + bias -> dense layer output ----
    if (blockIdx.y == 0) {
#pragma unroll 2
        for (int mt = 0; mt < 8; ++mt) {
            const int col0 = mt * 16 + kg * 4;
            f4v acc = *(const f4v*)&bias[col0];
#pragma unroll
            for (int kc = 0; kc < 4; ++kc) {
                s8v afrag = *(const s8v*)&RB[(((mt * 4 + kc) * 4 + kg) * 16 + lm) * 8];
                acc = __builtin_amdgcn_mfma_f32_16x16x32_bf16(afrag, bfr[kc], acc, 0, 0, 0);
            }
            if (OUT_BF16) {
                unsigned int p0 = (unsigned int)f2bfbits(acc[0]) |
                                  ((unsigned int)f2bfbits(acc[1]) << 16);
                unsigned int p1 = (unsigned int)f2bfbits(acc[2]) |
                                  ((unsigned int)f2bfbits(acc[3]) << 16);
                *(uint2*)((ushort*)outv + (size_t)node * DIM + col0) = make_uint2(p0, p1);
            } else {
                *(f4v*)((float*)outv + (size_t)node * DIM + col0) = acc;
            }
        }
    }
}

// ---------------------------------------------------------------------------
// Edge-stream aggregate over compact int8 table (indices in evec are already
// compact). Half-wave per dst node; 4 edges in flight x unroll 2.
// ---------------------------------------------------------------------------
template<bool OUT_BF16>
__global__ __launch_bounds__(256) void agg8_kernel(const int2* __restrict__ evec,
                                                   const int* __restrict__ off,
                                                   const char* __restrict__ tab,
                                                   const float* __restrict__ scl,
                                                   void* __restrict__ outv) {
    const int hw = threadIdx.x >> 5;
    const int o  = threadIdx.x & 31;
    const int v  = blockIdx.x * 8 + hw;

    const int start = (v == 0) ? 0 : off[v * N_REL - 1];
    const int end   = off[v * N_REL + N_REL - 1];

    const int p = o >> 4;            // edge parity within the quad (0/1)
    const int w = o & 15;            // 8-byte sub-chunk of the 128B row

    float acc[8];
#pragma unroll
    for (int j = 0; j < 8; ++j) acc[j] = 0.f;

#pragma unroll 2
    for (int base = start; base < end; base += 4) {
        const int k0 = base + p;
        const int k1 = base + 2 + p;
        const int2 e0 = evec[min(k0, end - 1)];
        const int2 e1 = evec[min(k1, end - 1)];
        const int g0 = e0.x, g1 = e1.x;
        const float i0 = (k0 < end) ? __int_as_float(e0.y) : 0.f;
        const float i1 = (k1 < end) ? __int_as_float(e1.y) : 0.f;
        const uint2 q0 = *(const uint2*)(tab + (size_t)g0 * 128 + w * 8);
        const uint2 q1 = *(const uint2*)(tab + (size_t)g1 * 128 + w * 8);
        const float s0 = scl[g0] * i0;
        const float s1 = scl[g1] * i1;
#pragma unroll
        for (int j = 0; j < 4; ++j) {
            acc[j]     = fmaf((float)(int)(signed char)(q0.x >> (8 * j)), s0, acc[j]);
            acc[4 + j] = fmaf((float)(int)(signed char)(q0.y >> (8 * j)), s0, acc[4 + j]);
        }
#pragma unroll
        for (int j = 0; j < 4; ++j) {
            acc[j]     = fmaf((float)(int)(signed char)(q1.x >> (8 * j)), s1, acc[j]);
            acc[4 + j] = fmaf((float)(int)(signed char)(q1.y >> (8 * j)), s1, acc[4 + j]);
        }
    }
#pragma unroll
    for (int j = 0; j < 8; ++j)
        acc[j] += __shfl_xor(acc[j], 16, 32);

    if (o < 16) {
        const int base0 = (o & 3) * 32 + (o >> 2) * 4;     // dim of acc[0]
        if (OUT_BF16) {
            ushort* hp = (ushort*)outv + (size_t)v * DIM + base0;
            ushort4 a0 = *(ushort4*)hp;
            ushort4 a1 = *(ushort4*)(hp + 16);
            a0.x = f2bfbits(bf2f(a0.x) + acc[0]);
            a0.y = f2bfbits(bf2f(a0.y) + acc[1]);
            a0.z = f2bfbits(bf2f(a0.z) + acc[2]);
            a0.w = f2bfbits(bf2f(a0.w) + acc[3]);
            a1.x = f2bfbits(bf2f(a1.x) + acc[4]);
            a1.y = f2bfbits(bf2f(a1.y) + acc[5]);
            a1.z = f2bfbits(bf2f(a1.z) + acc[6]);
            a1.w = f2bfbits(bf2f(a1.w) + acc[7]);
            *(ushort4*)hp        = a0;
            *(ushort4*)(hp + 16) = a1;
        } else {
            float* op = (float*)outv + (size_t)v * DIM + base0;
            float4 r0 = *(float4*)op;
            float4 r1 = *(float4*)(op + 16);
            r0.x += acc[0]; r0.y += acc[1]; r0.z += acc[2]; r0.w += acc[3];
            r1.x += acc[4]; r1.y += acc[5]; r1.z += acc[6]; r1.w += acc[7];
            *(float4*)op        = r0;
            *(float4*)(op + 16) = r1;
        }
    }
}

// ---------------------------------------------------------------------------
// Slow fallback (tiny ws): fp32 dense + gather-aggregate on x directly.
// ---------------------------------------------------------------------------
template<bool RELU>
__global__ __launch_bounds__(256) void dense_old_kernel(const float* __restrict__ x,
                                                        const float* __restrict__ root,
                                                        const float* __restrict__ bias,
                                                        float* __restrict__ out) {
    const int wv = threadIdx.x >> 6;
    const int l  = threadIdx.x & 63;
    const int wt = blockIdx.x * 4 + wv;
    if (wt >= NWT) return;
    const int nbase = wt * 16;
    const int lm = l & 15;
    const int kg = l >> 4;
    const int node = nbase + lm;

    s8v bfr[4];
#pragma unroll
    for (int kc = 0; kc < 4; ++kc) {
        const float* xp = &x[(size_t)node * DIM + kc * BS + kg * 8];
#pragma unroll
        for (int i = 0; i < 8; ++i) {
            float v = xp[i];
            if (RELU) v = fmaxf(v, 0.f);
            bfr[kc][i] = (short)f2bfbits(v);
        }
    }
#pragma unroll 2
    for (int mt = 0; mt < 8; ++mt) {
        const int col0 = mt * 16 + kg * 4;
        f4v acc = *(const f4v*)&bias[col0];
#pragma unroll
        for (int kc = 0; kc < 4; ++kc) {
            const float* rp = &root[(size_t)(kc * BS + kg * 8) * DIM + mt * 16 + lm];
            s8v afrag;
#pragma unroll
            for (int i = 0; i < 8; ++i)
                afrag[i] = (short)f2bfbits(rp[i * DIM]);
            acc = __builtin_amdgcn_mfma_f32_16x16x32_bf16(afrag, bfr[kc], acc, 0, 0, 0);
        }
        *(f4v*)&out[(size_t)node * DIM + col0] = acc;
    }
}

template<bool RELU>
__global__ __launch_bounds__(256) void agg_fallback_kernel(const int* __restrict__ srcs,
                                                           const int* __restrict__ off,
                                                           const int* __restrict__ cnt,
                                                           const float* __restrict__ x,
                                                           const float* __restrict__ W,
                                                           float* __restrict__ out) {
    __shared__ float Wsh[N_REL * BS * BS];
    const int bblk = blockIdx.y;
    for (int idx = threadIdx.x * 4; idx < N_REL * BS * BS; idx += 1024) {
        int r = idx >> 10, rest = idx & 1023;
        *(float4*)&Wsh[idx] = *(const float4*)&W[(r * NBLK + bblk) * 1024 + rest];
    }
    __syncthreads();
    const int hw = threadIdx.x >> 5;
    const int o  = threadIdx.x & 31;
    const int v  = blockIdx.x * 8 + hw;
    int endv = 0, cv = 0;
    if (o < N_REL) { endv = off[v * N_REL + o]; cv = cnt[v * N_REL + o]; }
    float acc = out[v * DIM + bblk * BS + o];
    for (int r = 0; r < N_REL; ++r) {
        const int c = __shfl(cv, r, 32);
        if (c == 0) continue;
        const int end = __shfl(endv, r, 32);
        float xs = 0.f;
        for (int k = end - c; k < end; ++k) {
            const int s = srcs[k];
            float xv = x[s * DIM + bblk * BS + o];
            if (RELU) xv = fmaxf(xv, 0.f);
            xs += xv;
        }
        xs *= (1.0f / (float)c);
        const float* wr = &Wsh[r * (BS * BS)];
#pragma unroll
        for (int i = 0; i < BS; i += 2) {
            float xi0 = __shfl(xs, i, 32);
            float xi1 = __shfl(xs, i + 1, 32);
            acc = fmaf(xi0, wr[i * BS + o], acc);
            acc = fmaf(xi1, wr[(i + 1) * BS + o], acc);
        }
    }
    out[v * DIM + bblk * BS + o] = acc;
}

// ---------------------------------------------------------------------------
extern "C" void kernel_launch(void* const* d_in, const int* in_sizes, int n_in,
                              void* d_out, int out_size, void* d_ws, size_t ws_size,
                              hipStream_t stream) {
    const int*   edge_index = (const int*)d_in[0];
    const int*   src   = edge_index;
    const int*   dstv  = edge_index + N_EDGES;
    const int*   et    = (const int*)d_in[1];
    const float* x0    = (const float*)d_in[2];
    const float* W1    = (const float*)d_in[3];
    const float* root1 = (const float*)d_in[4];
    const float* bias1 = (const float*)d_in[5];
    const float* W2    = (const float*)d_in[6];
    const float* root2 = (const float*)d_in[7];
    const float* bias2 = (const float*)d_in[8];
    float* out = (float*)d_out;

    // ---- fast-path workspace layout (138.2 MB total) ----
    char* ws = (char*)d_ws;
    ushort* h    = (ushort*)ws;                             // 12,800,000 (bf16)
    int*    cnt  = (int*)   (ws + 12800000);                //  3,200,000
    int*    used = (int*)   (ws + 16000000);                //  3,200,000 (adj to cnt)
    int*    off  = (int*)   (ws + 19200000);                //  3,200,000
    int*    cmap = (int*)   (ws + 22400000);                //  3,200,000
    int2*   evec = (int2*)  (ws + 25600000);                //  6,400,000
    int2*   bsum = (int2*)  (ws + 32000000);                //      8,192
    ushort* WB1  = (ushort*)(ws + 32008192);                //    262,144
    ushort* WB2  = (ushort*)(ws + 32270336);                //    262,144
    ushort* RB1  = (ushort*)(ws + 32532480);                //     32,768
    ushort* RB2  = (ushort*)(ws + 32565248);                //     32,768
    float*  scl  = (float*) (ws + 32598016);                //  3,200,000
    char*   tab  =          (ws + 35798016);                // 102,400,000
    const size_t FAST_NEED = 138198016ull;

    const int egrid = (N_EDGES + 255) / 256;     // 3125
    const int tgrid = (NWT + 3) / 4;             // 782

    if (ws_size >= FAST_NEED) {
        prep_kernel<<<1152, 256, 0, stream>>>(W1, W2, root1, root2, WB1, WB2, RB1, RB2);
        hipMemsetAsync(cnt, 0, 2 * (size_t)NSEG * sizeof(int), stream);  // cnt+used
        count_kernel<<<egrid, 256, 0, stream>>>(src, dstv, et, cnt, used, N_EDGES);
        scan1j_kernel<<<N_SCAN_BLKS, 256, 0, stream>>>(cnt, used, off, cmap, bsum, NSEG);
        scan2j_kernel<<<1, 1024, 0, stream>>>(bsum, N_SCAN_BLKS);
        scan3j_kernel<<<(NSEG + 255) / 256, 256, 0, stream>>>(off, cmap, bsum, NSEG);
        scatter_fast_kernel<<<egrid, 256, 0, stream>>>(src, dstv, et, off, cnt, cmap,
                                                       evec, N_EDGES);

        dim3 fgrid(tgrid, 2);                    // relation-split: 2x waves
        const int ngrid = N_NODES / 8;           // 6250

        // ---- layer 1: h(bf16) = x0@root1 + bias1 (dense) + compact table ----
        fused_kernel<false, true, false><<<fgrid, 256, 0, stream>>>(
            x0, WB1, RB1, bias1, used, cmap, tab, scl, h);
        agg8_kernel<true><<<ngrid, 256, 0, stream>>>(evec, off, tab, scl, h);

        // ---- layer 2: out(fp32) = relu(h)@root2 + bias2 + compact table ----
        fused_kernel<true, false, true><<<fgrid, 256, 0, stream>>>(
            h, WB2, RB2, bias2, used, cmap, tab, scl, out);
        agg8_kernel<false><<<ngrid, 256, 0, stream>>>(evec, off, tab, scl, out);
    } else {
        // ---- slow fallback (ws >= 35.3 MB): fp32 h + direct gather-agg ----
        float* hf    = (float*)d_ws;
        int*   cntf  = (int*)((char*)d_ws + 25600000);
        int*   offf  = (int*)((char*)d_ws + 28800000);
        int*   srcsf = (int*)((char*)d_ws + 32000000);
        int*   bsumf = (int*)((char*)d_ws + 35200000);
        int*   usedD = offf;   // scratch alias (overwritten before real use)

        hipMemsetAsync(cntf, 0, (size_t)NSEG * sizeof(int), stream);
        count_kernel<<<egrid, 256, 0, stream>>>(src, dstv, et, cntf, usedD, N_EDGES);
        scan1_kernel<<<N_SCAN_BLKS, 256, 0, stream>>>(cntf, offf, bsumf, NSEG);
        scan2_kernel<<<1, 1024, 0, stream>>>(bsumf, N_SCAN_BLKS);
        scan3_kernel<<<(NSEG + 255) / 256, 256, 0, stream>>>(offf, bsumf, NSEG);
        scatter_old_kernel<<<egrid, 256, 0, stream>>>(src, dstv, et, offf, srcsf, N_EDGES);

        dim3 fgrid2(N_NODES / 8, NBLK);
        dense_old_kernel<false><<<tgrid, 256, 0, stream>>>(x0, root1, bias1, hf);
        agg_fallback_kernel<false><<<fgrid2, 256, 0, stream>>>(srcsf, offf, cntf, x0, W1, hf);
        dense_old_kernel<true><<<tgrid, 256, 0, stream>>>(hf, root2, bias2, out);
        agg_fallback_kernel<true><<<fgrid2, 256, 0, stream>>>(srcsf, offf, cntf, hf, W2, out);
    }
}